// Round 5
// baseline (1692.019 us; speedup 1.0000x reference)
//
#include <hip/hip_runtime.h>
#include <stdint.h>

typedef unsigned short u16;
typedef __attribute__((ext_vector_type(4))) float f32x4;
typedef __attribute__((ext_vector_type(4))) unsigned short u16x4;
typedef __attribute__((ext_vector_type(8))) short short8;

#define DEV static __device__ __forceinline__

DEV float bf2f(u16 u){ union{unsigned int i; float f;} v; v.i=((unsigned int)u)<<16; return v.f; }
DEV u16 f2bf(float f){ union{float f; unsigned int i;} v; v.f=f; unsigned int u=v.i;
  return (u16)((u + 0x7FFFu + ((u>>16)&1u))>>16); }
DEV float wred(float v){ for(int o=32;o;o>>=1) v += __shfl_xor(v,o); return v; }
DEV float wredmax(float v){ for(int o=32;o;o>>=1) v = fmaxf(v,__shfl_xor(v,o)); return v; }

DEV float actf(int ACT, float v){
  if(ACT==1) return v>0.f?v:0.f;
  if(ACT==2) return 1.f/(1.f+__expf(-v));
  if(ACT==3) return tanhf(v);
  if(ACT==4) return v>0.f?v:(__expf(v)-1.f);
  return v;
}

// ---------------- f32 -> bf16 conversion ----------------
__global__ void cvt_kernel(const float* __restrict__ s, u16* __restrict__ d, int n4){
  for(int i=blockIdx.x*blockDim.x+threadIdx.x; i<n4; i+=gridDim.x*blockDim.x){
    f32x4 v=((const f32x4*)s)[i];
    u16x4 o;
    #pragma unroll
    for(int j=0;j<4;++j) o[j]=f2bf(v[j]);
    ((u16x4*)d)[i]=o;
  }
}

// f32 -> (hi, lo) bf16 split
__global__ void cvt_split(const float* __restrict__ s, u16* __restrict__ hi, u16* __restrict__ lo, int n4){
  for(int i=blockIdx.x*blockDim.x+threadIdx.x; i<n4; i+=gridDim.x*blockDim.x){
    f32x4 v=((const f32x4*)s)[i];
    u16x4 h,l;
    #pragma unroll
    for(int j=0;j<4;++j){ h[j]=f2bf(v[j]); l[j]=f2bf(v[j]-bf2f(h[j])); }
    ((u16x4*)hi)[i]=h; ((u16x4*)lo)[i]=l;
  }
}

// pack+split rout_w1[:, :1024] (lda=1030 f32) into dense hi/lo 512x1024
__global__ void cvt_split_rw1(const float* __restrict__ src, u16* __restrict__ hi, u16* __restrict__ lo){
  for(int i=blockIdx.x*blockDim.x+threadIdx.x; i<512*1024; i+=gridDim.x*blockDim.x){
    int r=i>>10, c=i&1023;
    float v=src[(size_t)r*1030+c];
    u16 h=f2bf(v);
    hi[i]=h; lo[i]=f2bf(v-bf2f(h));
  }
}

// ---------------- GEMM: C = act(A @ W^T + bias) (+ res), bf16 in, f32 accum ------------
// A: M x K row-major bf16, W: N x K row-major bf16. 128x128 tile, 4 waves, BK=64.
template<int ACT, bool RES, bool F32OUT>
__global__ __launch_bounds__(256) void gemm_bt(
    const u16* __restrict__ A, const u16* __restrict__ W,
    const float* __restrict__ bias, const float* __restrict__ res,
    void* __restrict__ Cv, int M, int N, int K)
{
  __shared__ __align__(16) u16 lA[128*64];
  __shared__ __align__(16) u16 lB[128*64];
  const int tid=threadIdx.x, lane=tid&63, wv=tid>>6;
  const int wr=wv>>1, wc=wv&1;
  const int bn=blockIdx.x*128, bm=blockIdx.y*128;
  f32x4 acc[4][4];
  #pragma unroll
  for(int m=0;m<4;++m){
    #pragma unroll
    for(int n=0;n<4;++n) acc[m][n]=(f32x4)0.f;
  }
  const int srow = wv*8 + (lane>>3);
  const int scol = (lane&7)*8;
  const int ldst = wv*8*64 + lane*8;
  for(int kt=0;kt<K;kt+=64){
    short8 ra[4], rb[4];
    #pragma unroll
    for(int i=0;i<4;++i){
      ra[i]=*(const short8*)(A + (size_t)(bm + i*32 + srow)*K + kt + scol);
      rb[i]=*(const short8*)(W + (size_t)(bn + i*32 + srow)*K + kt + scol);
    }
    __syncthreads();
    #pragma unroll
    for(int i=0;i<4;++i){
      *(short8*)&lA[i*32*64 + ldst] = ra[i];
      *(short8*)&lB[i*32*64 + ldst] = rb[i];
    }
    __syncthreads();
    #pragma unroll
    for(int kk=0;kk<2;++kk){
      const int fr=lane&15, kc=kk*32+(lane>>4)*8;
      short8 af[4], bfr[4];
      #pragma unroll
      for(int m=0;m<4;++m) af[m]=*(const short8*)&lA[(wr*64+m*16+fr)*64+kc];
      #pragma unroll
      for(int n=0;n<4;++n) bfr[n]=*(const short8*)&lB[(wc*64+n*16+fr)*64+kc];
      #pragma unroll
      for(int m=0;m<4;++m){
        #pragma unroll
        for(int n=0;n<4;++n)
          acc[m][n]=__builtin_amdgcn_mfma_f32_16x16x32_bf16(af[m],bfr[n],acc[m][n],0,0,0);
      }
    }
  }
  const int fr=lane&15, fq=lane>>4;
  #pragma unroll
  for(int m=0;m<4;++m){
    #pragma unroll
    for(int n=0;n<4;++n){
      const int col = bn + wc*64 + n*16 + fr;
      const float bv = bias[col];
      #pragma unroll
      for(int j=0;j<4;++j){
        const int row = bm + wr*64 + m*16 + fq*4 + j;
        float v = acc[m][n][j] + bv;
        v = actf(ACT, v);
        if(RES) v += res[(size_t)row*N+col];
        if(F32OUT) ((float*)Cv)[(size_t)row*N+col] = v;
        else       ((u16*)Cv)[(size_t)row*N+col] = f2bf(v);
      }
    }
  }
}

// ---------------- split-precision GEMM (f32-accurate): C = act(A@W^T + b), f32 out -----
// A = Ah+Al, W = Wh+Wl (bf16 hi/lo). 128x128 tile, BK=32, 4 MFMA products per fragment.
template<int ACT>
__global__ __launch_bounds__(256) void gemm_split(
    const u16* __restrict__ Ah, const u16* __restrict__ Al,
    const u16* __restrict__ Wh, const u16* __restrict__ Wl,
    const float* __restrict__ bias, float* __restrict__ C, int M, int N, int K)
{
  const int LDL=40; // 32 + 8 pad (bank spread)
  __shared__ __align__(16) u16 lAh[128*40], lAl[128*40], lBh[128*40], lBl[128*40];
  const int tid=threadIdx.x, lane=tid&63, wv=tid>>6;
  const int wr=wv>>1, wc=wv&1;
  const int bn=blockIdx.x*128, bm=blockIdx.y*128;
  f32x4 acc[4][4];
  #pragma unroll
  for(int m=0;m<4;++m){
    #pragma unroll
    for(int n=0;n<4;++n) acc[m][n]=(f32x4)0.f;
  }
  const int srow=tid>>2, scol=(tid&3)*8;
  for(int kt=0;kt<K;kt+=32){
    short8 rah[2],ral[2],rbh[2],rbl[2];
    #pragma unroll
    for(int i=0;i<2;++i){
      size_t ao=(size_t)(bm+i*64+srow)*K+kt+scol;
      size_t bo=(size_t)(bn+i*64+srow)*K+kt+scol;
      rah[i]=*(const short8*)(Ah+ao); ral[i]=*(const short8*)(Al+ao);
      rbh[i]=*(const short8*)(Wh+bo); rbl[i]=*(const short8*)(Wl+bo);
    }
    __syncthreads();
    #pragma unroll
    for(int i=0;i<2;++i){
      int d=(i*64+srow)*LDL+scol;
      *(short8*)&lAh[d]=rah[i]; *(short8*)&lAl[d]=ral[i];
      *(short8*)&lBh[d]=rbh[i]; *(short8*)&lBl[d]=rbl[i];
    }
    __syncthreads();
    const int fr=lane&15, kc=(lane>>4)*8;
    short8 ah[4],al[4],bh[4],bl[4];
    #pragma unroll
    for(int m=0;m<4;++m){ int r=(wr*64+m*16+fr)*LDL+kc; ah[m]=*(const short8*)&lAh[r]; al[m]=*(const short8*)&lAl[r]; }
    #pragma unroll
    for(int n=0;n<4;++n){ int r=(wc*64+n*16+fr)*LDL+kc; bh[n]=*(const short8*)&lBh[r]; bl[n]=*(const short8*)&lBl[r]; }
    #pragma unroll
    for(int m=0;m<4;++m){
      #pragma unroll
      for(int n=0;n<4;++n){
        acc[m][n]=__builtin_amdgcn_mfma_f32_16x16x32_bf16(ah[m],bh[n],acc[m][n],0,0,0);
        acc[m][n]=__builtin_amdgcn_mfma_f32_16x16x32_bf16(ah[m],bl[n],acc[m][n],0,0,0);
        acc[m][n]=__builtin_amdgcn_mfma_f32_16x16x32_bf16(al[m],bh[n],acc[m][n],0,0,0);
        acc[m][n]=__builtin_amdgcn_mfma_f32_16x16x32_bf16(al[m],bl[n],acc[m][n],0,0,0);
      }
    }
  }
  const int fr=lane&15, fq=lane>>4;
  #pragma unroll
  for(int m=0;m<4;++m){
    #pragma unroll
    for(int n=0;n<4;++n){
      const int col = bn + wc*64 + n*16 + fr;
      const float bv = bias[col];
      #pragma unroll
      for(int j=0;j<4;++j){
        const int row = bm + wr*64 + m*16 + fq*4 + j;
        C[(size_t)row*N+col] = actf(ACT, acc[m][n][j] + bv);
      }
    }
  }
}

// ---------------- feature stats + kpred MLP -> k_vals[row] (all f32) ----------------
__global__ __launch_bounds__(256) void feats_kernel(const float* __restrict__ x,
    const float* __restrict__ kw1, const float* __restrict__ kb1,
    const float* __restrict__ kw2, const float* __restrict__ kb2,
    float* __restrict__ kvals)
{
  __shared__ float xs[1024];
  __shared__ unsigned int cd[1024];
  __shared__ float rbuf[4*6];
  __shared__ float r2[4], r3[4];
  __shared__ float bres[6];
  __shared__ int icnt;
  const int tid=threadIdx.x, lane=tid&63, wv=tid>>6;
  const int row=blockIdx.x;
  f32x4 u = ((const f32x4*)(x+(size_t)row*1024))[tid];
  float s=0.f, ss=0.f, amax=0.f, sa=0.f; float nz=0.f;
  #pragma unroll
  for(int j=0;j<4;++j){
    float f=u[j];
    union{float f;unsigned int i;} cv; cv.f=f;
    xs[4*tid+j]=f; cd[4*tid+j]=cv.i&0x7fffffffu;
    s+=f; ss+=f*f; float a=fabsf(f); sa+=a; amax=fmaxf(amax,a); if(f==0.f) nz+=1.f;
  }
  s=wred(s); ss=wred(ss); sa=wred(sa); nz=wred(nz); amax=wredmax(amax);
  if(lane==0){ rbuf[wv*6+0]=s; rbuf[wv*6+1]=ss; rbuf[wv*6+2]=sa; rbuf[wv*6+3]=nz; rbuf[wv*6+4]=amax; }
  __syncthreads();
  if(tid==0){
    float S=0,SS=0,SA=0,NZ=0,AM=0;
    for(int i=0;i<4;++i){ S+=rbuf[i*6]; SS+=rbuf[i*6+1]; SA+=rbuf[i*6+2]; NZ+=rbuf[i*6+3]; AM=fmaxf(AM,rbuf[i*6+4]); }
    bres[0]=S; bres[1]=SS; bres[2]=SA; bres[3]=NZ; bres[4]=AM;
  }
  __syncthreads();
  const float S=bres[0], SS=bres[1], SA=bres[2], NZ=bres[3], AM=bres[4];
  const float mean=S/1024.f;
  const float var=(SS - S*mean)/1023.f;
  const float inv=1.f/sqrtf(var+1e-8f);
  float sk=0.f;
  #pragma unroll
  for(int j=0;j<4;++j){ float z=(xs[4*tid+j]-mean)*inv; sk+=z*z*z; }
  sk=wred(sk);
  if(lane==0) rbuf[wv*6+5]=sk;
  // binary search on f32 abs-codes: T = max code t with count(code>=t) >= 204
  unsigned int lo=0u, hi=0x7f800000u;
  while(hi-lo>1u){
    unsigned int mid=(lo+hi)>>1;
    if(tid==0) icnt=0;
    __syncthreads();
    int c0=0;
    #pragma unroll
    for(int j=0;j<4;++j) c0 += (cd[4*tid+j] >= mid);
    float cf=wred((float)c0);
    if(lane==0) atomicAdd(&icnt,(int)cf);
    __syncthreads();
    int cc=icnt;
    __syncthreads();
    if(cc>=204) lo=mid; else hi=mid;
  }
  float sg=0.f; float cg=0.f;
  #pragma unroll
  for(int j=0;j<4;++j){ if(cd[4*tid+j] > lo){ sg+=fabsf(xs[4*tid+j]); cg+=1.f; } }
  sg=wred(sg); cg=wred(cg);
  if(lane==0){ r2[wv]=sg; r3[wv]=cg; }
  __syncthreads();
  if(tid==0){
    float SK=rbuf[5]+rbuf[11]+rbuf[17]+rbuf[23];
    float SG=r2[0]+r2[1]+r2[2]+r2[3];
    float CG=r3[0]+r3[1]+r3[2]+r3[3];
    union{unsigned int i;float f;} tv; tv.i=lo;
    float conc=(SG + (204.f-CG)*tv.f)/(SA + 1e-8f);
    float feats[6]={ NZ/1024.f, var, AM, sqrtf(SS), SK/1024.f, conc };
    float out=kb2[0];
    #pragma unroll
    for(int i=0;i<16;++i){
      float hv=kb1[i];
      #pragma unroll
      for(int j=0;j<6;++j) hv+=kw1[i*6+j]*feats[j];
      hv=fmaxf(hv,0.f);
      out+=kw2[i]*hv;
    }
    kvals[row]=1.f + 3.f*(1.f/(1.f+__expf(-out)));
  }
}

// ---------------- exact median of 8192 -> k ----------------
__global__ __launch_bounds__(256) void median_kernel(const float* __restrict__ kvals, int* __restrict__ kint){
  __shared__ unsigned int v[8192];
  __shared__ int icnt;
  const int tid=threadIdx.x;
  for(int i=tid;i<8192;i+=256){ union{float f;unsigned int u;} c; c.f=kvals[i]; v[i]=c.u; }
  __syncthreads();
  unsigned int res[2];
  for(int t=0;t<2;++t){
    const int kth=4096+t;
    unsigned int lo=0u, hi=0xFFFFFFFFu;
    while(lo<hi){
      unsigned int mid=lo+((hi-lo)>>1);
      if(tid==0) icnt=0;
      __syncthreads();
      int c=0;
      for(int i=tid;i<8192;i+=256) c += (v[i] <= mid);
      float cf=wred((float)c);
      if((tid&63)==0) atomicAdd(&icnt,(int)cf);
      __syncthreads();
      int cc=icnt;
      __syncthreads();
      if(cc>=kth) hi=mid; else lo=mid+1u;
    }
    res[t]=lo;
  }
  if(tid==0){
    union{unsigned int u; float f;} a,b; a.u=res[0]; b.u=res[1];
    float med=0.5f*(a.f+b.f);
    int k=(int)floorf(med);
    k = k<1?1:(k>4?4:k);
    *kint=k;
  }
}

// ---------------- spec = sigmoid(x@esp^T + h512a@sim_w2^T + sim_b2), one wave/row ------
__global__ __launch_bounds__(256) void spec_kernel(const float* __restrict__ x, const float* __restrict__ h,
    const float* __restrict__ esp, const float* __restrict__ w2, const float* __restrict__ b2,
    float* __restrict__ spec){
  const int wv=threadIdx.x>>6, lane=threadIdx.x&63;
  const int row=blockIdx.x*4+wv;
  const float* xr=x+(size_t)row*1024;
  const float* hr=h+(size_t)row*512;
  float xv[16], hv[8];
  #pragma unroll
  for(int j=0;j<16;++j) xv[j]=xr[j*64+lane];
  #pragma unroll
  for(int j=0;j<8;++j) hv[j]=hr[j*64+lane];
  for(int e=0;e<6;++e){
    float s=0.f;
    #pragma unroll
    for(int j=0;j<16;++j) s+=xv[j]*esp[e*1024+j*64+lane];
    #pragma unroll
    for(int j=0;j<8;++j) s+=hv[j]*w2[e*512+j*64+lane];
    s=wred(s);
    if(lane==0) spec[row*6+e]=1.f/(1.f+__expf(-(s+b2[e])));
  }
}

// ---------------- rout pre-act += spec @ rw1[:,1024:]^T, relu (f32 h) ----------------
__global__ void rout_fix(float* __restrict__ h, const float* __restrict__ spec, const float* __restrict__ rw1){
  const int total=8192*128;
  for(int i=blockIdx.x*blockDim.x+threadIdx.x;i<total;i+=gridDim.x*blockDim.x){
    int row=i>>7, j0=(i&127)*4;
    const float* sp=&spec[row*6];
    f32x4 hv=((f32x4*)h)[i];
    #pragma unroll
    for(int j=0;j<4;++j){
      float v=hv[j];
      int col=j0+j;
      #pragma unroll
      for(int e=0;e<6;++e) v+=sp[e]*rw1[(size_t)col*1030+1024+e];
      hv[j]=fmaxf(v,0.f);
    }
    ((f32x4*)h)[i]=hv;
  }
}

// ---------------- probs = softmax(h512b@rout_w2^T + rout_b2), one wave per row ----------
__global__ __launch_bounds__(256) void probs_kernel(const float* __restrict__ h, const float* __restrict__ w2,
    const float* __restrict__ b2, float* __restrict__ probs){
  const int wv=threadIdx.x>>6, lane=threadIdx.x&63;
  const int row=blockIdx.x*4+wv;
  const float* hr=h+(size_t)row*512;
  float hv[8];
  #pragma unroll
  for(int j=0;j<8;++j) hv[j]=hr[j*64+lane];
  float lg[6];
  #pragma unroll
  for(int e=0;e<6;++e){
    float s=0.f;
    #pragma unroll
    for(int j=0;j<8;++j) s+=hv[j]*w2[e*512+j*64+lane];
    lg[e]=wred(s)+b2[e];
  }
  if(lane==0){
    float m=lg[0];
    #pragma unroll
    for(int e=1;e<6;++e) m=fmaxf(m,lg[e]);
    float den=0.f, ex[6];
    #pragma unroll
    for(int e=0;e<6;++e){ ex[e]=__expf(lg[e]-m); den+=ex[e]; }
    #pragma unroll
    for(int e=0;e<6;++e) probs[row*6+e]=ex[e]/den;
  }
}

// ---------------- top-4 + gates -> per-expert weights ----------------
__global__ void gates_kernel(const float* __restrict__ probs, const int* __restrict__ kint,
                             float* __restrict__ wsel){
  const int r=blockIdx.x*blockDim.x+threadIdx.x;
  if(r>=8192) return;
  const int k=*kint;
  float p[6];
  #pragma unroll
  for(int e=0;e<6;++e) p[e]=probs[r*6+e];
  float w[6]={0,0,0,0,0,0};
  bool used[6]={false,false,false,false,false,false};
  int idx[4]; float val[4];
  #pragma unroll
  for(int j=0;j<4;++j){
    int bi=0; float bv=-1e30f;
    #pragma unroll
    for(int e=0;e<6;++e) if(!used[e] && p[e]>bv){ bv=p[e]; bi=e; }
    used[bi]=true; idx[j]=bi; val[j]=bv;
  }
  float m=val[0], den=0.f, g[4]={0,0,0,0};
  for(int j=0;j<k;++j){ g[j]=__expf(val[j]-m); den+=g[j]; }
  for(int j=0;j<k;++j) w[idx[j]]=g[j]/den;
  #pragma unroll
  for(int e=0;e<6;++e) wsel[r*6+e]=w[e];
}

// ---------------- att*x elementwise: o = bf16(a_bf16 * x_f32) ----------------
__global__ void mul_kernel(const u16* __restrict__ a, const float* __restrict__ x, u16* __restrict__ o){
  const int total=8192*256;
  for(int i=blockIdx.x*blockDim.x+threadIdx.x;i<total;i+=gridDim.x*blockDim.x){
    u16x4 av=((const u16x4*)a)[i];
    f32x4 xv=((const f32x4*)x)[i];
    u16x4 ov;
    #pragma unroll
    for(int j=0;j<4;++j) ov[j]=f2bf(bf2f(av[j])*xv[j]);
    ((u16x4*)o)[i]=ov;
  }
}

// MODE 0: comb  = w0*p0             (sp)
// MODE 1: comb += w1*(p0 + p1*x)    p0=de2, p1=sig_gate
// MODE 2: comb += w2*p0             (cf)
// MODE 3: comb += w3*(x + (p0-x)*x) p0=filt
// MODE 5: comb += w5*sign(x)*sqrt(|p0*x|+1e-8)  p0=t
template<int MODE>
__global__ void acc_kernel(float* __restrict__ comb, const float* __restrict__ wsel,
    const u16* __restrict__ p0, const u16* __restrict__ p1, const float* __restrict__ xf){
  const int total=8192*256;
  const int widx = (MODE==5)?5:MODE;
  f32x4* c4=(f32x4*)comb;
  for(int i=blockIdx.x*blockDim.x+threadIdx.x;i<total;i+=gridDim.x*blockDim.x){
    const int row=i>>8;
    const float w=wsel[row*6+widx];
    u16x4 a=((const u16x4*)p0)[i];
    f32x4 r;
    if(MODE==0){
      #pragma unroll
      for(int j=0;j<4;++j) r[j]=w*bf2f(a[j]);
    } else if(MODE==1){
      u16x4 g=((const u16x4*)p1)[i];
      f32x4 xv=((const f32x4*)xf)[i];
      r=c4[i];
      #pragma unroll
      for(int j=0;j<4;++j) r[j]+=w*(bf2f(a[j]) + bf2f(g[j])*xv[j]);
    } else if(MODE==2){
      r=c4[i];
      #pragma unroll
      for(int j=0;j<4;++j) r[j]+=w*bf2f(a[j]);
    } else if(MODE==3){
      f32x4 xv=((const f32x4*)xf)[i];
      r=c4[i];
      #pragma unroll
      for(int j=0;j<4;++j){ float x0=xv[j]; float fl=bf2f(a[j]); r[j]+=w*(x0+(fl-x0)*x0); }
    } else {
      f32x4 xv=((const f32x4*)xf)[i];
      r=c4[i];
      #pragma unroll
      for(int j=0;j<4;++j){
        float x0=xv[j]; float t=bf2f(a[j]);
        float sgn=(x0>0.f)?1.f:((x0<0.f)?-1.f:0.f);
        r[j]+=w*sgn*sqrtf(fabsf(t*x0)+1e-8f);
      }
    }
    c4[i]=r;
  }
}

__global__ void tobf16_kernel(const float* __restrict__ c, u16* __restrict__ o){
  const int total=8192*256;
  for(int i=blockIdx.x*blockDim.x+threadIdx.x;i<total;i+=gridDim.x*blockDim.x){
    f32x4 cv=((const f32x4*)c)[i];
    u16x4 ov;
    #pragma unroll
    for(int j=0;j<4;++j) ov[j]=f2bf(cv[j]);
    ((u16x4*)o)[i]=ov;
  }
}

// ---------------- CrossField expert: per-row 32x32 field attention (f32) ----------------
__global__ __launch_bounds__(256) void cf_kernel(const float* __restrict__ x,
    const float* __restrict__ w_in, const float* __restrict__ b_in,
    const float* __restrict__ w_o, const float* __restrict__ b_o,
    const float* __restrict__ w_f, const float* __restrict__ b_f,
    u16* __restrict__ eout){
  __shared__ float xf[1024];
  __shared__ float qkv[32*96];
  __shared__ float sc[1024];
  __shared__ float av[1024];
  const int row=blockIdx.x, tid=threadIdx.x;
  f32x4 u=((const f32x4*)(x+(size_t)row*1024))[tid];
  #pragma unroll
  for(int j=0;j<4;++j) xf[4*tid+j]=u[j];
  __syncthreads();
  #pragma unroll
  for(int t=0;t<12;++t){
    int oi=t*256+tid; int f=oi/96, c=oi-96*f;
    float s=b_in[c];
    const float* wr=w_in+c*32;
    const float* xr=&xf[f*32];
    #pragma unroll
    for(int d=0;d<32;++d) s+=xr[d]*wr[d];
    qkv[f*96+c]=s;
  }
  __syncthreads();
  const float scale=0.17677669529663687f;
  #pragma unroll
  for(int t=0;t<4;++t){
    int oi=t*256+tid; int q=oi>>5, kq=oi&31;
    float s=0.f;
    #pragma unroll
    for(int d=0;d<32;++d) s+=qkv[q*96+d]*qkv[kq*96+32+d];
    sc[oi]=s*scale;
  }
  __syncthreads();
  if(tid<32){
    float m=-1e30f;
    for(int j=0;j<32;++j) m=fmaxf(m,sc[tid*32+j]);
    float den=0.f;
    for(int j=0;j<32;++j){ float e=__expf(sc[tid*32+j]-m); sc[tid*32+j]=e; den+=e; }
    float inv=1.f/den;
    for(int j=0;j<32;++j) sc[tid*32+j]*=inv;
  }
  __syncthreads();
  #pragma unroll
  for(int t=0;t<4;++t){
    int oi=t*256+tid; int q=oi>>5, d=oi&31;
    float s=0.f;
    #pragma unroll
    for(int k=0;k<32;++k) s+=sc[q*32+k]*qkv[k*96+64+d];
    av[oi]=s;
  }
  __syncthreads();
  #pragma unroll
  for(int t=0;t<4;++t){
    int oi=t*256+tid; int q=oi>>5, d=oi&31;
    float s=b_o[d];
    #pragma unroll
    for(int c=0;c<32;++c) s+=av[q*32+c]*w_o[d*32+c];
    sc[oi]=s*xf[oi];
  }
  __syncthreads();
  #pragma unroll
  for(int t=0;t<4;++t){
    int oi=t*256+tid; int q=oi>>5, d=oi&31;
    float s=b_f[d];
    #pragma unroll
    for(int c=0;c<32;++c) s+=sc[q*32+c]*w_f[d*32+c];
    eout[(size_t)row*1024+oi]=f2bf(s);
  }
}

// ---------------- Temporal expert: conv1d(k=3,pad=1,4ch) gate, fused accumulate --------
__global__ __launch_bounds__(256) void tp_kernel(const float* __restrict__ x,
    const float* __restrict__ wsel, float* __restrict__ comb,
    const float* __restrict__ tcw, const float* __restrict__ tcb,
    const float* __restrict__ tfw, const float* __restrict__ tfb){
  __shared__ float xs[1026];
  const int row=blockIdx.x, tid=threadIdx.x;
  f32x4 u=((const f32x4*)(x+(size_t)row*1024))[tid];
  #pragma unroll
  for(int j=0;j<4;++j) xs[1+4*tid+j]=u[j];
  if(tid==0){ xs[0]=0.f; xs[1025]=0.f; }
  __syncthreads();
  const float w4=wsel[row*6+4];
  float tc[4][3], tb[4], tf[4];
  #pragma unroll
  for(int o=0;o<4;++o){
    #pragma unroll
    for(int kh=0;kh<3;++kh) tc[o][kh]=tcw[o*3+kh];
    tb[o]=tcb[o]; tf[o]=tfw[o];
  }
  const float tfb0=tfb[0];
  #pragma unroll
  for(int j=0;j<4;++j){
    const int d=4*tid+j;
    float pre=tfb0;
    #pragma unroll
    for(int o=0;o<4;++o){
      float cv=tb[o]+tc[o][0]*xs[d]+tc[o][1]*xs[d+1]+tc[o][2]*xs[d+2];
      pre+=tf[o]*fmaxf(cv,0.f);
    }
    float wt=1.f/(1.f+__expf(-pre));
    float xv=xs[1+d];
    comb[(size_t)row*1024+d]+=w4*xv*xv*wt;
  }
}

// =======================================================================================
extern "C" void kernel_launch(void* const* d_in, const int* in_sizes, int n_in,
                              void* d_out, int out_size, void* d_ws, size_t ws_size,
                              hipStream_t stream)
{
  const float* x     =(const float*)d_in[0];
  const float* esp   =(const float*)d_in[1];
  const float* sim_w1=(const float*)d_in[2],  *sim_b1=(const float*)d_in[3];
  const float* sim_w2=(const float*)d_in[4],  *sim_b2=(const float*)d_in[5];
  const float* rout_w1=(const float*)d_in[6], *rout_b1=(const float*)d_in[7];
  const float* rout_w2=(const float*)d_in[8], *rout_b2=(const float*)d_in[9];
  const float* kw1=(const float*)d_in[10], *kb1=(const float*)d_in[11];
  const float* kw2=(const float*)d_in[12], *kb2=(const float*)d_in[13];
  const float* spv_w=(const float*)d_in[14], *spv_b=(const float*)d_in[15];
  const float* spo_w=(const float*)d_in[16], *spo_b=(const float*)d_in[17];
  const float* spq1_w=(const float*)d_in[18], *spq1_b=(const float*)d_in[19];
  const float* spq2_w=(const float*)d_in[20], *spq2_b=(const float*)d_in[21];
  const float* de_w1=(const float*)d_in[22], *de_b1=(const float*)d_in[23];
  const float* de_w2=(const float*)d_in[24], *de_b2=(const float*)d_in[25];
  const float* de_gw=(const float*)d_in[26], *de_gb=(const float*)d_in[27];
  const float* cf_inw=(const float*)d_in[28], *cf_inb=(const float*)d_in[29];
  const float* cf_ow=(const float*)d_in[30], *cf_ob=(const float*)d_in[31];
  const float* cf_fw=(const float*)d_in[32], *cf_fb=(const float*)d_in[33];
  const float* hf_w1=(const float*)d_in[34], *hf_b1=(const float*)d_in[35];
  const float* hf_w2=(const float*)d_in[36], *hf_b2=(const float*)d_in[37];
  const float* tc_w=(const float*)d_in[38], *tc_b=(const float*)d_in[39];
  const float* tf_w=(const float*)d_in[40], *tf_b=(const float*)d_in[41];
  const float* lt_w1=(const float*)d_in[42], *lt_b1=(const float*)d_in[43];
  const float* lt_w2=(const float*)d_in[44], *lt_b2=(const float*)d_in[45];
  const float* op_w=(const float*)d_in[46], *op_b=(const float*)d_in[47];
  float* out=(float*)d_out;
  (void)in_sizes; (void)n_in; (void)out_size; (void)ws_size;

  constexpr int NB=8192;
  const size_t BD=(size_t)NB*1024;
  char* base=(char*)d_ws; size_t off=0;
  auto carve=[&](size_t n)->void*{ void* q=base+off; off+=(n+255)&~(size_t)255; return q; };
  float* comb =(float*)carve(BD*4);
  u16*  bufA =(u16*)carve(BD*2);
  u16*  bufB =(u16*)carve(BD*2);
  u16*  x_hi =(u16*)carve(BD*2);
  u16*  x_lo =(u16*)carve(BD*2);
  float* h512a=(float*)carve((size_t)NB*512*4);
  float* h512b=(float*)carve((size_t)NB*512*4);
  u16*  h256 =(u16*)carve((size_t)NB*256*2);
  // split routing weights
  u16* sw1h=(u16*)carve((size_t)512*1024*2);
  u16* sw1l=(u16*)carve((size_t)512*1024*2);
  u16* rw1h=(u16*)carve((size_t)512*1024*2);
  u16* rw1l=(u16*)carve((size_t)512*1024*2);
  // bf16 expert weights
  u16* spv_bf =(u16*)carve((size_t)1024*1024*2);
  u16* spo_bf =(u16*)carve((size_t)1024*1024*2);
  u16* spq1_bf=(u16*)carve((size_t)1024*1024*2);
  u16* spq2_bf=(u16*)carve((size_t)1024*1024*2);
  u16* dew1_bf=(u16*)carve((size_t)256*1024*2);
  u16* dew2_bf=(u16*)carve((size_t)1024*256*2);
  u16* degw_bf=(u16*)carve((size_t)1024*1024*2);
  u16* hfw1_bf=(u16*)carve((size_t)256*1024*2);
  u16* hfw2_bf=(u16*)carve((size_t)1024*256*2);
  u16* ltw1_bf=(u16*)carve((size_t)256*1024*2);
  u16* ltw2_bf=(u16*)carve((size_t)1024*256*2);
  u16* opw_bf =(u16*)carve((size_t)1024*1024*2);
  float* spec=(float*)carve((size_t)NB*6*4);
  float* probs=(float*)carve((size_t)NB*6*4);
  float* wsel=(float*)carve((size_t)NB*6*4);
  float* kvals=(float*)carve((size_t)NB*4);
  int*   kint=(int*)carve(256);

  const dim3 blk(256);
  const dim3 gEW(2048);
  auto cgrid=[&](int n4)->dim3{ int g=(n4+255)/256; return dim3(g>2048?2048:g); };

  // ---- conversions ----
  cvt_split<<<cgrid(2097152),blk,0,stream>>>(x, x_hi, x_lo, 2097152);
  cvt_split<<<cgrid(131072),blk,0,stream>>>(sim_w1, sw1h, sw1l, 131072);
  cvt_split_rw1<<<cgrid(131072),blk,0,stream>>>(rout_w1, rw1h, rw1l);
  cvt_kernel<<<cgrid(262144),blk,0,stream>>>(spv_w,  spv_bf, 262144);
  cvt_kernel<<<cgrid(262144),blk,0,stream>>>(spo_w,  spo_bf, 262144);
  cvt_kernel<<<cgrid(262144),blk,0,stream>>>(spq1_w, spq1_bf,262144);
  cvt_kernel<<<cgrid(262144),blk,0,stream>>>(spq2_w, spq2_bf,262144);
  cvt_kernel<<<cgrid(65536),blk,0,stream>>>(de_w1,  dew1_bf,65536);
  cvt_kernel<<<cgrid(65536),blk,0,stream>>>(de_w2,  dew2_bf,65536);
  cvt_kernel<<<cgrid(262144),blk,0,stream>>>(de_gw,  degw_bf,262144);
  cvt_kernel<<<cgrid(65536),blk,0,stream>>>(hf_w1,  hfw1_bf,65536);
  cvt_kernel<<<cgrid(65536),blk,0,stream>>>(hf_w2,  hfw2_bf,65536);
  cvt_kernel<<<cgrid(65536),blk,0,stream>>>(lt_w1,  ltw1_bf,65536);
  cvt_kernel<<<cgrid(65536),blk,0,stream>>>(lt_w2,  ltw2_bf,65536);
  cvt_kernel<<<cgrid(262144),blk,0,stream>>>(op_w,   opw_bf, 262144);

  // ---- routing pipeline (f32-accurate) ----
  feats_kernel<<<dim3(NB),blk,0,stream>>>(x, kw1,kb1,kw2,kb2, kvals);
  median_kernel<<<dim3(1),blk,0,stream>>>(kvals, kint);
  gemm_split<1><<<dim3(4,64),blk,0,stream>>>(x_hi,x_lo, sw1h,sw1l, sim_b1, h512a, NB,512,1024);
  spec_kernel<<<gEW,blk,0,stream>>>(x, h512a, esp, sim_w2, sim_b2, spec);
  gemm_split<0><<<dim3(4,64),blk,0,stream>>>(x_hi,x_lo, rw1h,rw1l, rout_b1, h512b, NB,512,1024);
  rout_fix<<<gEW,blk,0,stream>>>(h512b, spec, rout_w1);
  probs_kernel<<<gEW,blk,0,stream>>>(h512b, rout_w2, rout_b2, probs);
  gates_kernel<<<dim3(32),blk,0,stream>>>(probs, kint, wsel);

  // ---- expert 0: SparseQuadratic ----
  gemm_bt<0,false,false><<<dim3(8,64),blk,0,stream>>>(x_hi, spv_bf, spv_b, nullptr, bufA, NB,1024,1024);
  gemm_bt<0,false,false><<<dim3(8,64),blk,0,stream>>>(bufA, spo_bf, spo_b, nullptr, bufB, NB,1024,1024);
  mul_kernel<<<gEW,blk,0,stream>>>(bufB, x, bufA);
  gemm_bt<1,false,false><<<dim3(8,64),blk,0,stream>>>(bufA, spq1_bf, spq1_b, nullptr, bufB, NB,1024,1024);
  gemm_bt<0,false,false><<<dim3(8,64),blk,0,stream>>>(bufB, spq2_bf, spq2_b, nullptr, bufA, NB,1024,1024);
  acc_kernel<0><<<gEW,blk,0,stream>>>(comb, wsel, bufA, nullptr, nullptr);

  // ---- expert 1: DenseQuadratic ----
  gemm_bt<1,false,false><<<dim3(2,64),blk,0,stream>>>(x_hi, dew1_bf, de_b1, nullptr, h256, NB,256,1024);
  gemm_bt<0,false,false><<<dim3(8,64),blk,0,stream>>>(h256, dew2_bf, de_b2, nullptr, bufA, NB,1024,256);
  gemm_bt<2,false,false><<<dim3(8,64),blk,0,stream>>>(x_hi, degw_bf, de_gb, nullptr, bufB, NB,1024,1024);
  acc_kernel<1><<<gEW,blk,0,stream>>>(comb, wsel, bufA, bufB, x);

  // ---- expert 2: CrossField ----
  cf_kernel<<<dim3(NB),blk,0,stream>>>(x, cf_inw, cf_inb, cf_ow, cf_ob, cf_fw, cf_fb, bufA);
  acc_kernel<2><<<gEW,blk,0,stream>>>(comb, wsel, bufA, nullptr, nullptr);

  // ---- expert 3: HighFreq ----
  gemm_bt<3,false,false><<<dim3(2,64),blk,0,stream>>>(x_hi, hfw1_bf, hf_b1, nullptr, h256, NB,256,1024);
  gemm_bt<0,false,false><<<dim3(8,64),blk,0,stream>>>(h256, hfw2_bf, hf_b2, nullptr, bufA, NB,1024,256);
  acc_kernel<3><<<gEW,blk,0,stream>>>(comb, wsel, bufA, nullptr, x);

  // ---- expert 4: Temporal (fused) ----
  tp_kernel<<<dim3(NB),blk,0,stream>>>(x, wsel, comb, tc_w, tc_b, tf_w, tf_b);

  // ---- expert 5: LongTail ----
  gemm_bt<4,false,false><<<dim3(2,64),blk,0,stream>>>(x_hi, ltw1_bf, lt_b1, nullptr, h256, NB,256,1024);
  gemm_bt<0,false,false><<<dim3(8,64),blk,0,stream>>>(h256, ltw2_bf, lt_b2, nullptr, bufA, NB,1024,256);
  acc_kernel<5><<<gEW,blk,0,stream>>>(comb, wsel, bufA, nullptr, x);

  // ---- output projection + residual (f32 out) ----
  tobf16_kernel<<<gEW,blk,0,stream>>>(comb, bufB);
  gemm_bt<0,true,true><<<dim3(8,64),blk,0,stream>>>(bufB, opw_bf, op_b, x, out, NB,1024,1024);
}

// Round 6
// 959.673 us; speedup vs baseline: 1.7631x; 1.7631x over previous
//
#include <hip/hip_runtime.h>
#include <stdint.h>

typedef unsigned short u16;
typedef __attribute__((ext_vector_type(4))) float f32x4;
typedef __attribute__((ext_vector_type(4))) unsigned short u16x4;
typedef __attribute__((ext_vector_type(8))) short short8;

#define DEV static __device__ __forceinline__

DEV float bf2f(u16 u){ union{unsigned int i; float f;} v; v.i=((unsigned int)u)<<16; return v.f; }
DEV u16 f2bf(float f){ union{float f; unsigned int i;} v; v.f=f; unsigned int u=v.i;
  return (u16)((u + 0x7FFFu + ((u>>16)&1u))>>16); }
DEV float wred(float v){ for(int o=32;o;o>>=1) v += __shfl_xor(v,o); return v; }
DEV float wredmax(float v){ for(int o=32;o;o>>=1) v = fmaxf(v,__shfl_xor(v,o)); return v; }

DEV float actf(int ACT, float v){
  if(ACT==1) return v>0.f?v:0.f;
  if(ACT==2) return 1.f/(1.f+__expf(-v));
  if(ACT==3) return tanhf(v);
  if(ACT==4) return v>0.f?v:(__expf(v)-1.f);
  return v;
}

// ---------------- f32 -> bf16 conversion ----------------
__global__ void cvt_kernel(const float* __restrict__ s, u16* __restrict__ d, int n4){
  for(int i=blockIdx.x*blockDim.x+threadIdx.x; i<n4; i+=gridDim.x*blockDim.x){
    f32x4 v=((const f32x4*)s)[i];
    u16x4 o;
    #pragma unroll
    for(int j=0;j<4;++j) o[j]=f2bf(v[j]);
    ((u16x4*)d)[i]=o;
  }
}

// f32 -> (hi, lo) bf16 split
__global__ void cvt_split(const float* __restrict__ s, u16* __restrict__ hi, u16* __restrict__ lo, int n4){
  for(int i=blockIdx.x*blockDim.x+threadIdx.x; i<n4; i+=gridDim.x*blockDim.x){
    f32x4 v=((const f32x4*)s)[i];
    u16x4 h,l;
    #pragma unroll
    for(int j=0;j<4;++j){ h[j]=f2bf(v[j]); l[j]=f2bf(v[j]-bf2f(h[j])); }
    ((u16x4*)hi)[i]=h; ((u16x4*)lo)[i]=l;
  }
}

// pack+split rout_w1[:, :1024] (lda=1030 f32) into dense hi/lo 512x1024
__global__ void cvt_split_rw1(const float* __restrict__ src, u16* __restrict__ hi, u16* __restrict__ lo){
  for(int i=blockIdx.x*blockDim.x+threadIdx.x; i<512*1024; i+=gridDim.x*blockDim.x){
    int r=i>>10, c=i&1023;
    float v=src[(size_t)r*1030+c];
    u16 h=f2bf(v);
    hi[i]=h; lo[i]=f2bf(v-bf2f(h));
  }
}

// ---------------- GEMM: C = act(A @ W^T + bias) (+ res), bf16 in, f32 accum ------------
template<int ACT, bool RES, bool F32OUT>
__global__ __launch_bounds__(256) void gemm_bt(
    const u16* __restrict__ A, const u16* __restrict__ W,
    const float* __restrict__ bias, const float* __restrict__ res,
    void* __restrict__ Cv, int M, int N, int K)
{
  __shared__ __align__(16) u16 lA[128*64];
  __shared__ __align__(16) u16 lB[128*64];
  const int tid=threadIdx.x, lane=tid&63, wv=tid>>6;
  const int wr=wv>>1, wc=wv&1;
  const int bn=blockIdx.x*128, bm=blockIdx.y*128;
  f32x4 acc[4][4];
  #pragma unroll
  for(int m=0;m<4;++m){
    #pragma unroll
    for(int n=0;n<4;++n) acc[m][n]=(f32x4)0.f;
  }
  const int srow = wv*8 + (lane>>3);
  const int scol = (lane&7)*8;
  const int ldst = wv*8*64 + lane*8;
  for(int kt=0;kt<K;kt+=64){
    short8 ra[4], rb[4];
    #pragma unroll
    for(int i=0;i<4;++i){
      ra[i]=*(const short8*)(A + (size_t)(bm + i*32 + srow)*K + kt + scol);
      rb[i]=*(const short8*)(W + (size_t)(bn + i*32 + srow)*K + kt + scol);
    }
    __syncthreads();
    #pragma unroll
    for(int i=0;i<4;++i){
      *(short8*)&lA[i*32*64 + ldst] = ra[i];
      *(short8*)&lB[i*32*64 + ldst] = rb[i];
    }
    __syncthreads();
    #pragma unroll
    for(int kk=0;kk<2;++kk){
      const int fr=lane&15, kc=kk*32+(lane>>4)*8;
      short8 af[4], bfr[4];
      #pragma unroll
      for(int m=0;m<4;++m) af[m]=*(const short8*)&lA[(wr*64+m*16+fr)*64+kc];
      #pragma unroll
      for(int n=0;n<4;++n) bfr[n]=*(const short8*)&lB[(wc*64+n*16+fr)*64+kc];
      #pragma unroll
      for(int m=0;m<4;++m){
        #pragma unroll
        for(int n=0;n<4;++n)
          acc[m][n]=__builtin_amdgcn_mfma_f32_16x16x32_bf16(af[m],bfr[n],acc[m][n],0,0,0);
      }
    }
  }
  const int fr=lane&15, fq=lane>>4;
  #pragma unroll
  for(int m=0;m<4;++m){
    #pragma unroll
    for(int n=0;n<4;++n){
      const int col = bn + wc*64 + n*16 + fr;
      const float bv = bias[col];
      #pragma unroll
      for(int j=0;j<4;++j){
        const int row = bm + wr*64 + m*16 + fq*4 + j;
        float v = acc[m][n][j] + bv;
        v = actf(ACT, v);
        if(RES) v += res[(size_t)row*N+col];
        if(F32OUT) ((float*)Cv)[(size_t)row*N+col] = v;
        else       ((u16*)Cv)[(size_t)row*N+col] = f2bf(v);
      }
    }
  }
}

// ---------------- split-precision GEMM (f32-accurate): C = act(A@W^T + b), f32 out -----
template<int ACT>
__global__ __launch_bounds__(256) void gemm_split(
    const u16* __restrict__ Ah, const u16* __restrict__ Al,
    const u16* __restrict__ Wh, const u16* __restrict__ Wl,
    const float* __restrict__ bias, float* __restrict__ C, int M, int N, int K)
{
  const int LDL=40;
  __shared__ __align__(16) u16 lAh[128*40], lAl[128*40], lBh[128*40], lBl[128*40];
  const int tid=threadIdx.x, lane=tid&63, wv=tid>>6;
  const int wr=wv>>1, wc=wv&1;
  const int bn=blockIdx.x*128, bm=blockIdx.y*128;
  f32x4 acc[4][4];
  #pragma unroll
  for(int m=0;m<4;++m){
    #pragma unroll
    for(int n=0;n<4;++n) acc[m][n]=(f32x4)0.f;
  }
  const int srow=tid>>2, scol=(tid&3)*8;
  for(int kt=0;kt<K;kt+=32){
    short8 rah[2],ral[2],rbh[2],rbl[2];
    #pragma unroll
    for(int i=0;i<2;++i){
      size_t ao=(size_t)(bm+i*64+srow)*K+kt+scol;
      size_t bo=(size_t)(bn+i*64+srow)*K+kt+scol;
      rah[i]=*(const short8*)(Ah+ao); ral[i]=*(const short8*)(Al+ao);
      rbh[i]=*(const short8*)(Wh+bo); rbl[i]=*(const short8*)(Wl+bo);
    }
    __syncthreads();
    #pragma unroll
    for(int i=0;i<2;++i){
      int d=(i*64+srow)*LDL+scol;
      *(short8*)&lAh[d]=rah[i]; *(short8*)&lAl[d]=ral[i];
      *(short8*)&lBh[d]=rbh[i]; *(short8*)&lBl[d]=rbl[i];
    }
    __syncthreads();
    const int fr=lane&15, kc=(lane>>4)*8;
    short8 ah[4],al[4],bh[4],bl[4];
    #pragma unroll
    for(int m=0;m<4;++m){ int r=(wr*64+m*16+fr)*LDL+kc; ah[m]=*(const short8*)&lAh[r]; al[m]=*(const short8*)&lAl[r]; }
    #pragma unroll
    for(int n=0;n<4;++n){ int r=(wc*64+n*16+fr)*LDL+kc; bh[n]=*(const short8*)&lBh[r]; bl[n]=*(const short8*)&lBl[r]; }
    #pragma unroll
    for(int m=0;m<4;++m){
      #pragma unroll
      for(int n=0;n<4;++n){
        acc[m][n]=__builtin_amdgcn_mfma_f32_16x16x32_bf16(ah[m],bh[n],acc[m][n],0,0,0);
        acc[m][n]=__builtin_amdgcn_mfma_f32_16x16x32_bf16(ah[m],bl[n],acc[m][n],0,0,0);
        acc[m][n]=__builtin_amdgcn_mfma_f32_16x16x32_bf16(al[m],bh[n],acc[m][n],0,0,0);
        acc[m][n]=__builtin_amdgcn_mfma_f32_16x16x32_bf16(al[m],bl[n],acc[m][n],0,0,0);
      }
    }
  }
  const int fr=lane&15, fq=lane>>4;
  #pragma unroll
  for(int m=0;m<4;++m){
    #pragma unroll
    for(int n=0;n<4;++n){
      const int col = bn + wc*64 + n*16 + fr;
      const float bv = bias[col];
      #pragma unroll
      for(int j=0;j<4;++j){
        const int row = bm + wr*64 + m*16 + fq*4 + j;
        C[(size_t)row*N+col] = actf(ACT, acc[m][n][j] + bv);
      }
    }
  }
}

// ---------------- feature stats + kpred MLP -> k_vals[row] (all f32) ----------------
__global__ __launch_bounds__(256) void feats_kernel(const float* __restrict__ x,
    const float* __restrict__ kw1, const float* __restrict__ kb1,
    const float* __restrict__ kw2, const float* __restrict__ kb2,
    float* __restrict__ kvals)
{
  __shared__ float xs[1024];
  __shared__ unsigned int cd[1024];
  __shared__ float rbuf[4*6];
  __shared__ float r2[4], r3[4];
  __shared__ float bres[6];
  __shared__ int icnt;
  const int tid=threadIdx.x, lane=tid&63, wv=tid>>6;
  const int row=blockIdx.x;
  f32x4 u = ((const f32x4*)(x+(size_t)row*1024))[tid];
  float s=0.f, ss=0.f, amax=0.f, sa=0.f; float nz=0.f;
  #pragma unroll
  for(int j=0;j<4;++j){
    float f=u[j];
    union{float f;unsigned int i;} cv; cv.f=f;
    xs[4*tid+j]=f; cd[4*tid+j]=cv.i&0x7fffffffu;
    s+=f; ss+=f*f; float a=fabsf(f); sa+=a; amax=fmaxf(amax,a); if(f==0.f) nz+=1.f;
  }
  s=wred(s); ss=wred(ss); sa=wred(sa); nz=wred(nz); amax=wredmax(amax);
  if(lane==0){ rbuf[wv*6+0]=s; rbuf[wv*6+1]=ss; rbuf[wv*6+2]=sa; rbuf[wv*6+3]=nz; rbuf[wv*6+4]=amax; }
  __syncthreads();
  if(tid==0){
    float S=0,SS=0,SA=0,NZ=0,AM=0;
    for(int i=0;i<4;++i){ S+=rbuf[i*6]; SS+=rbuf[i*6+1]; SA+=rbuf[i*6+2]; NZ+=rbuf[i*6+3]; AM=fmaxf(AM,rbuf[i*6+4]); }
    bres[0]=S; bres[1]=SS; bres[2]=SA; bres[3]=NZ; bres[4]=AM;
  }
  __syncthreads();
  const float S=bres[0], SS=bres[1], SA=bres[2], NZ=bres[3], AM=bres[4];
  const float mean=S/1024.f;
  const float var=(SS - S*mean)/1023.f;
  const float inv=1.f/sqrtf(var+1e-8f);
  float sk=0.f;
  #pragma unroll
  for(int j=0;j<4;++j){ float z=(xs[4*tid+j]-mean)*inv; sk+=z*z*z; }
  sk=wred(sk);
  if(lane==0) rbuf[wv*6+5]=sk;
  unsigned int lo=0u, hi=0x7f800000u;
  while(hi-lo>1u){
    unsigned int mid=(lo+hi)>>1;
    if(tid==0) icnt=0;
    __syncthreads();
    int c0=0;
    #pragma unroll
    for(int j=0;j<4;++j) c0 += (cd[4*tid+j] >= mid);
    float cf=wred((float)c0);
    if(lane==0) atomicAdd(&icnt,(int)cf);
    __syncthreads();
    int cc=icnt;
    __syncthreads();
    if(cc>=204) lo=mid; else hi=mid;
  }
  float sg=0.f; float cg=0.f;
  #pragma unroll
  for(int j=0;j<4;++j){ if(cd[4*tid+j] > lo){ sg+=fabsf(xs[4*tid+j]); cg+=1.f; } }
  sg=wred(sg); cg=wred(cg);
  if(lane==0){ r2[wv]=sg; r3[wv]=cg; }
  __syncthreads();
  if(tid==0){
    float SK=rbuf[5]+rbuf[11]+rbuf[17]+rbuf[23];
    float SG=r2[0]+r2[1]+r2[2]+r2[3];
    float CG=r3[0]+r3[1]+r3[2]+r3[3];
    union{unsigned int i;float f;} tv; tv.i=lo;
    float conc=(SG + (204.f-CG)*tv.f)/(SA + 1e-8f);
    float feats[6]={ NZ/1024.f, var, AM, sqrtf(SS), SK/1024.f, conc };
    float out=kb2[0];
    #pragma unroll
    for(int i=0;i<16;++i){
      float hv=kb1[i];
      #pragma unroll
      for(int j=0;j<6;++j) hv+=kw1[i*6+j]*feats[j];
      hv=fmaxf(hv,0.f);
      out+=kw2[i]*hv;
    }
    kvals[row]=1.f + 3.f*(1.f/(1.f+__expf(-out)));
  }
}

// ---------------- exact median of 8192 -> k ----------------
__global__ __launch_bounds__(256) void median_kernel(const float* __restrict__ kvals, int* __restrict__ kint){
  __shared__ unsigned int v[8192];
  __shared__ int icnt;
  const int tid=threadIdx.x;
  for(int i=tid;i<8192;i+=256){ union{float f;unsigned int u;} c; c.f=kvals[i]; v[i]=c.u; }
  __syncthreads();
  unsigned int res[2];
  for(int t=0;t<2;++t){
    const int kth=4096+t;
    unsigned int lo=0u, hi=0xFFFFFFFFu;
    while(lo<hi){
      unsigned int mid=lo+((hi-lo)>>1);
      if(tid==0) icnt=0;
      __syncthreads();
      int c=0;
      for(int i=tid;i<8192;i+=256) c += (v[i] <= mid);
      float cf=wred((float)c);
      if((tid&63)==0) atomicAdd(&icnt,(int)cf);
      __syncthreads();
      int cc=icnt;
      __syncthreads();
      if(cc>=kth) hi=mid; else lo=mid+1u;
    }
    res[t]=lo;
  }
  if(tid==0){
    union{unsigned int u; float f;} a,b; a.u=res[0]; b.u=res[1];
    float med=0.5f*(a.f+b.f);
    int k=(int)floorf(med);
    k = k<1?1:(k>4?4:k);
    *kint=k;
  }
}

// ---------------- spec = sigmoid(x@esp^T + h512a@sim_w2^T + sim_b2), one wave/row ------
__global__ __launch_bounds__(256) void spec_kernel(const float* __restrict__ x, const float* __restrict__ h,
    const float* __restrict__ esp, const float* __restrict__ w2, const float* __restrict__ b2,
    float* __restrict__ spec){
  const int wv=threadIdx.x>>6, lane=threadIdx.x&63;
  const int row=blockIdx.x*4+wv;
  const float* xr=x+(size_t)row*1024;
  const float* hr=h+(size_t)row*512;
  float xv[16], hv[8];
  #pragma unroll
  for(int j=0;j<16;++j) xv[j]=xr[j*64+lane];
  #pragma unroll
  for(int j=0;j<8;++j) hv[j]=hr[j*64+lane];
  for(int e=0;e<6;++e){
    float s=0.f;
    #pragma unroll
    for(int j=0;j<16;++j) s+=xv[j]*esp[e*1024+j*64+lane];
    #pragma unroll
    for(int j=0;j<8;++j) s+=hv[j]*w2[e*512+j*64+lane];
    s=wred(s);
    if(lane==0) spec[row*6+e]=1.f/(1.f+__expf(-(s+b2[e])));
  }
}

// ---------------- rout pre-act += spec @ rw1[:,1024:]^T, relu (f32 h) ----------------
__global__ void rout_fix(float* __restrict__ h, const float* __restrict__ spec, const float* __restrict__ rw1){
  const int total=8192*128;
  for(int i=blockIdx.x*blockDim.x+threadIdx.x;i<total;i+=gridDim.x*blockDim.x){
    int row=i>>7, j0=(i&127)*4;
    const float* sp=&spec[row*6];
    f32x4 hv=((f32x4*)h)[i];
    #pragma unroll
    for(int j=0;j<4;++j){
      float v=hv[j];
      int col=j0+j;
      #pragma unroll
      for(int e=0;e<6;++e) v+=sp[e]*rw1[(size_t)col*1030+1024+e];
      hv[j]=fmaxf(v,0.f);
    }
    ((f32x4*)h)[i]=hv;
  }
}

// ---------------- probs = softmax(h512b@rout_w2^T + rout_b2), one wave per row ----------
__global__ __launch_bounds__(256) void probs_kernel(const float* __restrict__ h, const float* __restrict__ w2,
    const float* __restrict__ b2, float* __restrict__ probs){
  const int wv=threadIdx.x>>6, lane=threadIdx.x&63;
  const int row=blockIdx.x*4+wv;
  const float* hr=h+(size_t)row*512;
  float hv[8];
  #pragma unroll
  for(int j=0;j<8;++j) hv[j]=hr[j*64+lane];
  float lg[6];
  #pragma unroll
  for(int e=0;e<6;++e){
    float s=0.f;
    #pragma unroll
    for(int j=0;j<8;++j) s+=hv[j]*w2[e*512+j*64+lane];
    lg[e]=wred(s)+b2[e];
  }
  if(lane==0){
    float m=lg[0];
    #pragma unroll
    for(int e=1;e<6;++e) m=fmaxf(m,lg[e]);
    float den=0.f, ex[6];
    #pragma unroll
    for(int e=0;e<6;++e){ ex[e]=__expf(lg[e]-m); den+=ex[e]; }
    #pragma unroll
    for(int e=0;e<6;++e) probs[row*6+e]=ex[e]/den;
  }
}

// ---------------- top-4 + gates -> per-expert weights ----------------
__global__ void gates_kernel(const float* __restrict__ probs, const int* __restrict__ kint,
                             float* __restrict__ wsel){
  const int r=blockIdx.x*blockDim.x+threadIdx.x;
  if(r>=8192) return;
  const int k=*kint;
  float p[6];
  #pragma unroll
  for(int e=0;e<6;++e) p[e]=probs[r*6+e];
  float w[6]={0,0,0,0,0,0};
  bool used[6]={false,false,false,false,false,false};
  int idx[4]; float val[4];
  #pragma unroll
  for(int j=0;j<4;++j){
    int bi=0; float bv=-1e30f;
    #pragma unroll
    for(int e=0;e<6;++e) if(!used[e] && p[e]>bv){ bv=p[e]; bi=e; }
    used[bi]=true; idx[j]=bi; val[j]=bv;
  }
  float m=val[0], den=0.f, g[4]={0,0,0,0};
  for(int j=0;j<k;++j){ g[j]=__expf(val[j]-m); den+=g[j]; }
  for(int j=0;j<k;++j) w[idx[j]]=g[j]/den;
  #pragma unroll
  for(int e=0;e<6;++e) wsel[r*6+e]=w[e];
}

// ---------------- att*x elementwise ----------------
__global__ void mul_kernel(const u16* __restrict__ a, const float* __restrict__ x, u16* __restrict__ o){
  const int total=8192*256;
  for(int i=blockIdx.x*blockDim.x+threadIdx.x;i<total;i+=gridDim.x*blockDim.x){
    u16x4 av=((const u16x4*)a)[i];
    f32x4 xv=((const f32x4*)x)[i];
    u16x4 ov;
    #pragma unroll
    for(int j=0;j<4;++j) ov[j]=f2bf(bf2f(av[j])*xv[j]);
    ((u16x4*)o)[i]=ov;
  }
}

// MODE 0: comb  = w0*p0; MODE 1: comb += w1*(p0 + p1*x); MODE 3: comb += w3*(x+(p0-x)*x)
// MODE 5: comb += w5*sign(x)*sqrt(|p0*x|+1e-8)
template<int MODE>
__global__ void acc_kernel(float* __restrict__ comb, const float* __restrict__ wsel,
    const u16* __restrict__ p0, const u16* __restrict__ p1, const float* __restrict__ xf){
  const int total=8192*256;
  const int widx = (MODE==5)?5:MODE;
  f32x4* c4=(f32x4*)comb;
  for(int i=blockIdx.x*blockDim.x+threadIdx.x;i<total;i+=gridDim.x*blockDim.x){
    const int row=i>>8;
    const float w=wsel[row*6+widx];
    u16x4 a=((const u16x4*)p0)[i];
    f32x4 r;
    if(MODE==0){
      #pragma unroll
      for(int j=0;j<4;++j) r[j]=w*bf2f(a[j]);
    } else if(MODE==1){
      u16x4 g=((const u16x4*)p1)[i];
      f32x4 xv=((const f32x4*)xf)[i];
      r=c4[i];
      #pragma unroll
      for(int j=0;j<4;++j) r[j]+=w*(bf2f(a[j]) + bf2f(g[j])*xv[j]);
    } else if(MODE==3){
      f32x4 xv=((const f32x4*)xf)[i];
      r=c4[i];
      #pragma unroll
      for(int j=0;j<4;++j){ float x0=xv[j]; float fl=bf2f(a[j]); r[j]+=w*(x0+(fl-x0)*x0); }
    } else {
      f32x4 xv=((const f32x4*)xf)[i];
      r=c4[i];
      #pragma unroll
      for(int j=0;j<4;++j){
        float x0=xv[j]; float t=bf2f(a[j]);
        float sgn=(x0>0.f)?1.f:((x0<0.f)?-1.f:0.f);
        r[j]+=w*sgn*sqrtf(fabsf(t*x0)+1e-8f);
      }
    }
    c4[i]=r;
  }
}

__global__ void tobf16_kernel(const float* __restrict__ c, u16* __restrict__ o){
  const int total=8192*256;
  for(int i=blockIdx.x*blockDim.x+threadIdx.x;i<total;i+=gridDim.x*blockDim.x){
    f32x4 cv=((const f32x4*)c)[i];
    u16x4 ov;
    #pragma unroll
    for(int j=0;j<4;++j) ov[j]=f2bf(cv[j]);
    ((u16x4*)o)[i]=ov;
  }
}

// ---------------- CrossField expert: conflict-free LDS, fused accumulate ----------------
// comb += w2 * ((softmax(q@k^T/sqrt(32)) @ v @ w_o^T + b_o) * xf) @ w_f^T + b_f
__global__ __launch_bounds__(256) void cf_kernel(const float* __restrict__ x,
    const float* __restrict__ w_in, const float* __restrict__ b_in,
    const float* __restrict__ w_o, const float* __restrict__ b_o,
    const float* __restrict__ w_f, const float* __restrict__ b_f,
    const float* __restrict__ wsel, float* __restrict__ comb){
  __shared__ float xf[1024];
  __shared__ float qkv[32*97];     // stride 97: bank-conflict-free strided reads
  __shared__ float sc[32*33+32];   // scores rows stride 33; later reused linearly for prod
  __shared__ float av[1024];
  __shared__ float win_l[96*33];   // weights staged, stride 33
  __shared__ float wo_l[32*33];
  __shared__ float wf_l[32*33];
  const int row=blockIdx.x, tid=threadIdx.x;
  // stage weights (coalesced global, padded LDS)
  for(int i=tid;i<3072;i+=256) win_l[(i>>5)*33+(i&31)]=w_in[i];
  for(int i=tid;i<1024;i+=256){ wo_l[(i>>5)*33+(i&31)]=w_o[i]; wf_l[(i>>5)*33+(i&31)]=w_f[i]; }
  f32x4 u=((const f32x4*)(x+(size_t)row*1024))[tid];
  #pragma unroll
  for(int j=0;j<4;++j) xf[4*tid+j]=u[j];
  __syncthreads();
  // qkv: 32 fields x 96 outputs
  #pragma unroll
  for(int t=0;t<12;++t){
    int oi=t*256+tid; int f=oi/96, c=oi-96*f;
    float s=b_in[c];
    const float* wr=&win_l[c*33];
    const float* xr=&xf[f*32];
    #pragma unroll
    for(int d=0;d<32;++d) s+=xr[d]*wr[d];
    qkv[f*97+c]=s;
  }
  __syncthreads();
  const float scale=0.17677669529663687f; // 1/sqrt(32)
  #pragma unroll
  for(int t=0;t<4;++t){
    int oi=t*256+tid; int q=oi>>5, kq=oi&31;
    float s=0.f;
    #pragma unroll
    for(int d=0;d<32;++d) s+=qkv[q*97+d]*qkv[kq*97+32+d];
    sc[q*33+kq]=s*scale;
  }
  __syncthreads();
  // wave-parallel softmax: 8 lanes per row
  {
    const int r=tid>>3, sub=tid&7;
    float v0[4];
    float m=-1e30f;
    #pragma unroll
    for(int jj=0;jj<4;++jj){ v0[jj]=sc[r*33+sub*4+jj]; m=fmaxf(m,v0[jj]); }
    #pragma unroll
    for(int o=1;o<8;o<<=1) m=fmaxf(m,__shfl_xor(m,o));
    float den=0.f;
    #pragma unroll
    for(int jj=0;jj<4;++jj){ v0[jj]=__expf(v0[jj]-m); den+=v0[jj]; }
    #pragma unroll
    for(int o=1;o<8;o<<=1) den+=__shfl_xor(den,o);
    float inv=1.f/den;
    #pragma unroll
    for(int jj=0;jj<4;++jj) sc[r*33+sub*4+jj]=v0[jj]*inv;
  }
  __syncthreads();
  // att = P @ v
  #pragma unroll
  for(int t=0;t<4;++t){
    int oi=t*256+tid; int q=oi>>5, d=oi&31;
    float s=0.f;
    #pragma unroll
    for(int k=0;k<32;++k) s+=sc[q*33+k]*qkv[k*97+64+d];
    av[oi]=s;
  }
  __syncthreads();
  // attf = att @ w_o^T + b_o ; prod = attf * xf (store into sc linearly)
  #pragma unroll
  for(int t=0;t<4;++t){
    int oi=t*256+tid; int q=oi>>5, d=oi&31;
    float s=b_o[d];
    #pragma unroll
    for(int c=0;c<32;++c) s+=av[q*32+c]*wo_l[d*33+c];
    sc[oi]=s*xf[oi];
  }
  __syncthreads();
  const float w2=wsel[row*6+2];
  #pragma unroll
  for(int t=0;t<4;++t){
    int oi=t*256+tid; int q=oi>>5, d=oi&31;
    float s=b_f[d];
    #pragma unroll
    for(int c=0;c<32;++c) s+=sc[q*32+c]*wf_l[d*33+c];
    comb[(size_t)row*1024+oi]+=w2*s;
  }
}

// ---------------- Temporal expert: conv1d(k=3,pad=1,4ch) gate, fused accumulate --------
__global__ __launch_bounds__(256) void tp_kernel(const float* __restrict__ x,
    const float* __restrict__ wsel, float* __restrict__ comb,
    const float* __restrict__ tcw, const float* __restrict__ tcb,
    const float* __restrict__ tfw, const float* __restrict__ tfb){
  __shared__ float xs[1026];
  const int row=blockIdx.x, tid=threadIdx.x;
  f32x4 u=((const f32x4*)(x+(size_t)row*1024))[tid];
  #pragma unroll
  for(int j=0;j<4;++j) xs[1+4*tid+j]=u[j];
  if(tid==0){ xs[0]=0.f; xs[1025]=0.f; }
  __syncthreads();
  const float w4=wsel[row*6+4];
  float tc[4][3], tb[4], tf[4];
  #pragma unroll
  for(int o=0;o<4;++o){
    #pragma unroll
    for(int kh=0;kh<3;++kh) tc[o][kh]=tcw[o*3+kh];
    tb[o]=tcb[o]; tf[o]=tfw[o];
  }
  const float tfb0=tfb[0];
  #pragma unroll
  for(int j=0;j<4;++j){
    const int d=4*tid+j;
    float pre=tfb0;
    #pragma unroll
    for(int o=0;o<4;++o){
      float cv=tb[o]+tc[o][0]*xs[d]+tc[o][1]*xs[d+1]+tc[o][2]*xs[d+2];
      pre+=tf[o]*fmaxf(cv,0.f);
    }
    float wt=1.f/(1.f+__expf(-pre));
    float xv=xs[1+d];
    comb[(size_t)row*1024+d]+=w4*xv*xv*wt;
  }
}

// =======================================================================================
extern "C" void kernel_launch(void* const* d_in, const int* in_sizes, int n_in,
                              void* d_out, int out_size, void* d_ws, size_t ws_size,
                              hipStream_t stream)
{
  const float* x     =(const float*)d_in[0];
  const float* esp   =(const float*)d_in[1];
  const float* sim_w1=(const float*)d_in[2],  *sim_b1=(const float*)d_in[3];
  const float* sim_w2=(const float*)d_in[4],  *sim_b2=(const float*)d_in[5];
  const float* rout_w1=(const float*)d_in[6], *rout_b1=(const float*)d_in[7];
  const float* rout_w2=(const float*)d_in[8], *rout_b2=(const float*)d_in[9];
  const float* kw1=(const float*)d_in[10], *kb1=(const float*)d_in[11];
  const float* kw2=(const float*)d_in[12], *kb2=(const float*)d_in[13];
  const float* spv_w=(const float*)d_in[14], *spv_b=(const float*)d_in[15];
  const float* spo_w=(const float*)d_in[16], *spo_b=(const float*)d_in[17];
  const float* spq1_w=(const float*)d_in[18], *spq1_b=(const float*)d_in[19];
  const float* spq2_w=(const float*)d_in[20], *spq2_b=(const float*)d_in[21];
  const float* de_w1=(const float*)d_in[22], *de_b1=(const float*)d_in[23];
  const float* de_w2=(const float*)d_in[24], *de_b2=(const float*)d_in[25];
  const float* de_gw=(const float*)d_in[26], *de_gb=(const float*)d_in[27];
  const float* cf_inw=(const float*)d_in[28], *cf_inb=(const float*)d_in[29];
  const float* cf_ow=(const float*)d_in[30], *cf_ob=(const float*)d_in[31];
  const float* cf_fw=(const float*)d_in[32], *cf_fb=(const float*)d_in[33];
  const float* hf_w1=(const float*)d_in[34], *hf_b1=(const float*)d_in[35];
  const float* hf_w2=(const float*)d_in[36], *hf_b2=(const float*)d_in[37];
  const float* tc_w=(const float*)d_in[38], *tc_b=(const float*)d_in[39];
  const float* tf_w=(const float*)d_in[40], *tf_b=(const float*)d_in[41];
  const float* lt_w1=(const float*)d_in[42], *lt_b1=(const float*)d_in[43];
  const float* lt_w2=(const float*)d_in[44], *lt_b2=(const float*)d_in[45];
  const float* op_w=(const float*)d_in[46], *op_b=(const float*)d_in[47];
  float* out=(float*)d_out;
  (void)in_sizes; (void)n_in; (void)out_size; (void)ws_size;

  constexpr int NB=8192;
  const size_t BD=(size_t)NB*1024;
  char* base=(char*)d_ws; size_t off=0;
  auto carve=[&](size_t n)->void*{ void* q=base+off; off+=(n+255)&~(size_t)255; return q; };
  float* comb =(float*)carve(BD*4);
  u16*  bufA =(u16*)carve(BD*2);
  u16*  bufB =(u16*)carve(BD*2);
  u16*  x_hi =(u16*)carve(BD*2);
  u16*  x_lo =(u16*)carve(BD*2);
  float* h512a=(float*)carve((size_t)NB*512*4);
  float* h512b=(float*)carve((size_t)NB*512*4);
  u16*  h256 =(u16*)carve((size_t)NB*256*2);
  u16* sw1h=(u16*)carve((size_t)512*1024*2);
  u16* sw1l=(u16*)carve((size_t)512*1024*2);
  u16* rw1h=(u16*)carve((size_t)512*1024*2);
  u16* rw1l=(u16*)carve((size_t)512*1024*2);
  u16* spv_bf =(u16*)carve((size_t)1024*1024*2);
  u16* spo_bf =(u16*)carve((size_t)1024*1024*2);
  u16* spq1_bf=(u16*)carve((size_t)1024*1024*2);
  u16* spq2_bf=(u16*)carve((size_t)1024*1024*2);
  u16* dew1_bf=(u16*)carve((size_t)256*1024*2);
  u16* dew2_bf=(u16*)carve((size_t)1024*256*2);
  u16* degw_bf=(u16*)carve((size_t)1024*1024*2);
  u16* hfw1_bf=(u16*)carve((size_t)256*1024*2);
  u16* hfw2_bf=(u16*)carve((size_t)1024*256*2);
  u16* ltw1_bf=(u16*)carve((size_t)256*1024*2);
  u16* ltw2_bf=(u16*)carve((size_t)1024*256*2);
  u16* opw_bf =(u16*)carve((size_t)1024*1024*2);
  float* spec=(float*)carve((size_t)NB*6*4);
  float* probs=(float*)carve((size_t)NB*6*4);
  float* wsel=(float*)carve((size_t)NB*6*4);
  float* kvals=(float*)carve((size_t)NB*4);
  int*   kint=(int*)carve(256);

  const dim3 blk(256);
  const dim3 gEW(2048);
  auto cgrid=[&](int n4)->dim3{ int g=(n4+255)/256; return dim3(g>2048?2048:g); };

  // ---- conversions ----
  cvt_split<<<cgrid(2097152),blk,0,stream>>>(x, x_hi, x_lo, 2097152);
  cvt_split<<<cgrid(131072),blk,0,stream>>>(sim_w1, sw1h, sw1l, 131072);
  cvt_split_rw1<<<cgrid(131072),blk,0,stream>>>(rout_w1, rw1h, rw1l);
  cvt_kernel<<<cgrid(262144),blk,0,stream>>>(spv_w,  spv_bf, 262144);
  cvt_kernel<<<cgrid(262144),blk,0,stream>>>(spo_w,  spo_bf, 262144);
  cvt_kernel<<<cgrid(262144),blk,0,stream>>>(spq1_w, spq1_bf,262144);
  cvt_kernel<<<cgrid(262144),blk,0,stream>>>(spq2_w, spq2_bf,262144);
  cvt_kernel<<<cgrid(65536),blk,0,stream>>>(de_w1,  dew1_bf,65536);
  cvt_kernel<<<cgrid(65536),blk,0,stream>>>(de_w2,  dew2_bf,65536);
  cvt_kernel<<<cgrid(262144),blk,0,stream>>>(de_gw,  degw_bf,262144);
  cvt_kernel<<<cgrid(65536),blk,0,stream>>>(hf_w1,  hfw1_bf,65536);
  cvt_kernel<<<cgrid(65536),blk,0,stream>>>(hf_w2,  hfw2_bf,65536);
  cvt_kernel<<<cgrid(65536),blk,0,stream>>>(lt_w1,  ltw1_bf,65536);
  cvt_kernel<<<cgrid(65536),blk,0,stream>>>(lt_w2,  ltw2_bf,65536);
  cvt_kernel<<<cgrid(262144),blk,0,stream>>>(op_w,   opw_bf, 262144);

  // ---- routing pipeline (f32-accurate) ----
  feats_kernel<<<dim3(NB),blk,0,stream>>>(x, kw1,kb1,kw2,kb2, kvals);
  median_kernel<<<dim3(1),blk,0,stream>>>(kvals, kint);
  gemm_split<1><<<dim3(4,64),blk,0,stream>>>(x_hi,x_lo, sw1h,sw1l, sim_b1, h512a, NB,512,1024);
  spec_kernel<<<gEW,blk,0,stream>>>(x, h512a, esp, sim_w2, sim_b2, spec);
  gemm_split<0><<<dim3(4,64),blk,0,stream>>>(x_hi,x_lo, rw1h,rw1l, rout_b1, h512b, NB,512,1024);
  rout_fix<<<gEW,blk,0,stream>>>(h512b, spec, rout_w1);
  probs_kernel<<<gEW,blk,0,stream>>>(h512b, rout_w2, rout_b2, probs);
  gates_kernel<<<dim3(32),blk,0,stream>>>(probs, kint, wsel);

  // ---- expert 0: SparseQuadratic ----
  gemm_bt<0,false,false><<<dim3(8,64),blk,0,stream>>>(x_hi, spv_bf, spv_b, nullptr, bufA, NB,1024,1024);
  gemm_bt<0,false,false><<<dim3(8,64),blk,0,stream>>>(bufA, spo_bf, spo_b, nullptr, bufB, NB,1024,1024);
  mul_kernel<<<gEW,blk,0,stream>>>(bufB, x, bufA);
  gemm_bt<1,false,false><<<dim3(8,64),blk,0,stream>>>(bufA, spq1_bf, spq1_b, nullptr, bufB, NB,1024,1024);
  gemm_bt<0,false,false><<<dim3(8,64),blk,0,stream>>>(bufB, spq2_bf, spq2_b, nullptr, bufA, NB,1024,1024);
  acc_kernel<0><<<gEW,blk,0,stream>>>(comb, wsel, bufA, nullptr, nullptr);

  // ---- expert 1: DenseQuadratic ----
  gemm_bt<1,false,false><<<dim3(2,64),blk,0,stream>>>(x_hi, dew1_bf, de_b1, nullptr, h256, NB,256,1024);
  gemm_bt<0,false,false><<<dim3(8,64),blk,0,stream>>>(h256, dew2_bf, de_b2, nullptr, bufA, NB,1024,256);
  gemm_bt<2,false,false><<<dim3(8,64),blk,0,stream>>>(x_hi, degw_bf, de_gb, nullptr, bufB, NB,1024,1024);
  acc_kernel<1><<<gEW,blk,0,stream>>>(comb, wsel, bufA, bufB, x);

  // ---- expert 2: CrossField (fused accumulate) ----
  cf_kernel<<<dim3(NB),blk,0,stream>>>(x, cf_inw, cf_inb, cf_ow, cf_ob, cf_fw, cf_fb, wsel, comb);

  // ---- expert 3: HighFreq ----
  gemm_bt<3,false,false><<<dim3(2,64),blk,0,stream>>>(x_hi, hfw1_bf, hf_b1, nullptr, h256, NB,256,1024);
  gemm_bt<0,false,false><<<dim3(8,64),blk,0,stream>>>(h256, hfw2_bf, hf_b2, nullptr, bufA, NB,1024,256);
  acc_kernel<3><<<gEW,blk,0,stream>>>(comb, wsel, bufA, nullptr, x);

  // ---- expert 4: Temporal (fused) ----
  tp_kernel<<<dim3(NB),blk,0,stream>>>(x, wsel, comb, tc_w, tc_b, tf_w, tf_b);

  // ---- expert 5: LongTail ----
  gemm_bt<4,false,false><<<dim3(2,64),blk,0,stream>>>(x_hi, ltw1_bf, lt_b1, nullptr, h256, NB,256,1024);
  gemm_bt<0,false,false><<<dim3(8,64),blk,0,stream>>>(h256, ltw2_bf, lt_b2, nullptr, bufA, NB,1024,256);
  acc_kernel<5><<<gEW,blk,0,stream>>>(comb, wsel, bufA, nullptr, x);

  // ---- output projection + residual (f32 out) ----
  tobf16_kernel<<<gEW,blk,0,stream>>>(comb, bufB);
  gemm_bt<0,true,true><<<dim3(8,64),blk,0,stream>>>(bufB, opw_bf, op_b, x, out, NB,1024,1024);
}

// Round 7
// 894.190 us; speedup vs baseline: 1.8922x; 1.0732x over previous
//
#include <hip/hip_runtime.h>
#include <stdint.h>

typedef unsigned short u16;
typedef __attribute__((ext_vector_type(2))) float f32x2;
typedef __attribute__((ext_vector_type(4))) float f32x4;
typedef __attribute__((ext_vector_type(4))) unsigned short u16x4;
typedef __attribute__((ext_vector_type(8))) short short8;

#define DEV static __device__ __forceinline__

DEV float bf2f(u16 u){ union{unsigned int i; float f;} v; v.i=((unsigned int)u)<<16; return v.f; }
DEV u16 f2bf(float f){ union{float f; unsigned int i;} v; v.f=f; unsigned int u=v.i;
  return (u16)((u + 0x7FFFu + ((u>>16)&1u))>>16); }
DEV float wred(float v){ for(int o=32;o;o>>=1) v += __shfl_xor(v,o); return v; }
DEV float wredmax(float v){ for(int o=32;o;o>>=1) v = fmaxf(v,__shfl_xor(v,o)); return v; }

DEV float actf(int ACT, float v){
  if(ACT==1) return v>0.f?v:0.f;
  if(ACT==2) return 1.f/(1.f+__expf(-v));
  if(ACT==3) return tanhf(v);
  if(ACT==4) return v>0.f?v:(__expf(v)-1.f);
  return v;
}

// ---------------- f32 -> bf16 conversion ----------------
__global__ void cvt_kernel(const float* __restrict__ s, u16* __restrict__ d, int n4){
  for(int i=blockIdx.x*blockDim.x+threadIdx.x; i<n4; i+=gridDim.x*blockDim.x){
    f32x4 v=((const f32x4*)s)[i];
    u16x4 o;
    #pragma unroll
    for(int j=0;j<4;++j) o[j]=f2bf(v[j]);
    ((u16x4*)d)[i]=o;
  }
}

// f32 -> (hi, lo) bf16 split
__global__ void cvt_split(const float* __restrict__ s, u16* __restrict__ hi, u16* __restrict__ lo, int n4){
  for(int i=blockIdx.x*blockDim.x+threadIdx.x; i<n4; i+=gridDim.x*blockDim.x){
    f32x4 v=((const f32x4*)s)[i];
    u16x4 h,l;
    #pragma unroll
    for(int j=0;j<4;++j){ h[j]=f2bf(v[j]); l[j]=f2bf(v[j]-bf2f(h[j])); }
    ((u16x4*)hi)[i]=h; ((u16x4*)lo)[i]=l;
  }
}

// pack+split rout_w1[:, :1024] (lda=1030 f32) into dense hi/lo 512x1024
__global__ void cvt_split_rw1(const float* __restrict__ src, u16* __restrict__ hi, u16* __restrict__ lo){
  for(int i=blockIdx.x*blockDim.x+threadIdx.x; i<512*1024; i+=gridDim.x*blockDim.x){
    int r=i>>10, c=i&1023;
    float v=src[(size_t)r*1030+c];
    u16 h=f2bf(v);
    hi[i]=h; lo[i]=f2bf(v-bf2f(h));
  }
}

// ---------------- GEMM: fused epilogues --------------------------------------------------
// EPI 0: C bf16 = v           1: C f32 = v        2: C bf16 = v*xf      (spo: att*x)
//     3: comb  = w[0]*v       4: comb += w[1]*(v + gate*xf)             (de2)
//     5: comb += w[3]*(xf + (v-xf)*xf)            6: comb += w[5]*sgn(xf)*sqrt(|v*xf|+1e-8)
//     7: C f32 = v + xf (residual)
template<int ACT, int EPI>
__global__ __launch_bounds__(256) void gemm_bt(
    const u16* __restrict__ A, const u16* __restrict__ W,
    const float* __restrict__ bias, const u16* __restrict__ auxb,
    const float* __restrict__ auxf, const float* __restrict__ wsel,
    float* __restrict__ comb, void* __restrict__ Cv, int M, int N, int K)
{
  __shared__ __align__(16) u16 lA[128*64];
  __shared__ __align__(16) u16 lB[128*64];
  const int tid=threadIdx.x, lane=tid&63, wv=tid>>6;
  const int wr=wv>>1, wc=wv&1;
  const int bn=blockIdx.x*128, bm=blockIdx.y*128;
  f32x4 acc[4][4];
  #pragma unroll
  for(int m=0;m<4;++m){
    #pragma unroll
    for(int n=0;n<4;++n) acc[m][n]=(f32x4)0.f;
  }
  const int srow = wv*8 + (lane>>3);
  const int scol = (lane&7)*8;
  const int ldst = wv*8*64 + lane*8;
  for(int kt=0;kt<K;kt+=64){
    short8 ra[4], rb[4];
    #pragma unroll
    for(int i=0;i<4;++i){
      ra[i]=*(const short8*)(A + (size_t)(bm + i*32 + srow)*K + kt + scol);
      rb[i]=*(const short8*)(W + (size_t)(bn + i*32 + srow)*K + kt + scol);
    }
    __syncthreads();
    #pragma unroll
    for(int i=0;i<4;++i){
      *(short8*)&lA[i*32*64 + ldst] = ra[i];
      *(short8*)&lB[i*32*64 + ldst] = rb[i];
    }
    __syncthreads();
    #pragma unroll
    for(int kk=0;kk<2;++kk){
      const int fr=lane&15, kc=kk*32+(lane>>4)*8;
      short8 af[4], bfr[4];
      #pragma unroll
      for(int m=0;m<4;++m) af[m]=*(const short8*)&lA[(wr*64+m*16+fr)*64+kc];
      #pragma unroll
      for(int n=0;n<4;++n) bfr[n]=*(const short8*)&lB[(wc*64+n*16+fr)*64+kc];
      #pragma unroll
      for(int m=0;m<4;++m){
        #pragma unroll
        for(int n=0;n<4;++n)
          acc[m][n]=__builtin_amdgcn_mfma_f32_16x16x32_bf16(af[m],bfr[n],acc[m][n],0,0,0);
      }
    }
  }
  const int fr=lane&15, fq=lane>>4;
  #pragma unroll
  for(int m=0;m<4;++m){
    #pragma unroll
    for(int n=0;n<4;++n){
      const int col = bn + wc*64 + n*16 + fr;
      const float bv = bias[col];
      #pragma unroll
      for(int j=0;j<4;++j){
        const int row = bm + wr*64 + m*16 + fq*4 + j;
        const size_t idx = (size_t)row*N+col;
        float v = acc[m][n][j] + bv;
        v = actf(ACT, v);
        if(EPI==0){ ((u16*)Cv)[idx]=f2bf(v); }
        else if(EPI==1){ ((float*)Cv)[idx]=v; }
        else if(EPI==2){ ((u16*)Cv)[idx]=f2bf(v*auxf[idx]); }
        else if(EPI==3){ comb[idx]=wsel[row*6+0]*v; }
        else if(EPI==4){ comb[idx]+=wsel[row*6+1]*(v + bf2f(auxb[idx])*auxf[idx]); }
        else if(EPI==5){ float x0=auxf[idx]; comb[idx]+=wsel[row*6+3]*(x0+(v-x0)*x0); }
        else if(EPI==6){
          float x0=auxf[idx];
          float sg=(x0>0.f)?1.f:((x0<0.f)?-1.f:0.f);
          comb[idx]+=wsel[row*6+5]*sg*sqrtf(fabsf(v*x0)+1e-8f);
        }
        else { ((float*)Cv)[idx]=v+auxf[idx]; }
      }
    }
  }
}

// ---------------- split-precision GEMM (f32-accurate): C = act(A@W^T + b), f32 out -----
template<int ACT>
__global__ __launch_bounds__(256) void gemm_split(
    const u16* __restrict__ Ah, const u16* __restrict__ Al,
    const u16* __restrict__ Wh, const u16* __restrict__ Wl,
    const float* __restrict__ bias, float* __restrict__ C, int M, int N, int K)
{
  const int LDL=40;
  __shared__ __align__(16) u16 lAh[128*40], lAl[128*40], lBh[128*40], lBl[128*40];
  const int tid=threadIdx.x, lane=tid&63, wv=tid>>6;
  const int wr=wv>>1, wc=wv&1;
  const int bn=blockIdx.x*128, bm=blockIdx.y*128;
  f32x4 acc[4][4];
  #pragma unroll
  for(int m=0;m<4;++m){
    #pragma unroll
    for(int n=0;n<4;++n) acc[m][n]=(f32x4)0.f;
  }
  const int srow=tid>>2, scol=(tid&3)*8;
  for(int kt=0;kt<K;kt+=32){
    short8 rah[2],ral[2],rbh[2],rbl[2];
    #pragma unroll
    for(int i=0;i<2;++i){
      size_t ao=(size_t)(bm+i*64+srow)*K+kt+scol;
      size_t bo=(size_t)(bn+i*64+srow)*K+kt+scol;
      rah[i]=*(const short8*)(Ah+ao); ral[i]=*(const short8*)(Al+ao);
      rbh[i]=*(const short8*)(Wh+bo); rbl[i]=*(const short8*)(Wl+bo);
    }
    __syncthreads();
    #pragma unroll
    for(int i=0;i<2;++i){
      int d=(i*64+srow)*LDL+scol;
      *(short8*)&lAh[d]=rah[i]; *(short8*)&lAl[d]=ral[i];
      *(short8*)&lBh[d]=rbh[i]; *(short8*)&lBl[d]=rbl[i];
    }
    __syncthreads();
    const int fr=lane&15, kc=(lane>>4)*8;
    short8 ah[4],al[4],bh[4],bl[4];
    #pragma unroll
    for(int m=0;m<4;++m){ int r=(wr*64+m*16+fr)*LDL+kc; ah[m]=*(const short8*)&lAh[r]; al[m]=*(const short8*)&lAl[r]; }
    #pragma unroll
    for(int n=0;n<4;++n){ int r=(wc*64+n*16+fr)*LDL+kc; bh[n]=*(const short8*)&lBh[r]; bl[n]=*(const short8*)&lBl[r]; }
    #pragma unroll
    for(int m=0;m<4;++m){
      #pragma unroll
      for(int n=0;n<4;++n){
        acc[m][n]=__builtin_amdgcn_mfma_f32_16x16x32_bf16(ah[m],bh[n],acc[m][n],0,0,0);
        acc[m][n]=__builtin_amdgcn_mfma_f32_16x16x32_bf16(ah[m],bl[n],acc[m][n],0,0,0);
        acc[m][n]=__builtin_amdgcn_mfma_f32_16x16x32_bf16(al[m],bh[n],acc[m][n],0,0,0);
        acc[m][n]=__builtin_amdgcn_mfma_f32_16x16x32_bf16(al[m],bl[n],acc[m][n],0,0,0);
      }
    }
  }
  const int fr=lane&15, fq=lane>>4;
  #pragma unroll
  for(int m=0;m<4;++m){
    #pragma unroll
    for(int n=0;n<4;++n){
      const int col = bn + wc*64 + n*16 + fr;
      const float bv = bias[col];
      #pragma unroll
      for(int j=0;j<4;++j){
        const int row = bm + wr*64 + m*16 + fq*4 + j;
        C[(size_t)row*N+col] = actf(ACT, acc[m][n][j] + bv);
      }
    }
  }
}

// ---------------- feature stats + kpred MLP -> k_vals[row] (all f32) ----------------
__global__ __launch_bounds__(256) void feats_kernel(const float* __restrict__ x,
    const float* __restrict__ kw1, const float* __restrict__ kb1,
    const float* __restrict__ kw2, const float* __restrict__ kb2,
    float* __restrict__ kvals)
{
  __shared__ float xs[1024];
  __shared__ unsigned int cd[1024];
  __shared__ float rbuf[4*6];
  __shared__ float r2[4], r3[4];
  __shared__ float bres[6];
  __shared__ int icnt;
  const int tid=threadIdx.x, lane=tid&63, wv=tid>>6;
  const int row=blockIdx.x;
  f32x4 u = ((const f32x4*)(x+(size_t)row*1024))[tid];
  float s=0.f, ss=0.f, amax=0.f, sa=0.f; float nz=0.f;
  #pragma unroll
  for(int j=0;j<4;++j){
    float f=u[j];
    union{float f;unsigned int i;} cv; cv.f=f;
    xs[4*tid+j]=f; cd[4*tid+j]=cv.i&0x7fffffffu;
    s+=f; ss+=f*f; float a=fabsf(f); sa+=a; amax=fmaxf(amax,a); if(f==0.f) nz+=1.f;
  }
  s=wred(s); ss=wred(ss); sa=wred(sa); nz=wred(nz); amax=wredmax(amax);
  if(lane==0){ rbuf[wv*6+0]=s; rbuf[wv*6+1]=ss; rbuf[wv*6+2]=sa; rbuf[wv*6+3]=nz; rbuf[wv*6+4]=amax; }
  __syncthreads();
  if(tid==0){
    float S=0,SS=0,SA=0,NZ=0,AM=0;
    for(int i=0;i<4;++i){ S+=rbuf[i*6]; SS+=rbuf[i*6+1]; SA+=rbuf[i*6+2]; NZ+=rbuf[i*6+3]; AM=fmaxf(AM,rbuf[i*6+4]); }
    bres[0]=S; bres[1]=SS; bres[2]=SA; bres[3]=NZ; bres[4]=AM;
  }
  __syncthreads();
  const float S=bres[0], SS=bres[1], SA=bres[2], NZ=bres[3], AM=bres[4];
  const float mean=S/1024.f;
  const float var=(SS - S*mean)/1023.f;
  const float inv=1.f/sqrtf(var+1e-8f);
  float sk=0.f;
  #pragma unroll
  for(int j=0;j<4;++j){ float z=(xs[4*tid+j]-mean)*inv; sk+=z*z*z; }
  sk=wred(sk);
  if(lane==0) rbuf[wv*6+5]=sk;
  unsigned int lo=0u, hi=0x7f800000u;
  while(hi-lo>1u){
    unsigned int mid=(lo+hi)>>1;
    if(tid==0) icnt=0;
    __syncthreads();
    int c0=0;
    #pragma unroll
    for(int j=0;j<4;++j) c0 += (cd[4*tid+j] >= mid);
    float cf=wred((float)c0);
    if(lane==0) atomicAdd(&icnt,(int)cf);
    __syncthreads();
    int cc=icnt;
    __syncthreads();
    if(cc>=204) lo=mid; else hi=mid;
  }
  float sg=0.f; float cg=0.f;
  #pragma unroll
  for(int j=0;j<4;++j){ if(cd[4*tid+j] > lo){ sg+=fabsf(xs[4*tid+j]); cg+=1.f; } }
  sg=wred(sg); cg=wred(cg);
  if(lane==0){ r2[wv]=sg; r3[wv]=cg; }
  __syncthreads();
  if(tid==0){
    float SK=rbuf[5]+rbuf[11]+rbuf[17]+rbuf[23];
    float SG=r2[0]+r2[1]+r2[2]+r2[3];
    float CG=r3[0]+r3[1]+r3[2]+r3[3];
    union{unsigned int i;float f;} tv; tv.i=lo;
    float conc=(SG + (204.f-CG)*tv.f)/(SA + 1e-8f);
    float feats[6]={ NZ/1024.f, var, AM, sqrtf(SS), SK/1024.f, conc };
    float out=kb2[0];
    #pragma unroll
    for(int i=0;i<16;++i){
      float hv=kb1[i];
      #pragma unroll
      for(int j=0;j<6;++j) hv+=kw1[i*6+j]*feats[j];
      hv=fmaxf(hv,0.f);
      out+=kw2[i]*hv;
    }
    kvals[row]=1.f + 3.f*(1.f/(1.f+__expf(-out)));
  }
}

// ---------------- exact median of 8192 -> k ----------------
__global__ __launch_bounds__(256) void median_kernel(const float* __restrict__ kvals, int* __restrict__ kint){
  __shared__ unsigned int v[8192];
  __shared__ int icnt;
  const int tid=threadIdx.x;
  for(int i=tid;i<8192;i+=256){ union{float f;unsigned int u;} c; c.f=kvals[i]; v[i]=c.u; }
  __syncthreads();
  unsigned int res[2];
  for(int t=0;t<2;++t){
    const int kth=4096+t;
    unsigned int lo=0u, hi=0xFFFFFFFFu;
    while(lo<hi){
      unsigned int mid=lo+((hi-lo)>>1);
      if(tid==0) icnt=0;
      __syncthreads();
      int c=0;
      for(int i=tid;i<8192;i+=256) c += (v[i] <= mid);
      float cf=wred((float)c);
      if((tid&63)==0) atomicAdd(&icnt,(int)cf);
      __syncthreads();
      int cc=icnt;
      __syncthreads();
      if(cc>=kth) hi=mid; else lo=mid+1u;
    }
    res[t]=lo;
  }
  if(tid==0){
    union{unsigned int u; float f;} a,b; a.u=res[0]; b.u=res[1];
    float med=0.5f*(a.f+b.f);
    int k=(int)floorf(med);
    k = k<1?1:(k>4?4:k);
    *kint=k;
  }
}

// ---------------- spec = sigmoid(x@esp^T + h512a@sim_w2^T + sim_b2), one wave/row ------
__global__ __launch_bounds__(256) void spec_kernel(const float* __restrict__ x, const float* __restrict__ h,
    const float* __restrict__ esp, const float* __restrict__ w2, const float* __restrict__ b2,
    float* __restrict__ spec){
  const int wv=threadIdx.x>>6, lane=threadIdx.x&63;
  const int row=blockIdx.x*4+wv;
  const float* xr=x+(size_t)row*1024;
  const float* hr=h+(size_t)row*512;
  float xv[16], hv[8];
  #pragma unroll
  for(int j=0;j<16;++j) xv[j]=xr[j*64+lane];
  #pragma unroll
  for(int j=0;j<8;++j) hv[j]=hr[j*64+lane];
  for(int e=0;e<6;++e){
    float s=0.f;
    #pragma unroll
    for(int j=0;j<16;++j) s+=xv[j]*esp[e*1024+j*64+lane];
    #pragma unroll
    for(int j=0;j<8;++j) s+=hv[j]*w2[e*512+j*64+lane];
    s=wred(s);
    if(lane==0) spec[row*6+e]=1.f/(1.f+__expf(-(s+b2[e])));
  }
}

// ---------------- rout pre-act += spec @ rw1[:,1024:]^T, relu (f32 h) ----------------
__global__ void rout_fix(float* __restrict__ h, const float* __restrict__ spec, const float* __restrict__ rw1){
  const int total=8192*128;
  for(int i=blockIdx.x*blockDim.x+threadIdx.x;i<total;i+=gridDim.x*blockDim.x){
    int row=i>>7, j0=(i&127)*4;
    const float* sp=&spec[row*6];
    f32x4 hv=((f32x4*)h)[i];
    #pragma unroll
    for(int j=0;j<4;++j){
      float v=hv[j];
      int col=j0+j;
      #pragma unroll
      for(int e=0;e<6;++e) v+=sp[e]*rw1[(size_t)col*1030+1024+e];
      hv[j]=fmaxf(v,0.f);
    }
    ((f32x4*)h)[i]=hv;
  }
}

// ---------------- probs = softmax(h512b@rout_w2^T + rout_b2), one wave per row ----------
__global__ __launch_bounds__(256) void probs_kernel(const float* __restrict__ h, const float* __restrict__ w2,
    const float* __restrict__ b2, float* __restrict__ probs){
  const int wv=threadIdx.x>>6, lane=threadIdx.x&63;
  const int row=blockIdx.x*4+wv;
  const float* hr=h+(size_t)row*512;
  float hv[8];
  #pragma unroll
  for(int j=0;j<8;++j) hv[j]=hr[j*64+lane];
  float lg[6];
  #pragma unroll
  for(int e=0;e<6;++e){
    float s=0.f;
    #pragma unroll
    for(int j=0;j<8;++j) s+=hv[j]*w2[e*512+j*64+lane];
    lg[e]=wred(s)+b2[e];
  }
  if(lane==0){
    float m=lg[0];
    #pragma unroll
    for(int e=1;e<6;++e) m=fmaxf(m,lg[e]);
    float den=0.f, ex[6];
    #pragma unroll
    for(int e=0;e<6;++e){ ex[e]=__expf(lg[e]-m); den+=ex[e]; }
    #pragma unroll
    for(int e=0;e<6;++e) probs[row*6+e]=ex[e]/den;
  }
}

// ---------------- top-4 + gates -> per-expert weights ----------------
__global__ void gates_kernel(const float* __restrict__ probs, const int* __restrict__ kint,
                             float* __restrict__ wsel){
  const int r=blockIdx.x*blockDim.x+threadIdx.x;
  if(r>=8192) return;
  const int k=*kint;
  float p[6];
  #pragma unroll
  for(int e=0;e<6;++e) p[e]=probs[r*6+e];
  float w[6]={0,0,0,0,0,0};
  bool used[6]={false,false,false,false,false,false};
  int idx[4]; float val[4];
  #pragma unroll
  for(int j=0;j<4;++j){
    int bi=0; float bv=-1e30f;
    #pragma unroll
    for(int e=0;e<6;++e) if(!used[e] && p[e]>bv){ bv=p[e]; bi=e; }
    used[bi]=true; idx[j]=bi; val[j]=bv;
  }
  float m=val[0], den=0.f, g[4]={0,0,0,0};
  for(int j=0;j<k;++j){ g[j]=__expf(val[j]-m); den+=g[j]; }
  for(int j=0;j<k;++j) w[idx[j]]=g[j]/den;
  #pragma unroll
  for(int e=0;e<6;++e) wsel[r*6+e]=w[e];
}

// ---------------- CrossField expert: register-tiled, conflict-free, fused accumulate ----
__global__ __launch_bounds__(256) void cf_kernel(const float* __restrict__ x,
    const float* __restrict__ w_in, const float* __restrict__ b_in,
    const float* __restrict__ w_o, const float* __restrict__ b_o,
    const float* __restrict__ w_f, const float* __restrict__ b_f,
    const float* __restrict__ wsel, float* __restrict__ comb){
  __shared__ float pool[10496];
  float* xf  = pool;          // 1024
  float* qkv = pool+1024;     // 32*97 = 3104
  float* sc  = pool+4128;     // 32*33+32 = 1088 (P, later prod)
  float* win = pool+5216;     // 96*33 = 3168 (stage1 only; av overlays)
  float* av  = pool+5216;     // 1024 (stages 3-4)
  float* wo  = pool+8384;     // 32*33 = 1056
  float* wf  = pool+9440;     // 32*33 = 1056
  const int row=blockIdx.x, tid=threadIdx.x;
  for(int i=tid;i<3072;i+=256) win[(i>>5)*33+(i&31)]=w_in[i];
  for(int i=tid;i<1024;i+=256){ wo[(i>>5)*33+(i&31)]=w_o[i]; wf[(i>>5)*33+(i&31)]=w_f[i]; }
  f32x4 u=((const f32x4*)(x+(size_t)row*1024))[tid];
  #pragma unroll
  for(int j=0;j<4;++j) xf[4*tid+j]=u[j];
  __syncthreads();
  // ---- stage 1: qkv = xf @ w_in^T + b_in  (4 fields x 3 outputs per thread) ----
  {
    const int fb=tid>>5, c0=(tid&31)*3;
    float a12[4][3];
    #pragma unroll
    for(int i=0;i<4;++i){
      #pragma unroll
      for(int j=0;j<3;++j) a12[i][j]=b_in[c0+j];
    }
    for(int d=0;d<32;++d){
      float xv[4], wv[3];
      #pragma unroll
      for(int i=0;i<4;++i) xv[i]=xf[(fb+8*i)*32+d];
      #pragma unroll
      for(int j=0;j<3;++j) wv[j]=win[(c0+j)*33+d];
      #pragma unroll
      for(int i=0;i<4;++i){
        #pragma unroll
        for(int j=0;j<3;++j) a12[i][j]+=xv[i]*wv[j];
      }
    }
    #pragma unroll
    for(int i=0;i<4;++i){
      #pragma unroll
      for(int j=0;j<3;++j) qkv[(fb+8*i)*97+c0+j]=a12[i][j];
    }
  }
  __syncthreads();
  const int qp=tid>>4, d0=(tid&15)*2;
  const float scale=0.17677669529663687f;
  // ---- stage 2: scores (2q x 2k per thread) ----
  {
    float s00=0,s01=0,s10=0,s11=0;
    for(int d=0;d<32;++d){
      float qa=qkv[qp*97+d], qb=qkv[(qp+16)*97+d];
      float ka=qkv[d0*97+32+d], kb=qkv[(d0+1)*97+32+d];
      s00+=qa*ka; s01+=qa*kb; s10+=qb*ka; s11+=qb*kb;
    }
    sc[qp*33+d0]=s00*scale; sc[qp*33+d0+1]=s01*scale;
    sc[(qp+16)*33+d0]=s10*scale; sc[(qp+16)*33+d0+1]=s11*scale;
  }
  __syncthreads();
  // ---- softmax: 8 lanes per row ----
  {
    const int r=tid>>3, sub=tid&7;
    float v0[4];
    float m=-1e30f;
    #pragma unroll
    for(int jj=0;jj<4;++jj){ v0[jj]=sc[r*33+sub*4+jj]; m=fmaxf(m,v0[jj]); }
    #pragma unroll
    for(int o=1;o<8;o<<=1) m=fmaxf(m,__shfl_xor(m,o));
    float den=0.f;
    #pragma unroll
    for(int jj=0;jj<4;++jj){ v0[jj]=__expf(v0[jj]-m); den+=v0[jj]; }
    #pragma unroll
    for(int o=1;o<8;o<<=1) den+=__shfl_xor(den,o);
    float inv=1.f/den;
    #pragma unroll
    for(int jj=0;jj<4;++jj) sc[r*33+sub*4+jj]=v0[jj]*inv;
  }
  __syncthreads();
  // ---- stage 3: av = P @ v (2q x 2d per thread); av overlays win ----
  {
    float s00=0,s01=0,s10=0,s11=0;
    for(int k=0;k<32;++k){
      float pa=sc[qp*33+k], pb=sc[(qp+16)*33+k];
      f32x2 vv=*(const f32x2*)&qkv[k*97+64+d0];
      s00+=pa*vv[0]; s01+=pa*vv[1]; s10+=pb*vv[0]; s11+=pb*vv[1];
    }
    *(f32x2*)&av[qp*32+d0]=f32x2{s00,s01};
    *(f32x2*)&av[(qp+16)*32+d0]=f32x2{s10,s11};
  }
  __syncthreads();
  // ---- stage 4: attf = av @ w_o^T + b_o; prod = attf * xf (into sc linear) ----
  {
    float s00=b_o[d0], s01=b_o[d0+1], s10=b_o[d0], s11=b_o[d0+1];
    for(int c=0;c<32;++c){
      float aa=av[qp*32+c], ab=av[(qp+16)*32+c];
      float wa=wo[d0*33+c], wb=wo[(d0+1)*33+c];
      s00+=aa*wa; s01+=aa*wb; s10+=ab*wa; s11+=ab*wb;
    }
    __syncthreads();   // av reads done before sc overwrite? sc!=av region; barrier orders P-read end vs prod write (P already consumed stage3)
    *(f32x2*)&sc[qp*32+d0]     = f32x2{s00*xf[qp*32+d0],      s01*xf[qp*32+d0+1]};
    *(f32x2*)&sc[(qp+16)*32+d0]= f32x2{s10*xf[(qp+16)*32+d0], s11*xf[(qp+16)*32+d0+1]};
  }
  __syncthreads();
  // ---- stage 5: e_cf = prod @ w_f^T + b_f; comb += w2 * e_cf ----
  {
    float s00=b_f[d0], s01=b_f[d0+1], s10=b_f[d0], s11=b_f[d0+1];
    for(int c=0;c<32;++c){
      float pa=sc[qp*32+c], pb=sc[(qp+16)*32+c];
      float wa=wf[d0*33+c], wb=wf[(d0+1)*33+c];
      s00+=pa*wa; s01+=pa*wb; s10+=pb*wa; s11+=pb*wb;
    }
    const float w2=wsel[row*6+2];
    float* cb=&comb[(size_t)row*1024];
    f32x2 c0v=*(f32x2*)&cb[qp*32+d0];
    c0v[0]+=w2*s00; c0v[1]+=w2*s01;
    *(f32x2*)&cb[qp*32+d0]=c0v;
    f32x2 c1v=*(f32x2*)&cb[(qp+16)*32+d0];
    c1v[0]+=w2*s10; c1v[1]+=w2*s11;
    *(f32x2*)&cb[(qp+16)*32+d0]=c1v;
  }
}

// ---------------- Temporal expert + final bf16 conversion ----------------
__global__ __launch_bounds__(256) void tp_kernel(const float* __restrict__ x,
    const float* __restrict__ wsel, const float* __restrict__ comb,
    const float* __restrict__ tcw, const float* __restrict__ tcb,
    const float* __restrict__ tfw, const float* __restrict__ tfb,
    u16* __restrict__ obf){
  __shared__ float xs[1026];
  const int row=blockIdx.x, tid=threadIdx.x;
  f32x4 u=((const f32x4*)(x+(size_t)row*1024))[tid];
  #pragma unroll
  for(int j=0;j<4;++j) xs[1+4*tid+j]=u[j];
  if(tid==0){ xs[0]=0.f; xs[1025]=0.f; }
  __syncthreads();
  const float w4=wsel[row*6+4];
  float tc[4][3], tb[4], tf[4];
  #pragma unroll
  for(int o=0;o<4;++o){
    #pragma unroll
    for(int kh=0;kh<3;++kh) tc[o][kh]=tcw[o*3+kh];
    tb[o]=tcb[o]; tf[o]=tfw[o];
  }
  const float tfb0=tfb[0];
  f32x4 cv=((const f32x4*)(comb+(size_t)row*1024))[tid];
  u16x4 ov;
  #pragma unroll
  for(int j=0;j<4;++j){
    const int d=4*tid+j;
    float pre=tfb0;
    #pragma unroll
    for(int o=0;o<4;++o){
      float c=tb[o]+tc[o][0]*xs[d]+tc[o][1]*xs[d+1]+tc[o][2]*xs[d+2];
      pre+=tf[o]*fmaxf(c,0.f);
    }
    float wt=1.f/(1.f+__expf(-pre));
    float xv=xs[1+d];
    ov[j]=f2bf(cv[j]+w4*xv*xv*wt);
  }
  ((u16x4*)(obf+(size_t)row*1024))[tid]=ov;
}

// =======================================================================================
extern "C" void kernel_launch(void* const* d_in, const int* in_sizes, int n_in,
                              void* d_out, int out_size, void* d_ws, size_t ws_size,
                              hipStream_t stream)
{
  const float* x     =(const float*)d_in[0];
  const float* esp   =(const float*)d_in[1];
  const float* sim_w1=(const float*)d_in[2],  *sim_b1=(const float*)d_in[3];
  const float* sim_w2=(const float*)d_in[4],  *sim_b2=(const float*)d_in[5];
  const float* rout_w1=(const float*)d_in[6], *rout_b1=(const float*)d_in[7];
  const float* rout_w2=(const float*)d_in[8], *rout_b2=(const float*)d_in[9];
  const float* kw1=(const float*)d_in[10], *kb1=(const float*)d_in[11];
  const float* kw2=(const float*)d_in[12], *kb2=(const float*)d_in[13];
  const float* spv_w=(const float*)d_in[14], *spv_b=(const float*)d_in[15];
  const float* spo_w=(const float*)d_in[16], *spo_b=(const float*)d_in[17];
  const float* spq1_w=(const float*)d_in[18], *spq1_b=(const float*)d_in[19];
  const float* spq2_w=(const float*)d_in[20], *spq2_b=(const float*)d_in[21];
  const float* de_w1=(const float*)d_in[22], *de_b1=(const float*)d_in[23];
  const float* de_w2=(const float*)d_in[24], *de_b2=(const float*)d_in[25];
  const float* de_gw=(const float*)d_in[26], *de_gb=(const float*)d_in[27];
  const float* cf_inw=(const float*)d_in[28], *cf_inb=(const float*)d_in[29];
  const float* cf_ow=(const float*)d_in[30], *cf_ob=(const float*)d_in[31];
  const float* cf_fw=(const float*)d_in[32], *cf_fb=(const float*)d_in[33];
  const float* hf_w1=(const float*)d_in[34], *hf_b1=(const float*)d_in[35];
  const float* hf_w2=(const float*)d_in[36], *hf_b2=(const float*)d_in[37];
  const float* tc_w=(const float*)d_in[38], *tc_b=(const float*)d_in[39];
  const float* tf_w=(const float*)d_in[40], *tf_b=(const float*)d_in[41];
  const float* lt_w1=(const float*)d_in[42], *lt_b1=(const float*)d_in[43];
  const float* lt_w2=(const float*)d_in[44], *lt_b2=(const float*)d_in[45];
  const float* op_w=(const float*)d_in[46], *op_b=(const float*)d_in[47];
  float* out=(float*)d_out;
  (void)in_sizes; (void)n_in; (void)out_size; (void)ws_size;

  constexpr int NB=8192;
  const size_t BD=(size_t)NB*1024;
  char* base=(char*)d_ws; size_t off=0;
  auto carve=[&](size_t n)->void*{ void* q=base+off; off+=(n+255)&~(size_t)255; return q; };
  float* comb =(float*)carve(BD*4);
  u16*  bufA =(u16*)carve(BD*2);
  u16*  bufB =(u16*)carve(BD*2);
  u16*  x_hi =(u16*)carve(BD*2);
  u16*  x_lo =(u16*)carve(BD*2);
  float* h512a=(float*)carve((size_t)NB*512*4);
  float* h512b=(float*)carve((size_t)NB*512*4);
  u16*  h256 =(u16*)carve((size_t)NB*256*2);
  u16* sw1h=(u16*)carve((size_t)512*1024*2);
  u16* sw1l=(u16*)carve((size_t)512*1024*2);
  u16* rw1h=(u16*)carve((size_t)512*1024*2);
  u16* rw1l=(u16*)carve((size_t)512*1024*2);
  u16* spv_bf =(u16*)carve((size_t)1024*1024*2);
  u16* spo_bf =(u16*)carve((size_t)1024*1024*2);
  u16* spq1_bf=(u16*)carve((size_t)1024*1024*2);
  u16* spq2_bf=(u16*)carve((size_t)1024*1024*2);
  u16* dew1_bf=(u16*)carve((size_t)256*1024*2);
  u16* dew2_bf=(u16*)carve((size_t)1024*256*2);
  u16* degw_bf=(u16*)carve((size_t)1024*1024*2);
  u16* hfw1_bf=(u16*)carve((size_t)256*1024*2);
  u16* hfw2_bf=(u16*)carve((size_t)1024*256*2);
  u16* ltw1_bf=(u16*)carve((size_t)256*1024*2);
  u16* ltw2_bf=(u16*)carve((size_t)1024*256*2);
  u16* opw_bf =(u16*)carve((size_t)1024*1024*2);
  float* spec=(float*)carve((size_t)NB*6*4);
  float* probs=(float*)carve((size_t)NB*6*4);
  float* wsel=(float*)carve((size_t)NB*6*4);
  float* kvals=(float*)carve((size_t)NB*4);
  int*   kint=(int*)carve(256);

  const dim3 blk(256);
  const dim3 gEW(2048);
  auto cgrid=[&](int n4)->dim3{ int g=(n4+255)/256; return dim3(g>2048?2048:g); };

  // ---- conversions ----
  cvt_split<<<cgrid(2097152),blk,0,stream>>>(x, x_hi, x_lo, 2097152);
  cvt_split<<<cgrid(131072),blk,0,stream>>>(sim_w1, sw1h, sw1l, 131072);
  cvt_split_rw1<<<cgrid(131072),blk,0,stream>>>(rout_w1, rw1h, rw1l);
  cvt_kernel<<<cgrid(262144),blk,0,stream>>>(spv_w,  spv_bf, 262144);
  cvt_kernel<<<cgrid(262144),blk,0,stream>>>(spo_w,  spo_bf, 262144);
  cvt_kernel<<<cgrid(262144),blk,0,stream>>>(spq1_w, spq1_bf,262144);
  cvt_kernel<<<cgrid(262144),blk,0,stream>>>(spq2_w, spq2_bf,262144);
  cvt_kernel<<<cgrid(65536),blk,0,stream>>>(de_w1,  dew1_bf,65536);
  cvt_kernel<<<cgrid(65536),blk,0,stream>>>(de_w2,  dew2_bf,65536);
  cvt_kernel<<<cgrid(262144),blk,0,stream>>>(de_gw,  degw_bf,262144);
  cvt_kernel<<<cgrid(65536),blk,0,stream>>>(hf_w1,  hfw1_bf,65536);
  cvt_kernel<<<cgrid(65536),blk,0,stream>>>(hf_w2,  hfw2_bf,65536);
  cvt_kernel<<<cgrid(65536),blk,0,stream>>>(lt_w1,  ltw1_bf,65536);
  cvt_kernel<<<cgrid(65536),blk,0,stream>>>(lt_w2,  ltw2_bf,65536);
  cvt_kernel<<<cgrid(262144),blk,0,stream>>>(op_w,   opw_bf, 262144);

  // ---- routing pipeline (f32-accurate) ----
  feats_kernel<<<dim3(NB),blk,0,stream>>>(x, kw1,kb1,kw2,kb2, kvals);
  median_kernel<<<dim3(1),blk,0,stream>>>(kvals, kint);
  gemm_split<1><<<dim3(4,64),blk,0,stream>>>(x_hi,x_lo, sw1h,sw1l, sim_b1, h512a, NB,512,1024);
  spec_kernel<<<gEW,blk,0,stream>>>(x, h512a, esp, sim_w2, sim_b2, spec);
  gemm_split<0><<<dim3(4,64),blk,0,stream>>>(x_hi,x_lo, rw1h,rw1l, rout_b1, h512b, NB,512,1024);
  rout_fix<<<gEW,blk,0,stream>>>(h512b, spec, rout_w1);
  probs_kernel<<<gEW,blk,0,stream>>>(h512b, rout_w2, rout_b2, probs);
  gates_kernel<<<dim3(32),blk,0,stream>>>(probs, kint, wsel);

  // ---- expert 0: SparseQuadratic (spq2 writes comb = w0*v) ----
  gemm_bt<0,0><<<dim3(8,64),blk,0,stream>>>(x_hi, spv_bf, spv_b, nullptr, nullptr, nullptr, nullptr, bufA, NB,1024,1024);
  gemm_bt<0,2><<<dim3(8,64),blk,0,stream>>>(bufA, spo_bf, spo_b, nullptr, x, nullptr, nullptr, bufB, NB,1024,1024);
  gemm_bt<1,0><<<dim3(8,64),blk,0,stream>>>(bufB, spq1_bf, spq1_b, nullptr, nullptr, nullptr, nullptr, bufA, NB,1024,1024);
  gemm_bt<0,3><<<dim3(8,64),blk,0,stream>>>(bufA, spq2_bf, spq2_b, nullptr, nullptr, wsel, comb, nullptr, NB,1024,1024);

  // ---- expert 1: DenseQuadratic ----
  gemm_bt<1,0><<<dim3(2,64),blk,0,stream>>>(x_hi, dew1_bf, de_b1, nullptr, nullptr, nullptr, nullptr, h256, NB,256,1024);
  gemm_bt<2,0><<<dim3(8,64),blk,0,stream>>>(x_hi, degw_bf, de_gb, nullptr, nullptr, nullptr, nullptr, bufB, NB,1024,1024);
  gemm_bt<0,4><<<dim3(8,64),blk,0,stream>>>(h256, dew2_bf, de_b2, bufB, x, wsel, comb, nullptr, NB,1024,256);

  // ---- expert 2: CrossField (fused accumulate) ----
  cf_kernel<<<dim3(NB),blk,0,stream>>>(x, cf_inw, cf_inb, cf_ow, cf_ob, cf_fw, cf_fb, wsel, comb);

  // ---- expert 3: HighFreq ----
  gemm_bt<3,0><<<dim3(2,64),blk,0,stream>>>(x_hi, hfw1_bf, hf_b1, nullptr, nullptr, nullptr, nullptr, h256, NB,256,1024);
  gemm_bt<0,5><<<dim3(8,64),blk,0,stream>>>(h256, hfw2_bf, hf_b2, nullptr, x, wsel, comb, nullptr, NB,1024,256);

  // ---- expert 5: LongTail ----
  gemm_bt<4,0><<<dim3(2,64),blk,0,stream>>>(x_hi, ltw1_bf, lt_b1, nullptr, nullptr, nullptr, nullptr, h256, NB,256,1024);
  gemm_bt<0,6><<<dim3(8,64),blk,0,stream>>>(h256, ltw2_bf, lt_b2, nullptr, x, wsel, comb, nullptr, NB,1024,256);

  // ---- expert 4: Temporal (last comb reader) + final bf16 conversion ----
  tp_kernel<<<dim3(NB),blk,0,stream>>>(x, wsel, comb, tc_w, tc_b, tf_w, tf_b, bufB);

  // ---- output projection + residual (f32 out) ----
  gemm_bt<0,7><<<dim3(8,64),blk,0,stream>>>(bufB, opw_bf, op_b, nullptr, x, nullptr, nullptr, out, NB,1024,1024);
}

// Round 9
// 805.150 us; speedup vs baseline: 2.1015x; 1.1106x over previous
//
#include <hip/hip_runtime.h>
#include <stdint.h>

typedef unsigned short u16;
typedef __attribute__((ext_vector_type(2))) float f32x2;
typedef __attribute__((ext_vector_type(4))) float f32x4;
typedef __attribute__((ext_vector_type(4))) unsigned short u16x4;
typedef __attribute__((ext_vector_type(8))) short short8;

#define DEV static __device__ __forceinline__

DEV float bf2f(u16 u){ union{unsigned int i; float f;} v; v.i=((unsigned int)u)<<16; return v.f; }
DEV u16 f2bf(float f){ union{float f; unsigned int i;} v; v.f=f; unsigned int u=v.i;
  return (u16)((u + 0x7FFFu + ((u>>16)&1u))>>16); }
DEV float wred(float v){ for(int o=32;o;o>>=1) v += __shfl_xor(v,o); return v; }
DEV float wredmax(float v){ for(int o=32;o;o>>=1) v = fmaxf(v,__shfl_xor(v,o)); return v; }

DEV void gload16(const void* g, void* l){
  __builtin_amdgcn_global_load_lds((const __attribute__((address_space(1))) unsigned int*)g,
                                   (__attribute__((address_space(3))) unsigned int*)l, 16, 0, 0);
}

DEV float actf(int ACT, float v){
  if(ACT==1) return v>0.f?v:0.f;
  if(ACT==2) return 1.f/(1.f+__expf(-v));
  if(ACT==3) return tanhf(v);
  if(ACT==4) return v>0.f?v:(__expf(v)-1.f);
  return v;
}

// ---------------- f32 -> bf16 conversions ----------------
__global__ void cvt_kernel(const float* __restrict__ s, u16* __restrict__ d, int n4){
  for(int i=blockIdx.x*blockDim.x+threadIdx.x; i<n4; i+=gridDim.x*blockDim.x){
    f32x4 v=((const f32x4*)s)[i];
    u16x4 o;
    #pragma unroll
    for(int j=0;j<4;++j) o[j]=f2bf(v[j]);
    ((u16x4*)d)[i]=o;
  }
}

// batched: 6 equal-size pairs
__global__ void cvt6_kernel(
    const float* __restrict__ s0, const float* __restrict__ s1, const float* __restrict__ s2,
    const float* __restrict__ s3, const float* __restrict__ s4, const float* __restrict__ s5,
    u16* __restrict__ d0, u16* __restrict__ d1, u16* __restrict__ d2,
    u16* __restrict__ d3, u16* __restrict__ d4, u16* __restrict__ d5, int n4each){
  const float* ss[6]={s0,s1,s2,s3,s4,s5};
  u16* dd[6]={d0,d1,d2,d3,d4,d5};
  const int total=6*n4each;
  for(int i=blockIdx.x*blockDim.x+threadIdx.x; i<total; i+=gridDim.x*blockDim.x){
    int b=i/n4each, r=i-b*n4each;
    f32x4 v=((const f32x4*)ss[b])[r];
    u16x4 o;
    #pragma unroll
    for(int j=0;j<4;++j) o[j]=f2bf(v[j]);
    ((u16x4*)dd[b])[r]=o;
  }
}

// f32 -> (hi, lo) bf16 split
__global__ void cvt_split(const float* __restrict__ s, u16* __restrict__ hi, u16* __restrict__ lo, int n4){
  for(int i=blockIdx.x*blockDim.x+threadIdx.x; i<n4; i+=gridDim.x*blockDim.x){
    f32x4 v=((const f32x4*)s)[i];
    u16x4 h,l;
    #pragma unroll
    for(int j=0;j<4;++j){ h[j]=f2bf(v[j]); l[j]=f2bf(v[j]-bf2f(h[j])); }
    ((u16x4*)hi)[i]=h; ((u16x4*)lo)[i]=l;
  }
}

// pack+split rout_w1[:, :1024] (lda=1030 f32) into dense hi/lo 512x1024
__global__ void cvt_split_rw1(const float* __restrict__ src, u16* __restrict__ hi, u16* __restrict__ lo){
  for(int i=blockIdx.x*blockDim.x+threadIdx.x; i<512*1024; i+=gridDim.x*blockDim.x){
    int r=i>>10, c=i&1023;
    float v=src[(size_t)r*1030+c];
    u16 h=f2bf(v);
    hi[i]=h; lo[i]=f2bf(v-bf2f(h));
  }
}

// ---------------- GEMM: fused epilogues, global_load_lds staging ------------------------
// EPI 0: C bf16 = v           1: C f32 = v        2: C bf16 = v*xf      (spo: att*x)
//     3: comb  = w[0]*v       4: comb += w[1]*(v + gate*xf)             (de2)
//     5: comb += w[3]*(xf + (v-xf)*xf)            6: comb += w[5]*sgn(xf)*sqrt(|v*xf|+1e-8)
//     7: C f32 = v + xf (residual)
template<int ACT, int EPI>
__global__ __launch_bounds__(256) void gemm_bt(
    const u16* __restrict__ A, const u16* __restrict__ W,
    const float* __restrict__ bias, const u16* __restrict__ auxb,
    const float* __restrict__ auxf, const float* __restrict__ wsel,
    float* __restrict__ comb, void* __restrict__ Cv, int M, int N, int K)
{
  __shared__ __align__(16) u16 lA[128*64];
  __shared__ __align__(16) u16 lB[128*64];
  const int tid=threadIdx.x, lane=tid&63, wv=tid>>6;
  const int wr=wv>>1, wc=wv&1;
  const int bn=blockIdx.x*128, bm=blockIdx.y*128;
  f32x4 acc[4][4];
  #pragma unroll
  for(int m=0;m<4;++m){
    #pragma unroll
    for(int n=0;n<4;++n) acc[m][n]=(f32x4)0.f;
  }
  const int srow = wv*8 + (lane>>3);       // source row within 32-row chunk
  const int scol = (lane&7)*8;             // element col (8 bf16 = 16B)
  for(int kt=0;kt<K;kt+=64){
    #pragma unroll
    for(int i=0;i<4;++i){
      gload16(A + (size_t)(bm + i*32 + srow)*K + kt + scol, &lA[(i*32 + wv*8)*64]);
      gload16(W + (size_t)(bn + i*32 + srow)*K + kt + scol, &lB[(i*32 + wv*8)*64]);
    }
    __syncthreads();   // drains vmcnt: LDS writes visible
    #pragma unroll
    for(int kk=0;kk<2;++kk){
      const int fr=lane&15, kc=kk*32+(lane>>4)*8;
      short8 af[4], bfr[4];
      #pragma unroll
      for(int m=0;m<4;++m) af[m]=*(const short8*)&lA[(wr*64+m*16+fr)*64+kc];
      #pragma unroll
      for(int n=0;n<4;++n) bfr[n]=*(const short8*)&lB[(wc*64+n*16+fr)*64+kc];
      #pragma unroll
      for(int m=0;m<4;++m){
        #pragma unroll
        for(int n=0;n<4;++n)
          acc[m][n]=__builtin_amdgcn_mfma_f32_16x16x32_bf16(af[m],bfr[n],acc[m][n],0,0,0);
      }
    }
    __syncthreads();   // reads done before next iter's gload overwrites
  }
  const int fr=lane&15, fq=lane>>4;
  #pragma unroll
  for(int m=0;m<4;++m){
    #pragma unroll
    for(int n=0;n<4;++n){
      const int col = bn + wc*64 + n*16 + fr;
      const float bv = bias[col];
      #pragma unroll
      for(int j=0;j<4;++j){
        const int row = bm + wr*64 + m*16 + fq*4 + j;
        const size_t idx = (size_t)row*N+col;
        float v = acc[m][n][j] + bv;
        v = actf(ACT, v);
        if(EPI==0){ ((u16*)Cv)[idx]=f2bf(v); }
        else if(EPI==1){ ((float*)Cv)[idx]=v; }
        else if(EPI==2){ ((u16*)Cv)[idx]=f2bf(v*auxf[idx]); }
        else if(EPI==3){ comb[idx]=wsel[row*6+0]*v; }
        else if(EPI==4){ comb[idx]+=wsel[row*6+1]*(v + bf2f(auxb[idx])*auxf[idx]); }
        else if(EPI==5){ float x0=auxf[idx]; comb[idx]+=wsel[row*6+3]*(x0+(v-x0)*x0); }
        else if(EPI==6){
          float x0=auxf[idx];
          float sg=(x0>0.f)?1.f:((x0<0.f)?-1.f:0.f);
          comb[idx]+=wsel[row*6+5]*sg*sqrtf(fabsf(v*x0)+1e-8f);
        }
        else { ((float*)Cv)[idx]=v+auxf[idx]; }
      }
    }
  }
}

// ---------------- split-precision GEMM (f32-accurate): C = act(A@W^T + b), f32 out -----
template<int ACT>
__global__ __launch_bounds__(256) void gemm_split(
    const u16* __restrict__ Ah, const u16* __restrict__ Al,
    const u16* __restrict__ Wh, const u16* __restrict__ Wl,
    const float* __restrict__ bias, float* __restrict__ C, int M, int N, int K)
{
  const int LDL=40;
  __shared__ __align__(16) u16 lAh[128*40], lAl[128*40], lBh[128*40], lBl[128*40];
  const int tid=threadIdx.x, lane=tid&63, wv=tid>>6;
  const int wr=wv>>1, wc=wv&1;
  const int bn=blockIdx.x*128, bm=blockIdx.y*128;
  f32x4 acc[4][4];
  #pragma unroll
  for(int m=0;m<4;++m){
    #pragma unroll
    for(int n=0;n<4;++n) acc[m][n]=(f32x4)0.f;
  }
  const int srow=tid>>2, scol=(tid&3)*8;
  for(int kt=0;kt<K;kt+=32){
    short8 rah[2],ral[2],rbh[2],rbl[2];
    #pragma unroll
    for(int i=0;i<2;++i){
      size_t ao=(size_t)(bm+i*64+srow)*K+kt+scol;
      size_t bo=(size_t)(bn+i*64+srow)*K+kt+scol;
      rah[i]=*(const short8*)(Ah+ao); ral[i]=*(const short8*)(Al+ao);
      rbh[i]=*(const short8*)(Wh+bo); rbl[i]=*(const short8*)(Wl+bo);
    }
    __syncthreads();
    #pragma unroll
    for(int i=0;i<2;++i){
      int d=(i*64+srow)*LDL+scol;
      *(short8*)&lAh[d]=rah[i]; *(short8*)&lAl[d]=ral[i];
      *(short8*)&lBh[d]=rbh[i]; *(short8*)&lBl[d]=rbl[i];
    }
    __syncthreads();
    const int fr=lane&15, kc=(lane>>4)*8;
    short8 ah[4],al[4],bh[4],bl[4];
    #pragma unroll
    for(int m=0;m<4;++m){ int r=(wr*64+m*16+fr)*LDL+kc; ah[m]=*(const short8*)&lAh[r]; al[m]=*(const short8*)&lAl[r]; }
    #pragma unroll
    for(int n=0;n<4;++n){ int r=(wc*64+n*16+fr)*LDL+kc; bh[n]=*(const short8*)&lBh[r]; bl[n]=*(const short8*)&lBl[r]; }
    #pragma unroll
    for(int m=0;m<4;++m){
      #pragma unroll
      for(int n=0;n<4;++n){
        acc[m][n]=__builtin_amdgcn_mfma_f32_16x16x32_bf16(ah[m],bh[n],acc[m][n],0,0,0);
        acc[m][n]=__builtin_amdgcn_mfma_f32_16x16x32_bf16(ah[m],bl[n],acc[m][n],0,0,0);
        acc[m][n]=__builtin_amdgcn_mfma_f32_16x16x32_bf16(al[m],bh[n],acc[m][n],0,0,0);
        acc[m][n]=__builtin_amdgcn_mfma_f32_16x16x32_bf16(al[m],bl[n],acc[m][n],0,0,0);
      }
    }
  }
  const int fr=lane&15, fq=lane>>4;
  #pragma unroll
  for(int m=0;m<4;++m){
    #pragma unroll
    for(int n=0;n<4;++n){
      const int col = bn + wc*64 + n*16 + fr;
      const float bv = bias[col];
      #pragma unroll
      for(int j=0;j<4;++j){
        const int row = bm + wr*64 + m*16 + fq*4 + j;
        C[(size_t)row*N+col] = actf(ACT, acc[m][n][j] + bv);
      }
    }
  }
}

// ---------------- feature stats + kpred MLP -> k_vals[row] (all f32) ----------------
__global__ __launch_bounds__(256) void feats_kernel(const float* __restrict__ x,
    const float* __restrict__ kw1, const float* __restrict__ kb1,
    const float* __restrict__ kw2, const float* __restrict__ kb2,
    float* __restrict__ kvals)
{
  __shared__ float xs[1024];
  __shared__ unsigned int cd[1024];
  __shared__ float rbuf[4*6];
  __shared__ float r2[4], r3[4];
  __shared__ float bres[6];
  __shared__ int icnt;
  const int tid=threadIdx.x, lane=tid&63, wv=tid>>6;
  const int row=blockIdx.x;
  f32x4 u = ((const f32x4*)(x+(size_t)row*1024))[tid];
  float s=0.f, ss=0.f, amax=0.f, sa=0.f; float nz=0.f;
  #pragma unroll
  for(int j=0;j<4;++j){
    float f=u[j];
    union{float f;unsigned int i;} cv; cv.f=f;
    xs[4*tid+j]=f; cd[4*tid+j]=cv.i&0x7fffffffu;
    s+=f; ss+=f*f; float a=fabsf(f); sa+=a; amax=fmaxf(amax,a); if(f==0.f) nz+=1.f;
  }
  s=wred(s); ss=wred(ss); sa=wred(sa); nz=wred(nz); amax=wredmax(amax);
  if(lane==0){ rbuf[wv*6+0]=s; rbuf[wv*6+1]=ss; rbuf[wv*6+2]=sa; rbuf[wv*6+3]=nz; rbuf[wv*6+4]=amax; }
  __syncthreads();
  if(tid==0){
    float S=0,SS=0,SA=0,NZ=0,AM=0;
    for(int i=0;i<4;++i){ S+=rbuf[i*6]; SS+=rbuf[i*6+1]; SA+=rbuf[i*6+2]; NZ+=rbuf[i*6+3]; AM=fmaxf(AM,rbuf[i*6+4]); }
    bres[0]=S; bres[1]=SS; bres[2]=SA; bres[3]=NZ; bres[4]=AM;
  }
  __syncthreads();
  const float S=bres[0], SS=bres[1], SA=bres[2], NZ=bres[3], AM=bres[4];
  const float mean=S/1024.f;
  const float var=(SS - S*mean)/1023.f;
  const float inv=1.f/sqrtf(var+1e-8f);
  float sk=0.f;
  #pragma unroll
  for(int j=0;j<4;++j){ float z=(xs[4*tid+j]-mean)*inv; sk+=z*z*z; }
  sk=wred(sk);
  if(lane==0) rbuf[wv*6+5]=sk;
  unsigned int lo=0u, hi=0x7f800000u;
  while(hi-lo>1u){
    unsigned int mid=(lo+hi)>>1;
    if(tid==0) icnt=0;
    __syncthreads();
    int c0=0;
    #pragma unroll
    for(int j=0;j<4;++j) c0 += (cd[4*tid+j] >= mid);
    float cf=wred((float)c0);
    if(lane==0) atomicAdd(&icnt,(int)cf);
    __syncthreads();
    int cc=icnt;
    __syncthreads();
    if(cc>=204) lo=mid; else hi=mid;
  }
  float sg=0.f; float cg=0.f;
  #pragma unroll
  for(int j=0;j<4;++j){ if(cd[4*tid+j] > lo){ sg+=fabsf(xs[4*tid+j]); cg+=1.f; } }
  sg=wred(sg); cg=wred(cg);
  if(lane==0){ r2[wv]=sg; r3[wv]=cg; }
  __syncthreads();
  if(tid==0){
    float SK=rbuf[5]+rbuf[11]+rbuf[17]+rbuf[23];
    float SG=r2[0]+r2[1]+r2[2]+r2[3];
    float CG=r3[0]+r3[1]+r3[2]+r3[3];
    union{unsigned int i;float f;} tv; tv.i=lo;
    float conc=(SG + (204.f-CG)*tv.f)/(SA + 1e-8f);
    float feats[6]={ NZ/1024.f, var, AM, sqrtf(SS), SK/1024.f, conc };
    float out=kb2[0];
    #pragma unroll
    for(int i=0;i<16;++i){
      float hv=kb1[i];
      #pragma unroll
      for(int j=0;j<6;++j) hv+=kw1[i*6+j]*feats[j];
      hv=fmaxf(hv,0.f);
      out+=kw2[i]*hv;
    }
    kvals[row]=1.f + 3.f*(1.f/(1.f+__expf(-out)));
  }
}

// ---------------- exact median of 8192 -> k ----------------
__global__ __launch_bounds__(256) void median_kernel(const float* __restrict__ kvals, int* __restrict__ kint){
  __shared__ unsigned int v[8192];
  __shared__ int icnt;
  const int tid=threadIdx.x;
  for(int i=tid;i<8192;i+=256){ union{float f;unsigned int u;} c; c.f=kvals[i]; v[i]=c.u; }
  __syncthreads();
  unsigned int res[2];
  for(int t=0;t<2;++t){
    const int kth=4096+t;
    unsigned int lo=0u, hi=0xFFFFFFFFu;
    while(lo<hi){
      unsigned int mid=lo+((hi-lo)>>1);
      if(tid==0) icnt=0;
      __syncthreads();
      int c=0;
      for(int i=tid;i<8192;i+=256) c += (v[i] <= mid);
      float cf=wred((float)c);
      if((tid&63)==0) atomicAdd(&icnt,(int)cf);
      __syncthreads();
      int cc=icnt;
      __syncthreads();
      if(cc>=kth) hi=mid; else lo=mid+1u;
    }
    res[t]=lo;
  }
  if(tid==0){
    union{unsigned int u; float f;} a,b; a.u=res[0]; b.u=res[1];
    float med=0.5f*(a.f+b.f);
    int k=(int)floorf(med);
    k = k<1?1:(k>4?4:k);
    *kint=k;
  }
}

// ---------------- spec = sigmoid(x@esp^T + h512a@sim_w2^T + sim_b2), one wave/row ------
__global__ __launch_bounds__(256) void spec_kernel(const float* __restrict__ x, const float* __restrict__ h,
    const float* __restrict__ esp, const float* __restrict__ w2, const float* __restrict__ b2,
    float* __restrict__ spec){
  const int wv=threadIdx.x>>6, lane=threadIdx.x&63;
  const int row=blockIdx.x*4+wv;
  const float* xr=x+(size_t)row*1024;
  const float* hr=h+(size_t)row*512;
  float xv[16], hv[8];
  #pragma unroll
  for(int j=0;j<16;++j) xv[j]=xr[j*64+lane];
  #pragma unroll
  for(int j=0;j<8;++j) hv[j]=hr[j*64+lane];
  for(int e=0;e<6;++e){
    float s=0.f;
    #pragma unroll
    for(int j=0;j<16;++j) s+=xv[j]*esp[e*1024+j*64+lane];
    #pragma unroll
    for(int j=0;j<8;++j) s+=hv[j]*w2[e*512+j*64+lane];
    s=wred(s);
    if(lane==0) spec[row*6+e]=1.f/(1.f+__expf(-(s+b2[e])));
  }
}

// ---------------- rout pre-act += spec @ rw1[:,1024:]^T, relu (f32 h) ----------------
__global__ void rout_fix(float* __restrict__ h, const float* __restrict__ spec, const float* __restrict__ rw1){
  const int total=8192*128;
  for(int i=blockIdx.x*blockDim.x+threadIdx.x;i<total;i+=gridDim.x*blockDim.x){
    int row=i>>7, j0=(i&127)*4;
    const float* sp=&spec[row*6];
    f32x4 hv=((f32x4*)h)[i];
    #pragma unroll
    for(int j=0;j<4;++j){
      float v=hv[j];
      int col=j0+j;
      #pragma unroll
      for(int e=0;e<6;++e) v+=sp[e]*rw1[(size_t)col*1030+1024+e];
      hv[j]=fmaxf(v,0.f);
    }
    ((f32x4*)h)[i]=hv;
  }
}

// ---------------- probs = softmax(h512b@rout_w2^T + rout_b2), one wave per row ----------
__global__ __launch_bounds__(256) void probs_kernel(const float* __restrict__ h, const float* __restrict__ w2,
    const float* __restrict__ b2, float* __restrict__ probs){
  const int wv=threadIdx.x>>6, lane=threadIdx.x&63;
  const int row=blockIdx.x*4+wv;
  const float* hr=h+(size_t)row*512;
  float hv[8];
  #pragma unroll
  for(int j=0;j<8;++j) hv[j]=hr[j*64+lane];
  float lg[6];
  #pragma unroll
  for(int e=0;e<6;++e){
    float s=0.f;
    #pragma unroll
    for(int j=0;j<8;++j) s+=hv[j]*w2[e*512+j*64+lane];
    lg[e]=wred(s)+b2[e];
  }
  if(lane==0){
    float m=lg[0];
    #pragma unroll
    for(int e=1;e<6;++e) m=fmaxf(m,lg[e]);
    float den=0.f, ex[6];
    #pragma unroll
    for(int e=0;e<6;++e){ ex[e]=__expf(lg[e]-m); den+=ex[e]; }
    #pragma unroll
    for(int e=0;e<6;++e) probs[row*6+e]=ex[e]/den;
  }
}

// ---------------- top-4 + gates -> per-expert weights ----------------
__global__ void gates_kernel(const float* __restrict__ probs, const int* __restrict__ kint,
                             float* __restrict__ wsel){
  const int r=blockIdx.x*blockDim.x+threadIdx.x;
  if(r>=8192) return;
  const int k=*kint;
  float p[6];
  #pragma unroll
  for(int e=0;e<6;++e) p[e]=probs[r*6+e];
  float w[6]={0,0,0,0,0,0};
  bool used[6]={false,false,false,false,false,false};
  int idx[4]; float val[4];
  #pragma unroll
  for(int j=0;j<4;++j){
    int bi=0; float bv=-1e30f;
    #pragma unroll
    for(int e=0;e<6;++e) if(!used[e] && p[e]>bv){ bv=p[e]; bi=e; }
    used[bi]=true; idx[j]=bi; val[j]=bv;
  }
  float m=val[0], den=0.f, g[4]={0,0,0,0};
  for(int j=0;j<k;++j){ g[j]=__expf(val[j]-m); den+=g[j]; }
  for(int j=0;j<k;++j) w[idx[j]]=g[j]/den;
  #pragma unroll
  for(int e=0;e<6;++e) wsel[r*6+e]=w[e];
}

// ---------------- CrossField expert: vectorized LDS (b128/b64), fused accumulate --------
__global__ __launch_bounds__(256) void cf_kernel(const float* __restrict__ x,
    const float* __restrict__ w_in, const float* __restrict__ b_in,
    const float* __restrict__ w_o, const float* __restrict__ b_o,
    const float* __restrict__ w_f, const float* __restrict__ b_f,
    const float* __restrict__ wsel, float* __restrict__ comb){
  __shared__ __align__(16) float pool[11136];
  float* xf  = pool;          // 32x32 (stride 32)
  float* qkv = pool+1024;     // 32 x stride 100 (16B-aligned rows)
  float* sc  = pool+4224;     // 32 x stride 36  (P, then prod)
  float* win = pool+5376;     // 96 x stride 36 (stage1 only)
  float* av  = pool+5376;     // 32 x stride 36 (overlays win after stage1)
  float* wo  = pool+8832;     // 32 x stride 36
  float* wf  = pool+9984;     // 32 x stride 36
  const int row=blockIdx.x, tid=threadIdx.x;
  for(int i=tid;i<3072;i+=256) win[(i>>5)*36+(i&31)]=w_in[i];
  for(int i=tid;i<1024;i+=256){ wo[(i>>5)*36+(i&31)]=w_o[i]; wf[(i>>5)*36+(i&31)]=w_f[i]; }
  f32x4 u=((const f32x4*)(x+(size_t)row*1024))[tid];
  *(f32x4*)&xf[4*tid]=u;
  __syncthreads();
  // ---- stage 1: qkv = xf @ w_in^T + b_in  (4 fields x 3 cols per thread, f32x4 inner) --
  {
    const int fb=tid>>5, c0=(tid&31)*3;
    float a12[4][3];
    #pragma unroll
    for(int i=0;i<4;++i){
      #pragma unroll
      for(int j=0;j<3;++j) a12[i][j]=b_in[c0+j];
    }
    #pragma unroll
    for(int d=0;d<32;d+=4){
      f32x4 xv[4], wv[3];
      #pragma unroll
      for(int i=0;i<4;++i) xv[i]=*(const f32x4*)&xf[(fb+8*i)*32+d];
      #pragma unroll
      for(int j=0;j<3;++j) wv[j]=*(const f32x4*)&win[(c0+j)*36+d];
      #pragma unroll
      for(int i=0;i<4;++i){
        #pragma unroll
        for(int j=0;j<3;++j){
          #pragma unroll
          for(int e=0;e<4;++e) a12[i][j]+=xv[i][e]*wv[j][e];
        }
      }
    }
    #pragma unroll
    for(int i=0;i<4;++i){
      #pragma unroll
      for(int j=0;j<3;++j) qkv[(fb+8*i)*100+c0+j]=a12[i][j];
    }
  }
  __syncthreads();
  const int qp=tid>>4, d0=(tid&15)*2;
  const float scale=0.17677669529663687f;
  // ---- stage 2: scores (2q x 2k per thread), f32x4 inner ----
  {
    float s00=0,s01=0,s10=0,s11=0;
    #pragma unroll
    for(int d=0;d<32;d+=4){
      f32x4 qa=*(const f32x4*)&qkv[qp*100+d];
      f32x4 qb=*(const f32x4*)&qkv[(qp+16)*100+d];
      f32x4 ka=*(const f32x4*)&qkv[d0*100+32+d];
      f32x4 kb=*(const f32x4*)&qkv[(d0+1)*100+32+d];
      #pragma unroll
      for(int e=0;e<4;++e){ s00+=qa[e]*ka[e]; s01+=qa[e]*kb[e]; s10+=qb[e]*ka[e]; s11+=qb[e]*kb[e]; }
    }
    sc[qp*36+d0]=s00*scale; sc[qp*36+d0+1]=s01*scale;
    sc[(qp+16)*36+d0]=s10*scale; sc[(qp+16)*36+d0+1]=s11*scale;
  }
  __syncthreads();
  // ---- softmax: 8 lanes per row, f32x4 ----
  {
    const int r=tid>>3, sub=tid&7;
    f32x4 v0=*(const f32x4*)&sc[r*36+sub*4];
    float m=fmaxf(fmaxf(v0[0],v0[1]),fmaxf(v0[2],v0[3]));
    #pragma unroll
    for(int o=1;o<8;o<<=1) m=fmaxf(m,__shfl_xor(m,o));
    float den=0.f;
    #pragma unroll
    for(int jj=0;jj<4;++jj){ v0[jj]=__expf(v0[jj]-m); den+=v0[jj]; }
    #pragma unroll
    for(int o=1;o<8;o<<=1) den+=__shfl_xor(den,o);
    float inv=1.f/den;
    #pragma unroll
    for(int jj=0;jj<4;++jj) v0[jj]*=inv;
    *(f32x4*)&sc[r*36+sub*4]=v0;
  }
  __syncthreads();
  // ---- stage 3: av = P @ v (2q x 2d per thread, f32x2) ----
  {
    float s00=0,s01=0,s10=0,s11=0;
    #pragma unroll
    for(int k=0;k<32;k+=2){
      f32x2 pa=*(const f32x2*)&sc[qp*36+k];
      f32x2 pb=*(const f32x2*)&sc[(qp+16)*36+k];
      f32x2 v0=*(const f32x2*)&qkv[k*100+64+d0];
      f32x2 v1=*(const f32x2*)&qkv[(k+1)*100+64+d0];
      s00+=pa[0]*v0[0]+pa[1]*v1[0]; s01+=pa[0]*v0[1]+pa[1]*v1[1];
      s10+=pb[0]*v0[0]+pb[1]*v1[0]; s11+=pb[0]*v0[1]+pb[1]*v1[1];
    }
    *(f32x2*)&av[qp*36+d0]=f32x2{s00,s01};
    *(f32x2*)&av[(qp+16)*36+d0]=f32x2{s10,s11};
  }
  __syncthreads();
  // ---- stage 4: attf = av @ w_o^T + b_o; prod = attf * xf (into sc, stride 36) ----
  {
    float s00=b_o[d0], s01=b_o[d0+1], s10=b_o[d0], s11=b_o[d0+1];
    #pragma unroll
    for(int c=0;c<32;c+=4){
      f32x4 aa=*(const f32x4*)&av[qp*36+c];
      f32x4 ab=*(const f32x4*)&av[(qp+16)*36+c];
      f32x4 wa=*(const f32x4*)&wo[d0*36+c];
      f32x4 wb=*(const f32x4*)&wo[(d0+1)*36+c];
      #pragma unroll
      for(int e=0;e<4;++e){ s00+=aa[e]*wa[e]; s01+=aa[e]*wb[e]; s10+=ab[e]*wa[e]; s11+=ab[e]*wb[e]; }
    }
    f32x2 xa=*(const f32x2*)&xf[qp*32+d0];
    f32x2 xb=*(const f32x2*)&xf[(qp+16)*32+d0];
    *(f32x2*)&sc[qp*36+d0]     = f32x2{s00*xa[0], s01*xa[1]};
    *(f32x2*)&sc[(qp+16)*36+d0]= f32x2{s10*xb[0], s11*xb[1]};
  }
  __syncthreads();
  // ---- stage 5: e_cf = prod @ w_f^T + b_f; comb += w2 * e_cf ----
  {
    float s00=b_f[d0], s01=b_f[d0+1], s10=b_f[d0], s11=b_f[d0+1];
    #pragma unroll
    for(int c=0;c<32;c+=4){
      f32x4 pa=*(const f32x4*)&sc[qp*36+c];
      f32x4 pb=*(const f32x4*)&sc[(qp+16)*36+c];
      f32x4 wa=*(const f32x4*)&wf[d0*36+c];
      f32x4 wb=*(const f32x4*)&wf[(d0+1)*36+c];
      #pragma unroll
      for(int e=0;e<4;++e){ s00+=pa[e]*wa[e]; s01+=pa[e]*wb[e]; s10+=pb[e]*wa[e]; s11+=pb[e]*wb[e]; }
    }
    const float w2=wsel[row*6+2];
    float* cb=&comb[(size_t)row*1024];
    f32x2 c0v=*(f32x2*)&cb[qp*32+d0];
    c0v[0]+=w2*s00; c0v[1]+=w2*s01;
    *(f32x2*)&cb[qp*32+d0]=c0v;
    f32x2 c1v=*(f32x2*)&cb[(qp+16)*32+d0];
    c1v[0]+=w2*s10; c1v[1]+=w2*s11;
    *(f32x2*)&cb[(qp+16)*32+d0]=c1v;
  }
}

// ---------------- Temporal expert + final bf16 conversion ----------------
__global__ __launch_bounds__(256) void tp_kernel(const float* __restrict__ x,
    const float* __restrict__ wsel, const float* __restrict__ comb,
    const float* __restrict__ tcw, const float* __restrict__ tcb,
    const float* __restrict__ tfw, const float* __restrict__ tfb,
    u16* __restrict__ obf){
  __shared__ float xs[1026];
  const int row=blockIdx.x, tid=threadIdx.x;
  f32x4 u=((const f32x4*)(x+(size_t)row*1024))[tid];
  #pragma unroll
  for(int j=0;j<4;++j) xs[1+4*tid+j]=u[j];
  if(tid==0){ xs[0]=0.f; xs[1025]=0.f; }
  __syncthreads();
  const float w4=wsel[row*6+4];
  float tc[4][3], tb[4], tf[4];
  #pragma unroll
  for(int o=0;o<4;++o){
    #pragma unroll
    for(int kh=0;kh<3;++kh) tc[o][kh]=tcw[o*3+kh];
    tb[o]=tcb[o]; tf[o]=tfw[o];
  }
  const float tfb0=tfb[0];
  f32x4 cv=((const f32x4*)(comb+(size_t)row*1024))[tid];
  u16x4 ov;
  #pragma unroll
  for(int j=0;j<4;++j){
    const int d=4*tid+j;
    float pre=tfb0;
    #pragma unroll
    for(int o=0;o<4;++o){
      float c=tb[o]+tc[o][0]*xs[d]+tc[o][1]*xs[d+1]+tc[o][2]*xs[d+2];
      pre+=tf[o]*fmaxf(c,0.f);
    }
    float wt=1.f/(1.f+__expf(-pre));
    float xv=xs[1+d];
    ov[j]=f2bf(cv[j]+w4*xv*xv*wt);
  }
  ((u16x4*)(obf+(size_t)row*1024))[tid]=ov;
}

// =======================================================================================
extern "C" void kernel_launch(void* const* d_in, const int* in_sizes, int n_in,
                              void* d_out, int out_size, void* d_ws, size_t ws_size,
                              hipStream_t stream)
{
  const float* x     =(const float*)d_in[0];
  const float* esp   =(const float*)d_in[1];
  const float* sim_w1=(const float*)d_in[2],  *sim_b1=(const float*)d_in[3];
  const float* sim_w2=(const float*)d_in[4],  *sim_b2=(const float*)d_in[5];
  const float* rout_w1=(const float*)d_in[6], *rout_b1=(const float*)d_in[7];
  const float* rout_w2=(const float*)d_in[8], *rout_b2=(const float*)d_in[9];
  const float* kw1=(const float*)d_in[10], *kb1=(const float*)d_in[11];
  const float* kw2=(const float*)d_in[12], *kb2=(const float*)d_in[13];
  const float* spv_w=(const float*)d_in[14], *spv_b=(const float*)d_in[15];
  const float* spo_w=(const float*)d_in[16], *spo_b=(const float*)d_in[17];
  const float* spq1_w=(const float*)d_in[18], *spq1_b=(const float*)d_in[19];
  const float* spq2_w=(const float*)d_in[20], *spq2_b=(const float*)d_in[21];
  const float* de_w1=(const float*)d_in[22], *de_b1=(const float*)d_in[23];
  const float* de_w2=(const float*)d_in[24], *de_b2=(const float*)d_in[25];
  const float* de_gw=(const float*)d_in[26], *de_gb=(const float*)d_in[27];
  const float* cf_inw=(const float*)d_in[28], *cf_inb=(const float*)d_in[29];
  const float* cf_ow=(const float*)d_in[30], *cf_ob=(const float*)d_in[31];
  const float* cf_fw=(const float*)d_in[32], *cf_fb=(const float*)d_in[33];
  const float* hf_w1=(const float*)d_in[34], *hf_b1=(const float*)d_in[35];
  const float* hf_w2=(const float*)d_in[36], *hf_b2=(const float*)d_in[37];
  const float* tc_w=(const float*)d_in[38], *tc_b=(const float*)d_in[39];
  const float* tf_w=(const float*)d_in[40], *tf_b=(const float*)d_in[41];
  const float* lt_w1=(const float*)d_in[42], *lt_b1=(const float*)d_in[43];
  const float* lt_w2=(const float*)d_in[44], *lt_b2=(const float*)d_in[45];
  const float* op_w=(const float*)d_in[46], *op_b=(const float*)d_in[47];
  float* out=(float*)d_out;
  (void)in_sizes; (void)n_in; (void)out_size; (void)ws_size;

  constexpr int NB=8192;
  const size_t BD=(size_t)NB*1024;
  char* base=(char*)d_ws; size_t off=0;
  auto carve=[&](size_t n)->void*{ void* q=base+off; off+=(n+255)&~(size_t)255; return q; };
  float* comb =(float*)carve(BD*4);
  u16*  bufA =(u16*)carve(BD*2);
  u16*  bufB =(u16*)carve(BD*2);
  u16*  x_hi =(u16*)carve(BD*2);
  u16*  x_lo =(u16*)carve(BD*2);
  float* h512a=(float*)carve((size_t)NB*512*4);
  float* h512b=(float*)carve((size_t)NB*512*4);
  u16*  h256 =(u16*)carve((size_t)NB*256*2);
  u16* sw1h=(u16*)carve((size_t)512*1024*2);
  u16* sw1l=(u16*)carve((size_t)512*1024*2);
  u16* rw1h=(u16*)carve((size_t)512*1024*2);
  u16* rw1l=(u16*)carve((size_t)512*1024*2);
  u16* spv_bf =(u16*)carve((size_t)1024*1024*2);
  u16* spo_bf =(u16*)carve((size_t)1024*1024*2);
  u16* spq1_bf=(u16*)carve((size_t)1024*1024*2);
  u16* spq2_bf=(u16*)carve((size_t)1024*1024*2);
  u16* dew1_bf=(u16*)carve((size_t)256*1024*2);
  u16* dew2_bf=(u16*)carve((size_t)1024*256*2);
  u16* degw_bf=(u16*)carve((size_t)1024*1024*2);
  u16* hfw1_bf=(u16*)carve((size_t)256*1024*2);
  u16* hfw2_bf=(u16*)carve((size_t)1024*256*2);
  u16* ltw1_bf=(u16*)carve((size_t)256*1024*2);
  u16* ltw2_bf=(u16*)carve((size_t)1024*256*2);
  u16* opw_bf =(u16*)carve((size_t)1024*1024*2);
  float* spec=(float*)carve((size_t)NB*6*4);
  float* probs=(float*)carve((size_t)NB*6*4);
  float* wsel=(float*)carve((size_t)NB*6*4);
  float* kvals=(float*)carve((size_t)NB*4);
  int*   kint=(int*)carve(256);

  const dim3 blk(256);
  const dim3 gEW(2048);
  auto cgrid=[&](int n4)->dim3{ int g=(n4+255)/256; return dim3(g>2048?2048:g); };

  // ---- conversions (batched) ----
  cvt_split<<<cgrid(2097152),blk,0,stream>>>(x, x_hi, x_lo, 2097152);
  cvt_split<<<cgrid(131072),blk,0,stream>>>(sim_w1, sw1h, sw1l, 131072);
  cvt_split_rw1<<<cgrid(131072),blk,0,stream>>>(rout_w1, rw1h, rw1l);
  cvt6_kernel<<<cgrid(6*262144),blk,0,stream>>>(spv_w,spo_w,spq1_w,spq2_w,de_gw,op_w,
                                                spv_bf,spo_bf,spq1_bf,spq2_bf,degw_bf,opw_bf, 262144);
  cvt6_kernel<<<cgrid(6*65536),blk,0,stream>>>(de_w1,de_w2,hf_w1,hf_w2,lt_w1,lt_w2,
                                               dew1_bf,dew2_bf,hfw1_bf,hfw2_bf,ltw1_bf,ltw2_bf, 65536);

  // ---- routing pipeline (f32-accurate) ----
  feats_kernel<<<dim3(NB),blk,0,stream>>>(x, kw1,kb1,kw2,kb2, kvals);
  median_kernel<<<dim3(1),blk,0,stream>>>(kvals, kint);
  gemm_split<1><<<dim3(4,64),blk,0,stream>>>(x_hi,x_lo, sw1h,sw1l, sim_b1, h512a, NB,512,1024);
  spec_kernel<<<gEW,blk,0,stream>>>(x, h512a, esp, sim_w2, sim_b2, spec);
  gemm_split<0><<<dim3(4,64),blk,0,stream>>>(x_hi,x_lo, rw1h,rw1l, rout_b1, h512b, NB,512,1024);
  rout_fix<<<gEW,blk,0,stream>>>(h512b, spec, rout_w1);
  probs_kernel<<<gEW,blk,0,stream>>>(h512b, rout_w2, rout_b2, probs);
  gates_kernel<<<dim3(32),blk,0,stream>>>(probs, kint, wsel);

  // ---- expert 0: SparseQuadratic (spq2 writes comb = w0*v) ----
  gemm_bt<0,0><<<dim3(8,64),blk,0,stream>>>(x_hi, spv_bf, spv_b, nullptr, nullptr, nullptr, nullptr, bufA, NB,1024,1024);
  gemm_bt<0,2><<<dim3(8,64),blk,0,stream>>>(bufA, spo_bf, spo_b, nullptr, x, nullptr, nullptr, bufB, NB,1024,1024);
  gemm_bt<1,0><<<dim3(8,64),blk,0,stream>>>(bufB, spq1_bf, spq1_b, nullptr, nullptr, nullptr, nullptr, bufA, NB,1024,1024);
  gemm_bt<0,3><<<dim3(8,64),blk,0,stream>>>(bufA, spq2_bf, spq2_b, nullptr, nullptr, wsel, comb, nullptr, NB,1024,1024);

  // ---- expert 1: DenseQuadratic ----
  gemm_bt<1,0><<<dim3(2,64),blk,0,stream>>>(x_hi, dew1_bf, de_b1, nullptr, nullptr, nullptr, nullptr, h256, NB,256,1024);
  gemm_bt<2,0><<<dim3(8,64),blk,0,stream>>>(x_hi, degw_bf, de_gb, nullptr, nullptr, nullptr, nullptr, bufB, NB,1024,1024);
  gemm_bt<0,4><<<dim3(8,64),blk,0,stream>>>(h256, dew2_bf, de_b2, bufB, x, wsel, comb, nullptr, NB,1024,256);

  // ---- expert 2: CrossField (fused accumulate) ----
  cf_kernel<<<dim3(NB),blk,0,stream>>>(x, cf_inw, cf_inb, cf_ow, cf_ob, cf_fw, cf_fb, wsel, comb);

  // ---- expert 3: HighFreq ----
  gemm_bt<3,0><<<dim3(2,64),blk,0,stream>>>(x_hi, hfw1_bf, hf_b1, nullptr, nullptr, nullptr, nullptr, h256, NB,256,1024);
  gemm_bt<0,5><<<dim3(8,64),blk,0,stream>>>(h256, hfw2_bf, hf_b2, nullptr, x, wsel, comb, nullptr, NB,1024,256);

  // ---- expert 5: LongTail ----
  gemm_bt<4,0><<<dim3(2,64),blk,0,stream>>>(x_hi, ltw1_bf, lt_b1, nullptr, nullptr, nullptr, nullptr, h256, NB,256,1024);
  gemm_bt<0,6><<<dim3(8,64),blk,0,stream>>>(h256, ltw2_bf, lt_b2, nullptr, x, wsel, comb, nullptr, NB,1024,256);

  // ---- expert 4: Temporal (last comb reader) + final bf16 conversion ----
  tp_kernel<<<dim3(NB),blk,0,stream>>>(x, wsel, comb, tc_w, tc_b, tf_w, tf_b, bufB);

  // ---- output projection + residual (f32 out) ----
  gemm_bt<0,7><<<dim3(8,64),blk,0,stream>>>(bufB, opw_bf, op_b, nullptr, x, nullptr, nullptr, out, NB,1024,1024);
}

// Round 10
// 749.044 us; speedup vs baseline: 2.2589x; 1.0749x over previous
//
#include <hip/hip_runtime.h>
#include <stdint.h>

typedef unsigned short u16;
typedef __attribute__((ext_vector_type(2))) float f32x2;
typedef __attribute__((ext_vector_type(4))) float f32x4;
typedef __attribute__((ext_vector_type(4))) unsigned short u16x4;
typedef __attribute__((ext_vector_type(8))) short short8;

#define DEV static __device__ __forceinline__

DEV float bf2f(u16 u){ union{unsigned int i; float f;} v; v.i=((unsigned int)u)<<16; return v.f; }
DEV u16 f2bf(float f){ union{float f; unsigned int i;} v; v.f=f; unsigned int u=v.i;
  return (u16)((u + 0x7FFFu + ((u>>16)&1u))>>16); }
DEV float wred(float v){ for(int o=32;o;o>>=1) v += __shfl_xor(v,o); return v; }
DEV float wredmax(float v){ for(int o=32;o;o>>=1) v = fmaxf(v,__shfl_xor(v,o)); return v; }

DEV void gload16(const void* g, void* l){
  __builtin_amdgcn_global_load_lds((const __attribute__((address_space(1))) unsigned int*)g,
                                   (__attribute__((address_space(3))) unsigned int*)l, 16, 0, 0);
}

DEV float actf(int ACT, float v){
  if(ACT==1) return v>0.f?v:0.f;
  if(ACT==2) return 1.f/(1.f+__expf(-v));
  if(ACT==3) return tanhf(v);
  if(ACT==4) return v>0.f?v:(__expf(v)-1.f);
  return v;
}

// ---------------- f32 -> bf16 conversions ----------------
__global__ void cvt_kernel(const float* __restrict__ s, u16* __restrict__ d, int n4){
  for(int i=blockIdx.x*blockDim.x+threadIdx.x; i<n4; i+=gridDim.x*blockDim.x){
    f32x4 v=((const f32x4*)s)[i];
    u16x4 o;
    #pragma unroll
    for(int j=0;j<4;++j) o[j]=f2bf(v[j]);
    ((u16x4*)d)[i]=o;
  }
}

// batched: 6 equal-size pairs
__global__ void cvt6_kernel(
    const float* __restrict__ s0, const float* __restrict__ s1, const float* __restrict__ s2,
    const float* __restrict__ s3, const float* __restrict__ s4, const float* __restrict__ s5,
    u16* __restrict__ d0, u16* __restrict__ d1, u16* __restrict__ d2,
    u16* __restrict__ d3, u16* __restrict__ d4, u16* __restrict__ d5, int n4each){
  const float* ss[6]={s0,s1,s2,s3,s4,s5};
  u16* dd[6]={d0,d1,d2,d3,d4,d5};
  const int total=6*n4each;
  for(int i=blockIdx.x*blockDim.x+threadIdx.x; i<total; i+=gridDim.x*blockDim.x){
    int b=i/n4each, r=i-b*n4each;
    f32x4 v=((const f32x4*)ss[b])[r];
    u16x4 o;
    #pragma unroll
    for(int j=0;j<4;++j) o[j]=f2bf(v[j]);
    ((u16x4*)dd[b])[r]=o;
  }
}

// f32 -> (hi, lo) bf16 split
__global__ void cvt_split(const float* __restrict__ s, u16* __restrict__ hi, u16* __restrict__ lo, int n4){
  for(int i=blockIdx.x*blockDim.x+threadIdx.x; i<n4; i+=gridDim.x*blockDim.x){
    f32x4 v=((const f32x4*)s)[i];
    u16x4 h,l;
    #pragma unroll
    for(int j=0;j<4;++j){ h[j]=f2bf(v[j]); l[j]=f2bf(v[j]-bf2f(h[j])); }
    ((u16x4*)hi)[i]=h; ((u16x4*)lo)[i]=l;
  }
}

// pack+split rout_w1[:, :1024] (lda=1030 f32) into dense hi/lo 512x1024
__global__ void cvt_split_rw1(const float* __restrict__ src, u16* __restrict__ hi, u16* __restrict__ lo){
  for(int i=blockIdx.x*blockDim.x+threadIdx.x; i<512*1024; i+=gridDim.x*blockDim.x){
    int r=i>>10, c=i&1023;
    float v=src[(size_t)r*1030+c];
    u16 h=f2bf(v);
    hi[i]=h; lo[i]=f2bf(v-bf2f(h));
  }
}

// ---------------- GEMM: fused epilogues, global_load_lds staging ------------------------
// EPI 0: C bf16 = v           1: C f32 = v        2: C bf16 = v*xf      (spo: att*x)
//     3: comb  = w[0]*v       4: comb += w[1]*(v + gate*xf)             (de2)
//     5: comb += w[3]*(xf + (v-xf)*xf)            6: comb += w[5]*sgn(xf)*sqrt(|v*xf|+1e-8)
//     7: C f32 = v + xf (residual)
template<int ACT, int EPI>
__global__ __launch_bounds__(256) void gemm_bt(
    const u16* __restrict__ A, const u16* __restrict__ W,
    const float* __restrict__ bias, const u16* __restrict__ auxb,
    const float* __restrict__ auxf, const float* __restrict__ wsel,
    float* __restrict__ comb, void* __restrict__ Cv, int M, int N, int K)
{
  __shared__ __align__(16) u16 lA[128*64];
  __shared__ __align__(16) u16 lB[128*64];
  const int tid=threadIdx.x, lane=tid&63, wv=tid>>6;
  const int wr=wv>>1, wc=wv&1;
  const int bn=blockIdx.x*128, bm=blockIdx.y*128;
  f32x4 acc[4][4];
  #pragma unroll
  for(int m=0;m<4;++m){
    #pragma unroll
    for(int n=0;n<4;++n) acc[m][n]=(f32x4)0.f;
  }
  const int srow = wv*8 + (lane>>3);       // source row within 32-row chunk
  const int scol = (lane&7)*8;             // element col (8 bf16 = 16B)
  for(int kt=0;kt<K;kt+=64){
    #pragma unroll
    for(int i=0;i<4;++i){
      gload16(A + (size_t)(bm + i*32 + srow)*K + kt + scol, &lA[(i*32 + wv*8)*64]);
      gload16(W + (size_t)(bn + i*32 + srow)*K + kt + scol, &lB[(i*32 + wv*8)*64]);
    }
    __syncthreads();   // drains vmcnt: LDS writes visible
    #pragma unroll
    for(int kk=0;kk<2;++kk){
      const int fr=lane&15, kc=kk*32+(lane>>4)*8;
      short8 af[4], bfr[4];
      #pragma unroll
      for(int m=0;m<4;++m) af[m]=*(const short8*)&lA[(wr*64+m*16+fr)*64+kc];
      #pragma unroll
      for(int n=0;n<4;++n) bfr[n]=*(const short8*)&lB[(wc*64+n*16+fr)*64+kc];
      #pragma unroll
      for(int m=0;m<4;++m){
        #pragma unroll
        for(int n=0;n<4;++n)
          acc[m][n]=__builtin_amdgcn_mfma_f32_16x16x32_bf16(af[m],bfr[n],acc[m][n],0,0,0);
      }
    }
    __syncthreads();   // reads done before next iter's gload overwrites
  }
  const int fr=lane&15, fq=lane>>4;
  #pragma unroll
  for(int m=0;m<4;++m){
    #pragma unroll
    for(int n=0;n<4;++n){
      const int col = bn + wc*64 + n*16 + fr;
      const float bv = bias[col];
      #pragma unroll
      for(int j=0;j<4;++j){
        const int row = bm + wr*64 + m*16 + fq*4 + j;
        const size_t idx = (size_t)row*N+col;
        float v = acc[m][n][j] + bv;
        v = actf(ACT, v);
        if(EPI==0){ ((u16*)Cv)[idx]=f2bf(v); }
        else if(EPI==1){ ((float*)Cv)[idx]=v; }
        else if(EPI==2){ ((u16*)Cv)[idx]=f2bf(v*auxf[idx]); }
        else if(EPI==3){ comb[idx]=wsel[row*6+0]*v; }
        else if(EPI==4){ comb[idx]+=wsel[row*6+1]*(v + bf2f(auxb[idx])*auxf[idx]); }
        else if(EPI==5){ float x0=auxf[idx]; comb[idx]+=wsel[row*6+3]*(x0+(v-x0)*x0); }
        else if(EPI==6){
          float x0=auxf[idx];
          float sg=(x0>0.f)?1.f:((x0<0.f)?-1.f:0.f);
          comb[idx]+=wsel[row*6+5]*sg*sqrtf(fabsf(v*x0)+1e-8f);
        }
        else { ((float*)Cv)[idx]=v+auxf[idx]; }
      }
    }
  }
}

// ---------------- split-precision GEMM (f32-accurate): C = act(A@W^T + b), f32 out -----
template<int ACT>
__global__ __launch_bounds__(256) void gemm_split(
    const u16* __restrict__ Ah, const u16* __restrict__ Al,
    const u16* __restrict__ Wh, const u16* __restrict__ Wl,
    const float* __restrict__ bias, float* __restrict__ C, int M, int N, int K)
{
  const int LDL=40;
  __shared__ __align__(16) u16 lAh[128*40], lAl[128*40], lBh[128*40], lBl[128*40];
  const int tid=threadIdx.x, lane=tid&63, wv=tid>>6;
  const int wr=wv>>1, wc=wv&1;
  const int bn=blockIdx.x*128, bm=blockIdx.y*128;
  f32x4 acc[4][4];
  #pragma unroll
  for(int m=0;m<4;++m){
    #pragma unroll
    for(int n=0;n<4;++n) acc[m][n]=(f32x4)0.f;
  }
  const int srow=tid>>2, scol=(tid&3)*8;
  for(int kt=0;kt<K;kt+=32){
    short8 rah[2],ral[2],rbh[2],rbl[2];
    #pragma unroll
    for(int i=0;i<2;++i){
      size_t ao=(size_t)(bm+i*64+srow)*K+kt+scol;
      size_t bo=(size_t)(bn+i*64+srow)*K+kt+scol;
      rah[i]=*(const short8*)(Ah+ao); ral[i]=*(const short8*)(Al+ao);
      rbh[i]=*(const short8*)(Wh+bo); rbl[i]=*(const short8*)(Wl+bo);
    }
    __syncthreads();
    #pragma unroll
    for(int i=0;i<2;++i){
      int d=(i*64+srow)*LDL+scol;
      *(short8*)&lAh[d]=rah[i]; *(short8*)&lAl[d]=ral[i];
      *(short8*)&lBh[d]=rbh[i]; *(short8*)&lBl[d]=rbl[i];
    }
    __syncthreads();
    const int fr=lane&15, kc=(lane>>4)*8;
    short8 ah[4],al[4],bh[4],bl[4];
    #pragma unroll
    for(int m=0;m<4;++m){ int r=(wr*64+m*16+fr)*LDL+kc; ah[m]=*(const short8*)&lAh[r]; al[m]=*(const short8*)&lAl[r]; }
    #pragma unroll
    for(int n=0;n<4;++n){ int r=(wc*64+n*16+fr)*LDL+kc; bh[n]=*(const short8*)&lBh[r]; bl[n]=*(const short8*)&lBl[r]; }
    #pragma unroll
    for(int m=0;m<4;++m){
      #pragma unroll
      for(int n=0;n<4;++n){
        acc[m][n]=__builtin_amdgcn_mfma_f32_16x16x32_bf16(ah[m],bh[n],acc[m][n],0,0,0);
        acc[m][n]=__builtin_amdgcn_mfma_f32_16x16x32_bf16(ah[m],bl[n],acc[m][n],0,0,0);
        acc[m][n]=__builtin_amdgcn_mfma_f32_16x16x32_bf16(al[m],bh[n],acc[m][n],0,0,0);
        acc[m][n]=__builtin_amdgcn_mfma_f32_16x16x32_bf16(al[m],bl[n],acc[m][n],0,0,0);
      }
    }
  }
  const int fr=lane&15, fq=lane>>4;
  #pragma unroll
  for(int m=0;m<4;++m){
    #pragma unroll
    for(int n=0;n<4;++n){
      const int col = bn + wc*64 + n*16 + fr;
      const float bv = bias[col];
      #pragma unroll
      for(int j=0;j<4;++j){
        const int row = bm + wr*64 + m*16 + fq*4 + j;
        C[(size_t)row*N+col] = actf(ACT, acc[m][n][j] + bv);
      }
    }
  }
}

// ---------------- feature stats + kpred MLP -> k_vals[row] (all f32) ----------------
// top-204 selection via exact 4-level radix select (replaces 31-iter binary search)
__global__ __launch_bounds__(256) void feats_kernel(const float* __restrict__ x,
    const float* __restrict__ kw1, const float* __restrict__ kb1,
    const float* __restrict__ kw2, const float* __restrict__ kb2,
    float* __restrict__ kvals)
{
  __shared__ float xs[1024];
  __shared__ unsigned int cd[1024];
  __shared__ float rbuf[4*6];
  __shared__ float r2[4], r3[4];
  __shared__ float bres[6];
  __shared__ int hist[256];
  __shared__ unsigned int selT;
  __shared__ int selR;
  const int tid=threadIdx.x, lane=tid&63, wv=tid>>6;
  const int row=blockIdx.x;
  f32x4 u = ((const f32x4*)(x+(size_t)row*1024))[tid];
  float s=0.f, ss=0.f, amax=0.f, sa=0.f; float nz=0.f;
  #pragma unroll
  for(int j=0;j<4;++j){
    float f=u[j];
    union{float f;unsigned int i;} cv; cv.f=f;
    xs[4*tid+j]=f; cd[4*tid+j]=cv.i&0x7fffffffu;
    s+=f; ss+=f*f; float a=fabsf(f); sa+=a; amax=fmaxf(amax,a); if(f==0.f) nz+=1.f;
  }
  s=wred(s); ss=wred(ss); sa=wred(sa); nz=wred(nz); amax=wredmax(amax);
  if(lane==0){ rbuf[wv*6+0]=s; rbuf[wv*6+1]=ss; rbuf[wv*6+2]=sa; rbuf[wv*6+3]=nz; rbuf[wv*6+4]=amax; }
  __syncthreads();
  if(tid==0){
    float S=0,SS=0,SA=0,NZ=0,AM=0;
    for(int i=0;i<4;++i){ S+=rbuf[i*6]; SS+=rbuf[i*6+1]; SA+=rbuf[i*6+2]; NZ+=rbuf[i*6+3]; AM=fmaxf(AM,rbuf[i*6+4]); }
    bres[0]=S; bres[1]=SS; bres[2]=SA; bres[3]=NZ; bres[4]=AM;
  }
  __syncthreads();
  const float S=bres[0], SS=bres[1], SA=bres[2], NZ=bres[3], AM=bres[4];
  const float mean=S/1024.f;
  const float var=(SS - S*mean)/1023.f;
  const float inv=1.f/sqrtf(var+1e-8f);
  float sk=0.f;
  #pragma unroll
  for(int j=0;j<4;++j){ float z=(xs[4*tid+j]-mean)*inv; sk+=z*z*z; }
  sk=wred(sk);
  if(lane==0) rbuf[wv*6+5]=sk;
  // ---- radix select: T = 204th largest abs-code (== max t with count(>=t) >= 204) ----
  unsigned int prefix=0u; int r=204;
  #pragma unroll
  for(int lvl=0;lvl<4;++lvl){
    const int shift=24-lvl*8;
    const unsigned int pmask = (lvl==0)?0u:(0xFFFFFFFFu<<(shift+8));
    hist[tid]=0;
    __syncthreads();
    #pragma unroll
    for(int j=0;j<4;++j){
      unsigned int c=cd[4*tid+j];
      if((c&pmask)==prefix) atomicAdd(&hist[(c>>shift)&0xFFu],1);
    }
    __syncthreads();
    if(wv==0){
      int h[4]; int ls=0;
      #pragma unroll
      for(int b=0;b<4;++b){ h[b]=hist[lane*4+b]; ls+=h[b]; }
      int pfx=ls;
      #pragma unroll
      for(int off=1;off<64;off<<=1){ int t=__shfl_up(pfx,off); if(lane>=off) pfx+=t; }
      int total=__shfl(pfx,63);
      int cgt = total - pfx;      // codes in bins of lanes > mine
      #pragma unroll
      for(int b=3;b>=0;--b){
        if(cgt < r && r <= cgt + h[b]){
          selT = prefix | ((unsigned int)(lane*4+b)<<shift);
          selR = r - cgt;
        }
        cgt += h[b];
      }
    }
    __syncthreads();
    prefix=selT; r=selR;
  }
  const unsigned int T=prefix;
  float sg=0.f; float cg=0.f;
  #pragma unroll
  for(int j=0;j<4;++j){ if(cd[4*tid+j] > T){ sg+=fabsf(xs[4*tid+j]); cg+=1.f; } }
  sg=wred(sg); cg=wred(cg);
  if(lane==0){ r2[wv]=sg; r3[wv]=cg; }
  __syncthreads();
  if(tid==0){
    float SK=rbuf[5]+rbuf[11]+rbuf[17]+rbuf[23];
    float SG=r2[0]+r2[1]+r2[2]+r2[3];
    float CG=r3[0]+r3[1]+r3[2]+r3[3];
    union{unsigned int i;float f;} tv; tv.i=T;
    float conc=(SG + (204.f-CG)*tv.f)/(SA + 1e-8f);
    float feats[6]={ NZ/1024.f, var, AM, sqrtf(SS), SK/1024.f, conc };
    float out=kb2[0];
    #pragma unroll
    for(int i=0;i<16;++i){
      float hv=kb1[i];
      #pragma unroll
      for(int j=0;j<6;++j) hv+=kw1[i*6+j]*feats[j];
      hv=fmaxf(hv,0.f);
      out+=kw2[i]*hv;
    }
    kvals[row]=1.f + 3.f*(1.f/(1.f+__expf(-out)));
  }
}

// ---------------- exact median of 8192 -> k (radix select ×2) ----------------
__global__ __launch_bounds__(256) void median_kernel(const float* __restrict__ kvals, int* __restrict__ kint){
  __shared__ unsigned int v[8192];
  __shared__ int hist[256];
  __shared__ unsigned int selT;
  __shared__ int selR;
  const int tid=threadIdx.x, lane=tid&63, wv=tid>>6;
  for(int i=tid;i<8192;i+=256){ union{float f;unsigned int u;} c; c.f=kvals[i]; v[i]=c.u; }
  __syncthreads();
  unsigned int res[2];
  for(int t=0;t<2;++t){
    // kth smallest s = 4096+t  ->  rank among largest r = 8192 - s + 1
    int r = 8192 - (4096+t) + 1;
    unsigned int prefix=0u;
    for(int lvl=0;lvl<4;++lvl){
      const int shift=24-lvl*8;
      const unsigned int pmask = (lvl==0)?0u:(0xFFFFFFFFu<<(shift+8));
      hist[tid]=0;
      __syncthreads();
      for(int i=tid;i<8192;i+=256){
        unsigned int c=v[i];
        if((c&pmask)==prefix) atomicAdd(&hist[(c>>shift)&0xFFu],1);
      }
      __syncthreads();
      if(wv==0){
        int h[4]; int ls=0;
        #pragma unroll
        for(int b=0;b<4;++b){ h[b]=hist[lane*4+b]; ls+=h[b]; }
        int pfx=ls;
        #pragma unroll
        for(int off=1;off<64;off<<=1){ int tt=__shfl_up(pfx,off); if(lane>=off) pfx+=tt; }
        int total=__shfl(pfx,63);
        int cgt = total - pfx;
        #pragma unroll
        for(int b=3;b>=0;--b){
          if(cgt < r && r <= cgt + h[b]){
            selT = prefix | ((unsigned int)(lane*4+b)<<shift);
            selR = r - cgt;
          }
          cgt += h[b];
        }
      }
      __syncthreads();
      prefix=selT; r=selR;
      __syncthreads();
    }
    res[t]=prefix;
  }
  if(tid==0){
    union{unsigned int u; float f;} a,b; a.u=res[0]; b.u=res[1];
    float med=0.5f*(a.f+b.f);
    int k=(int)floorf(med);
    k = k<1?1:(k>4?4:k);
    *kint=k;
  }
}

// ---------------- spec = sigmoid(x@esp^T + h512a@sim_w2^T + sim_b2), one wave/row ------
__global__ __launch_bounds__(256) void spec_kernel(const float* __restrict__ x, const float* __restrict__ h,
    const float* __restrict__ esp, const float* __restrict__ w2, const float* __restrict__ b2,
    float* __restrict__ spec){
  const int wv=threadIdx.x>>6, lane=threadIdx.x&63;
  const int row=blockIdx.x*4+wv;
  const float* xr=x+(size_t)row*1024;
  const float* hr=h+(size_t)row*512;
  float xv[16], hv[8];
  #pragma unroll
  for(int j=0;j<16;++j) xv[j]=xr[j*64+lane];
  #pragma unroll
  for(int j=0;j<8;++j) hv[j]=hr[j*64+lane];
  for(int e=0;e<6;++e){
    float s=0.f;
    #pragma unroll
    for(int j=0;j<16;++j) s+=xv[j]*esp[e*1024+j*64+lane];
    #pragma unroll
    for(int j=0;j<8;++j) s+=hv[j]*w2[e*512+j*64+lane];
    s=wred(s);
    if(lane==0) spec[row*6+e]=1.f/(1.f+__expf(-(s+b2[e])));
  }
}

// ---------------- rout pre-act += spec @ rw1[:,1024:]^T, relu (f32 h) ----------------
__global__ void rout_fix(float* __restrict__ h, const float* __restrict__ spec, const float* __restrict__ rw1){
  const int total=8192*128;
  for(int i=blockIdx.x*blockDim.x+threadIdx.x;i<total;i+=gridDim.x*blockDim.x){
    int row=i>>7, j0=(i&127)*4;
    const float* sp=&spec[row*6];
    f32x4 hv=((f32x4*)h)[i];
    #pragma unroll
    for(int j=0;j<4;++j){
      float v=hv[j];
      int col=j0+j;
      #pragma unroll
      for(int e=0;e<6;++e) v+=sp[e]*rw1[(size_t)col*1030+1024+e];
      hv[j]=fmaxf(v,0.f);
    }
    ((f32x4*)h)[i]=hv;
  }
}

// ---------------- probs = softmax(h512b@rout_w2^T + rout_b2), one wave per row ----------
__global__ __launch_bounds__(256) void probs_kernel(const float* __restrict__ h, const float* __restrict__ w2,
    const float* __restrict__ b2, float* __restrict__ probs){
  const int wv=threadIdx.x>>6, lane=threadIdx.x&63;
  const int row=blockIdx.x*4+wv;
  const float* hr=h+(size_t)row*512;
  float hv[8];
  #pragma unroll
  for(int j=0;j<8;++j) hv[j]=hr[j*64+lane];
  float lg[6];
  #pragma unroll
  for(int e=0;e<6;++e){
    float s=0.f;
    #pragma unroll
    for(int j=0;j<8;++j) s+=hv[j]*w2[e*512+j*64+lane];
    lg[e]=wred(s)+b2[e];
  }
  if(lane==0){
    float m=lg[0];
    #pragma unroll
    for(int e=1;e<6;++e) m=fmaxf(m,lg[e]);
    float den=0.f, ex[6];
    #pragma unroll
    for(int e=0;e<6;++e){ ex[e]=__expf(lg[e]-m); den+=ex[e]; }
    #pragma unroll
    for(int e=0;e<6;++e) probs[row*6+e]=ex[e]/den;
  }
}

// ---------------- top-4 + gates -> per-expert weights ----------------
__global__ void gates_kernel(const float* __restrict__ probs, const int* __restrict__ kint,
                             float* __restrict__ wsel){
  const int r=blockIdx.x*blockDim.x+threadIdx.x;
  if(r>=8192) return;
  const int k=*kint;
  float p[6];
  #pragma unroll
  for(int e=0;e<6;++e) p[e]=probs[r*6+e];
  float w[6]={0,0,0,0,0,0};
  bool used[6]={false,false,false,false,false,false};
  int idx[4]; float val[4];
  #pragma unroll
  for(int j=0;j<4;++j){
    int bi=0; float bv=-1e30f;
    #pragma unroll
    for(int e=0;e<6;++e) if(!used[e] && p[e]>bv){ bv=p[e]; bi=e; }
    used[bi]=true; idx[j]=bi; val[j]=bv;
  }
  float m=val[0], den=0.f, g[4]={0,0,0,0};
  for(int j=0;j<k;++j){ g[j]=__expf(val[j]-m); den+=g[j]; }
  for(int j=0;j<k;++j) w[idx[j]]=g[j]/den;
  #pragma unroll
  for(int e=0;e<6;++e) wsel[r*6+e]=w[e];
}

// ---------------- CrossField expert: vectorized LDS (b128/b64), fused accumulate --------
__global__ __launch_bounds__(256) void cf_kernel(const float* __restrict__ x,
    const float* __restrict__ w_in, const float* __restrict__ b_in,
    const float* __restrict__ w_o, const float* __restrict__ b_o,
    const float* __restrict__ w_f, const float* __restrict__ b_f,
    const float* __restrict__ wsel, float* __restrict__ comb){
  __shared__ __align__(16) float pool[11136];
  float* xf  = pool;          // 32x32 (stride 32)
  float* qkv = pool+1024;     // 32 x stride 100 (16B-aligned rows)
  float* sc  = pool+4224;     // 32 x stride 36  (P, then prod)
  float* win = pool+5376;     // 96 x stride 36 (stage1 only)
  float* av  = pool+5376;     // 32 x stride 36 (overlays win after stage1)
  float* wo  = pool+8832;     // 32 x stride 36
  float* wf  = pool+9984;     // 32 x stride 36
  const int row=blockIdx.x, tid=threadIdx.x;
  for(int i=tid;i<3072;i+=256) win[(i>>5)*36+(i&31)]=w_in[i];
  for(int i=tid;i<1024;i+=256){ wo[(i>>5)*36+(i&31)]=w_o[i]; wf[(i>>5)*36+(i&31)]=w_f[i]; }
  f32x4 u=((const f32x4*)(x+(size_t)row*1024))[tid];
  *(f32x4*)&xf[4*tid]=u;
  __syncthreads();
  // ---- stage 1: qkv = xf @ w_in^T + b_in  (4 fields x 3 cols per thread, f32x4 inner) --
  {
    const int fb=tid>>5, c0=(tid&31)*3;
    float a12[4][3];
    #pragma unroll
    for(int i=0;i<4;++i){
      #pragma unroll
      for(int j=0;j<3;++j) a12[i][j]=b_in[c0+j];
    }
    #pragma unroll
    for(int d=0;d<32;d+=4){
      f32x4 xv[4], wv[3];
      #pragma unroll
      for(int i=0;i<4;++i) xv[i]=*(const f32x4*)&xf[(fb+8*i)*32+d];
      #pragma unroll
      for(int j=0;j<3;++j) wv[j]=*(const f32x4*)&win[(c0+j)*36+d];
      #pragma unroll
      for(int i=0;i<4;++i){
        #pragma unroll
        for(int j=0;j<3;++j){
          #pragma unroll
          for(int e=0;e<4;++e) a12[i][j]+=xv[i][e]*wv[j][e];
        }
      }
    }
    #pragma unroll
    for(int i=0;i<4;++i){
      #pragma unroll
      for(int j=0;j<3;++j) qkv[(fb+8*i)*100+c0+j]=a12[i][j];
    }
  }
  __syncthreads();
  const int qp=tid>>4, d0=(tid&15)*2;
  const float scale=0.17677669529663687f;
  // ---- stage 2: scores (2q x 2k per thread), f32x4 inner ----
  {
    float s00=0,s01=0,s10=0,s11=0;
    #pragma unroll
    for(int d=0;d<32;d+=4){
      f32x4 qa=*(const f32x4*)&qkv[qp*100+d];
      f32x4 qb=*(const f32x4*)&qkv[(qp+16)*100+d];
      f32x4 ka=*(const f32x4*)&qkv[d0*100+32+d];
      f32x4 kb=*(const f32x4*)&qkv[(d0+1)*100+32+d];
      #pragma unroll
      for(int e=0;e<4;++e){ s00+=qa[e]*ka[e]; s01+=qa[e]*kb[e]; s10+=qb[e]*ka[e]; s11+=qb[e]*kb[e]; }
    }
    sc[qp*36+d0]=s00*scale; sc[qp*36+d0+1]=s01*scale;
    sc[(qp+16)*36+d0]=s10*scale; sc[(qp+16)*36+d0+1]=s11*scale;
  }
  __syncthreads();
  // ---- softmax: 8 lanes per row, f32x4 ----
  {
    const int r=tid>>3, sub=tid&7;
    f32x4 v0=*(const f32x4*)&sc[r*36+sub*4];
    float m=fmaxf(fmaxf(v0[0],v0[1]),fmaxf(v0[2],v0[3]));
    #pragma unroll
    for(int o=1;o<8;o<<=1) m=fmaxf(m,__shfl_xor(m,o));
    float den=0.f;
    #pragma unroll
    for(int jj=0;jj<4;++jj){ v0[jj]=__expf(v0[jj]-m); den+=v0[jj]; }
    #pragma unroll
    for(int o=1;o<8;o<<=1) den+=__shfl_xor(den,o);
    float inv=1.f/den;
    #pragma unroll
    for(int jj=0;jj<4;++jj) v0[jj]*=inv;
    *(f32x4*)&sc[r*36+sub*4]=v0;
  }
  __syncthreads();
  // ---- stage 3: av = P @ v (2q x 2d per thread, f32x2) ----
  {
    float s00=0,s01=0,s10=0,s11=0;
    #pragma unroll
    for(int k=0;k<32;k+=2){
      f32x2 pa=*(const f32x2*)&sc[qp*36+k];
      f32x2 pb=*(const f32x2*)&sc[(qp+16)*36+k];
      f32x2 v0=*(const f32x2*)&qkv[k*100+64+d0];
      f32x2 v1=*(const f32x2*)&qkv[(k+1)*100+64+d0];
      s00+=pa[0]*v0[0]+pa[1]*v1[0]; s01+=pa[0]*v0[1]+pa[1]*v1[1];
      s10+=pb[0]*v0[0]+pb[1]*v1[0]; s11+=pb[0]*v0[1]+pb[1]*v1[1];
    }
    *(f32x2*)&av[qp*36+d0]=f32x2{s00,s01};
    *(f32x2*)&av[(qp+16)*36+d0]=f32x2{s10,s11};
  }
  __syncthreads();
  // ---- stage 4: attf = av @ w_o^T + b_o; prod = attf * xf (into sc, stride 36) ----
  {
    float s00=b_o[d0], s01=b_o[d0+1], s10=b_o[d0], s11=b_o[d0+1];
    #pragma unroll
    for(int c=0;c<32;c+=4){
      f32x4 aa=*(const f32x4*)&av[qp*36+c];
      f32x4 ab=*(const f32x4*)&av[(qp+16)*36+c];
      f32x4 wa=*(const f32x4*)&wo[d0*36+c];
      f32x4 wb=*(const f32x4*)&wo[(d0+1)*36+c];
      #pragma unroll
      for(int e=0;e<4;++e){ s00+=aa[e]*wa[e]; s01+=aa[e]*wb[e]; s10+=ab[e]*wa[e]; s11+=ab[e]*wb[e]; }
    }
    f32x2 xa=*(const f32x2*)&xf[qp*32+d0];
    f32x2 xb=*(const f32x2*)&xf[(qp+16)*32+d0];
    *(f32x2*)&sc[qp*36+d0]     = f32x2{s00*xa[0], s01*xa[1]};
    *(f32x2*)&sc[(qp+16)*36+d0]= f32x2{s10*xb[0], s11*xb[1]};
  }
  __syncthreads();
  // ---- stage 5: e_cf = prod @ w_f^T + b_f; comb += w2 * e_cf ----
  {
    float s00=b_f[d0], s01=b_f[d0+1], s10=b_f[d0], s11=b_f[d0+1];
    #pragma unroll
    for(int c=0;c<32;c+=4){
      f32x4 pa=*(const f32x4*)&sc[qp*36+c];
      f32x4 pb=*(const f32x4*)&sc[(qp+16)*36+c];
      f32x4 wa=*(const f32x4*)&wf[d0*36+c];
      f32x4 wb=*(const f32x4*)&wf[(d0+1)*36+c];
      #pragma unroll
      for(int e=0;e<4;++e){ s00+=pa[e]*wa[e]; s01+=pa[e]*wb[e]; s10+=pb[e]*wa[e]; s11+=pb[e]*wb[e]; }
    }
    const float w2=wsel[row*6+2];
    float* cb=&comb[(size_t)row*1024];
    f32x2 c0v=*(f32x2*)&cb[qp*32+d0];
    c0v[0]+=w2*s00; c0v[1]+=w2*s01;
    *(f32x2*)&cb[qp*32+d0]=c0v;
    f32x2 c1v=*(f32x2*)&cb[(qp+16)*32+d0];
    c1v[0]+=w2*s10; c1v[1]+=w2*s11;
    *(f32x2*)&cb[(qp+16)*32+d0]=c1v;
  }
}

// ---------------- Temporal expert + final bf16 conversion ----------------
__global__ __launch_bounds__(256) void tp_kernel(const float* __restrict__ x,
    const float* __restrict__ wsel, const float* __restrict__ comb,
    const float* __restrict__ tcw, const float* __restrict__ tcb,
    const float* __restrict__ tfw, const float* __restrict__ tfb,
    u16* __restrict__ obf){
  __shared__ float xs[1026];
  const int row=blockIdx.x, tid=threadIdx.x;
  f32x4 u=((const f32x4*)(x+(size_t)row*1024))[tid];
  #pragma unroll
  for(int j=0;j<4;++j) xs[1+4*tid+j]=u[j];
  if(tid==0){ xs[0]=0.f; xs[1025]=0.f; }
  __syncthreads();
  const float w4=wsel[row*6+4];
  float tc[4][3], tb[4], tf[4];
  #pragma unroll
  for(int o=0;o<4;++o){
    #pragma unroll
    for(int kh=0;kh<3;++kh) tc[o][kh]=tcw[o*3+kh];
    tb[o]=tcb[o]; tf[o]=tfw[o];
  }
  const float tfb0=tfb[0];
  f32x4 cv=((const f32x4*)(comb+(size_t)row*1024))[tid];
  u16x4 ov;
  #pragma unroll
  for(int j=0;j<4;++j){
    const int d=4*tid+j;
    float pre=tfb0;
    #pragma unroll
    for(int o=0;o<4;++o){
      float c=tb[o]+tc[o][0]*xs[d]+tc[o][1]*xs[d+1]+tc[o][2]*xs[d+2];
      pre+=tf[o]*fmaxf(c,0.f);
    }
    float wt=1.f/(1.f+__expf(-pre));
    float xv=xs[1+d];
    ov[j]=f2bf(cv[j]+w4*xv*xv*wt);
  }
  ((u16x4*)(obf+(size_t)row*1024))[tid]=ov;
}

// =======================================================================================
extern "C" void kernel_launch(void* const* d_in, const int* in_sizes, int n_in,
                              void* d_out, int out_size, void* d_ws, size_t ws_size,
                              hipStream_t stream)
{
  const float* x     =(const float*)d_in[0];
  const float* esp   =(const float*)d_in[1];
  const float* sim_w1=(const float*)d_in[2],  *sim_b1=(const float*)d_in[3];
  const float* sim_w2=(const float*)d_in[4],  *sim_b2=(const float*)d_in[5];
  const float* rout_w1=(const float*)d_in[6], *rout_b1=(const float*)d_in[7];
  const float* rout_w2=(const float*)d_in[8], *rout_b2=(const float*)d_in[9];
  const float* kw1=(const float*)d_in[10], *kb1=(const float*)d_in[11];
  const float* kw2=(const float*)d_in[12], *kb2=(const float*)d_in[13];
  const float* spv_w=(const float*)d_in[14], *spv_b=(const float*)d_in[15];
  const float* spo_w=(const float*)d_in[16], *spo_b=(const float*)d_in[17];
  const float* spq1_w=(const float*)d_in[18], *spq1_b=(const float*)d_in[19];
  const float* spq2_w=(const float*)d_in[20], *spq2_b=(const float*)d_in[21];
  const float* de_w1=(const float*)d_in[22], *de_b1=(const float*)d_in[23];
  const float* de_w2=(const float*)d_in[24], *de_b2=(const float*)d_in[25];
  const float* de_gw=(const float*)d_in[26], *de_gb=(const float*)d_in[27];
  const float* cf_inw=(const float*)d_in[28], *cf_inb=(const float*)d_in[29];
  const float* cf_ow=(const float*)d_in[30], *cf_ob=(const float*)d_in[31];
  const float* cf_fw=(const float*)d_in[32], *cf_fb=(const float*)d_in[33];
  const float* hf_w1=(const float*)d_in[34], *hf_b1=(const float*)d_in[35];
  const float* hf_w2=(const float*)d_in[36], *hf_b2=(const float*)d_in[37];
  const float* tc_w=(const float*)d_in[38], *tc_b=(const float*)d_in[39];
  const float* tf_w=(const float*)d_in[40], *tf_b=(const float*)d_in[41];
  const float* lt_w1=(const float*)d_in[42], *lt_b1=(const float*)d_in[43];
  const float* lt_w2=(const float*)d_in[44], *lt_b2=(const float*)d_in[45];
  const float* op_w=(const float*)d_in[46], *op_b=(const float*)d_in[47];
  float* out=(float*)d_out;
  (void)in_sizes; (void)n_in; (void)out_size; (void)ws_size;

  constexpr int NB=8192;
  const size_t BD=(size_t)NB*1024;
  char* base=(char*)d_ws; size_t off=0;
  auto carve=[&](size_t n)->void*{ void* q=base+off; off+=(n+255)&~(size_t)255; return q; };
  float* comb =(float*)carve(BD*4);
  u16*  bufA =(u16*)carve(BD*2);
  u16*  bufB =(u16*)carve(BD*2);
  u16*  x_hi =(u16*)carve(BD*2);
  u16*  x_lo =(u16*)carve(BD*2);
  float* h512a=(float*)carve((size_t)NB*512*4);
  float* h512b=(float*)carve((size_t)NB*512*4);
  u16*  h256 =(u16*)carve((size_t)NB*256*2);
  u16* sw1h=(u16*)carve((size_t)512*1024*2);
  u16* sw1l=(u16*)carve((size_t)512*1024*2);
  u16* rw1h=(u16*)carve((size_t)512*1024*2);
  u16* rw1l=(u16*)carve((size_t)512*1024*2);
  u16* spv_bf =(u16*)carve((size_t)1024*1024*2);
  u16* spo_bf =(u16*)carve((size_t)1024*1024*2);
  u16* spq1_bf=(u16*)carve((size_t)1024*1024*2);
  u16* spq2_bf=(u16*)carve((size_t)1024*1024*2);
  u16* dew1_bf=(u16*)carve((size_t)256*1024*2);
  u16* dew2_bf=(u16*)carve((size_t)1024*256*2);
  u16* degw_bf=(u16*)carve((size_t)1024*1024*2);
  u16* hfw1_bf=(u16*)carve((size_t)256*1024*2);
  u16* hfw2_bf=(u16*)carve((size_t)1024*256*2);
  u16* ltw1_bf=(u16*)carve((size_t)256*1024*2);
  u16* ltw2_bf=(u16*)carve((size_t)1024*256*2);
  u16* opw_bf =(u16*)carve((size_t)1024*1024*2);
  float* spec=(float*)carve((size_t)NB*6*4);
  float* probs=(float*)carve((size_t)NB*6*4);
  float* wsel=(float*)carve((size_t)NB*6*4);
  float* kvals=(float*)carve((size_t)NB*4);
  int*   kint=(int*)carve(256);

  const dim3 blk(256);
  const dim3 gEW(2048);
  auto cgrid=[&](int n4)->dim3{ int g=(n4+255)/256; return dim3(g>2048?2048:g); };

  // ---- conversions (batched) ----
  cvt_split<<<cgrid(2097152),blk,0,stream>>>(x, x_hi, x_lo, 2097152);
  cvt_split<<<cgrid(131072),blk,0,stream>>>(sim_w1, sw1h, sw1l, 131072);
  cvt_split_rw1<<<cgrid(131072),blk,0,stream>>>(rout_w1, rw1h, rw1l);
  cvt6_kernel<<<cgrid(6*262144),blk,0,stream>>>(spv_w,spo_w,spq1_w,spq2_w,de_gw,op_w,
                                                spv_bf,spo_bf,spq1_bf,spq2_bf,degw_bf,opw_bf, 262144);
  cvt6_kernel<<<cgrid(6*65536),blk,0,stream>>>(de_w1,de_w2,hf_w1,hf_w2,lt_w1,lt_w2,
                                               dew1_bf,dew2_bf,hfw1_bf,hfw2_bf,ltw1_bf,ltw2_bf, 65536);

  // ---- routing pipeline (f32-accurate) ----
  feats_kernel<<<dim3(NB),blk,0,stream>>>(x, kw1,kb1,kw2,kb2, kvals);
  median_kernel<<<dim3(1),blk,0,stream>>>(kvals, kint);
  gemm_split<1><<<dim3(4,64),blk,0,stream>>>(x_hi,x_lo, sw1h,sw1l, sim_b1, h512a, NB,512,1024);
  spec_kernel<<<gEW,blk,0,stream>>>(x, h512a, esp, sim_w2, sim_b2, spec);
  gemm_split<0><<<dim3(4,64),blk,0,stream>>>(x_hi,x_lo, rw1h,rw1l, rout_b1, h512b, NB,512,1024);
  rout_fix<<<gEW,blk,0,stream>>>(h512b, spec, rout_w1);
  probs_kernel<<<gEW,blk,0,stream>>>(h512b, rout_w2, rout_b2, probs);
  gates_kernel<<<dim3(32),blk,0,stream>>>(probs, kint, wsel);

  // ---- expert 0: SparseQuadratic (spq2 writes comb = w0*v) ----
  gemm_bt<0,0><<<dim3(8,64),blk,0,stream>>>(x_hi, spv_bf, spv_b, nullptr, nullptr, nullptr, nullptr, bufA, NB,1024,1024);
  gemm_bt<0,2><<<dim3(8,64),blk,0,stream>>>(bufA, spo_bf, spo_b, nullptr, x, nullptr, nullptr, bufB, NB,1024,1024);
  gemm_bt<1,0><<<dim3(8,64),blk,0,stream>>>(bufB, spq1_bf, spq1_b, nullptr, nullptr, nullptr, nullptr, bufA, NB,1024,1024);
  gemm_bt<0,3><<<dim3(8,64),blk,0,stream>>>(bufA, spq2_bf, spq2_b, nullptr, nullptr, wsel, comb, nullptr, NB,1024,1024);

  // ---- expert 1: DenseQuadratic ----
  gemm_bt<1,0><<<dim3(2,64),blk,0,stream>>>(x_hi, dew1_bf, de_b1, nullptr, nullptr, nullptr, nullptr, h256, NB,256,1024);
  gemm_bt<2,0><<<dim3(8,64),blk,0,stream>>>(x_hi, degw_bf, de_gb, nullptr, nullptr, nullptr, nullptr, bufB, NB,1024,1024);
  gemm_bt<0,4><<<dim3(8,64),blk,0,stream>>>(h256, dew2_bf, de_b2, bufB, x, wsel, comb, nullptr, NB,1024,256);

  // ---- expert 2: CrossField (fused accumulate) ----
  cf_kernel<<<dim3(NB),blk,0,stream>>>(x, cf_inw, cf_inb, cf_ow, cf_ob, cf_fw, cf_fb, wsel, comb);

  // ---- expert 3: HighFreq ----
  gemm_bt<3,0><<<dim3(2,64),blk,0,stream>>>(x_hi, hfw1_bf, hf_b1, nullptr, nullptr, nullptr, nullptr, h256, NB,256,1024);
  gemm_bt<0,5><<<dim3(8,64),blk,0,stream>>>(h256, hfw2_bf, hf_b2, nullptr, x, wsel, comb, nullptr, NB,1024,256);

  // ---- expert 5: LongTail ----
  gemm_bt<4,0><<<dim3(2,64),blk,0,stream>>>(x_hi, ltw1_bf, lt_b1, nullptr, nullptr, nullptr, nullptr, h256, NB,256,1024);
  gemm_bt<0,6><<<dim3(8,64),blk,0,stream>>>(h256, ltw2_bf, lt_b2, nullptr, x, wsel, comb, nullptr, NB,1024,256);

  // ---- expert 4: Temporal (last comb reader) + final bf16 conversion ----
  tp_kernel<<<dim3(NB),blk,0,stream>>>(x, wsel, comb, tc_w, tc_b, tf_w, tf_b, bufB);

  // ---- output projection + residual (f32 out) ----
  gemm_bt<0,7><<<dim3(8,64),blk,0,stream>>>(bufB, opw_bf, op_b, nullptr, x, nullptr, nullptr, out, NB,1024,1024);
}

// Round 11
// 683.669 us; speedup vs baseline: 2.4749x; 1.0956x over previous
//
#include <hip/hip_runtime.h>
#include <stdint.h>

typedef unsigned short u16;
typedef __attribute__((ext_vector_type(2))) float f32x2;
typedef __attribute__((ext_vector_type(4))) float f32x4;
typedef __attribute__((ext_vector_type(4))) unsigned short u16x4;
typedef __attribute__((ext_vector_type(8))) short short8;

#define DEV static __device__ __forceinline__

DEV float bf2f(u16 u){ union{unsigned int i; float f;} v; v.i=((unsigned int)u)<<16; return v.f; }
DEV u16 f2bf(float f){ union{float f; unsigned int i;} v; v.f=f; unsigned int u=v.i;
  return (u16)((u + 0x7FFFu + ((u>>16)&1u))>>16); }
DEV float wred(float v){ for(int o=32;o;o>>=1) v += __shfl_xor(v,o); return v; }
DEV float wredmax(float v){ for(int o=32;o;o>>=1) v = fmaxf(v,__shfl_xor(v,o)); return v; }

DEV void gload16(const void* g, void* l){
  __builtin_amdgcn_global_load_lds((const __attribute__((address_space(1))) unsigned int*)g,
                                   (__attribute__((address_space(3))) unsigned int*)l, 16, 0, 0);
}

DEV float actf(int ACT, float v){
  if(ACT==1) return v>0.f?v:0.f;
  if(ACT==2) return 1.f/(1.f+__expf(-v));
  if(ACT==3) return tanhf(v);
  if(ACT==4) return v>0.f?v:(__expf(v)-1.f);
  return v;
}

// ---------------- f32 -> bf16 conversions ----------------
__global__ void cvt_kernel(const float* __restrict__ s, u16* __restrict__ d, int n4){
  for(int i=blockIdx.x*blockDim.x+threadIdx.x; i<n4; i+=gridDim.x*blockDim.x){
    f32x4 v=((const f32x4*)s)[i];
    u16x4 o;
    #pragma unroll
    for(int j=0;j<4;++j) o[j]=f2bf(v[j]);
    ((u16x4*)d)[i]=o;
  }
}

__global__ void cvt6_kernel(
    const float* __restrict__ s0, const float* __restrict__ s1, const float* __restrict__ s2,
    const float* __restrict__ s3, const float* __restrict__ s4, const float* __restrict__ s5,
    u16* __restrict__ d0, u16* __restrict__ d1, u16* __restrict__ d2,
    u16* __restrict__ d3, u16* __restrict__ d4, u16* __restrict__ d5, int n4each){
  const float* ss[6]={s0,s1,s2,s3,s4,s5};
  u16* dd[6]={d0,d1,d2,d3,d4,d5};
  const int total=6*n4each;
  for(int i=blockIdx.x*blockDim.x+threadIdx.x; i<total; i+=gridDim.x*blockDim.x){
    int b=i/n4each, r=i-b*n4each;
    f32x4 v=((const f32x4*)ss[b])[r];
    u16x4 o;
    #pragma unroll
    for(int j=0;j<4;++j) o[j]=f2bf(v[j]);
    ((u16x4*)dd[b])[r]=o;
  }
}

__global__ void cvt_split(const float* __restrict__ s, u16* __restrict__ hi, u16* __restrict__ lo, int n4){
  for(int i=blockIdx.x*blockDim.x+threadIdx.x; i<n4; i+=gridDim.x*blockDim.x){
    f32x4 v=((const f32x4*)s)[i];
    u16x4 h,l;
    #pragma unroll
    for(int j=0;j<4;++j){ h[j]=f2bf(v[j]); l[j]=f2bf(v[j]-bf2f(h[j])); }
    ((u16x4*)hi)[i]=h; ((u16x4*)lo)[i]=l;
  }
}

__global__ void cvt_split_rw1(const float* __restrict__ src, u16* __restrict__ hi, u16* __restrict__ lo){
  for(int i=blockIdx.x*blockDim.x+threadIdx.x; i<512*1024; i+=gridDim.x*blockDim.x){
    int r=i>>10, c=i&1023;
    float v=src[(size_t)r*1030+c];
    u16 h=f2bf(v);
    hi[i]=h; lo[i]=f2bf(v-bf2f(h));
  }
}

// ---------------- GEMM: fused epilogues, global_load_lds staging ------------------------
template<int ACT, int EPI>
__global__ __launch_bounds__(256) void gemm_bt(
    const u16* __restrict__ A, const u16* __restrict__ W,
    const float* __restrict__ bias, const u16* __restrict__ auxb,
    const float* __restrict__ auxf, const float* __restrict__ wsel,
    float* __restrict__ comb, void* __restrict__ Cv, int M, int N, int K)
{
  __shared__ __align__(16) u16 lA[128*64];
  __shared__ __align__(16) u16 lB[128*64];
  const int tid=threadIdx.x, lane=tid&63, wv=tid>>6;
  const int wr=wv>>1, wc=wv&1;
  const int bn=blockIdx.x*128, bm=blockIdx.y*128;
  f32x4 acc[4][4];
  #pragma unroll
  for(int m=0;m<4;++m){
    #pragma unroll
    for(int n=0;n<4;++n) acc[m][n]=(f32x4)0.f;
  }
  const int srow = wv*8 + (lane>>3);
  const int scol = (lane&7)*8;
  for(int kt=0;kt<K;kt+=64){
    #pragma unroll
    for(int i=0;i<4;++i){
      gload16(A + (size_t)(bm + i*32 + srow)*K + kt + scol, &lA[(i*32 + wv*8)*64]);
      gload16(W + (size_t)(bn + i*32 + srow)*K + kt + scol, &lB[(i*32 + wv*8)*64]);
    }
    __syncthreads();
    #pragma unroll
    for(int kk=0;kk<2;++kk){
      const int fr=lane&15, kc=kk*32+(lane>>4)*8;
      short8 af[4], bfr[4];
      #pragma unroll
      for(int m=0;m<4;++m) af[m]=*(const short8*)&lA[(wr*64+m*16+fr)*64+kc];
      #pragma unroll
      for(int n=0;n<4;++n) bfr[n]=*(const short8*)&lB[(wc*64+n*16+fr)*64+kc];
      #pragma unroll
      for(int m=0;m<4;++m){
        #pragma unroll
        for(int n=0;n<4;++n)
          acc[m][n]=__builtin_amdgcn_mfma_f32_16x16x32_bf16(af[m],bfr[n],acc[m][n],0,0,0);
      }
    }
    __syncthreads();
  }
  const int fr=lane&15, fq=lane>>4;
  #pragma unroll
  for(int m=0;m<4;++m){
    #pragma unroll
    for(int n=0;n<4;++n){
      const int col = bn + wc*64 + n*16 + fr;
      const float bv = bias[col];
      #pragma unroll
      for(int j=0;j<4;++j){
        const int row = bm + wr*64 + m*16 + fq*4 + j;
        const size_t idx = (size_t)row*N+col;
        float v = acc[m][n][j] + bv;
        v = actf(ACT, v);
        if(EPI==0){ ((u16*)Cv)[idx]=f2bf(v); }
        else if(EPI==1){ ((float*)Cv)[idx]=v; }
        else if(EPI==2){ ((u16*)Cv)[idx]=f2bf(v*auxf[idx]); }
        else if(EPI==3){ comb[idx]=wsel[row*6+0]*v; }
        else if(EPI==4){ comb[idx]+=wsel[row*6+1]*(v + bf2f(auxb[idx])*auxf[idx]); }
        else if(EPI==5){ float x0=auxf[idx]; comb[idx]+=wsel[row*6+3]*(x0+(v-x0)*x0); }
        else if(EPI==6){
          float x0=auxf[idx];
          float sg=(x0>0.f)?1.f:((x0<0.f)?-1.f:0.f);
          comb[idx]+=wsel[row*6+5]*sg*sqrtf(fabsf(v*x0)+1e-8f);
        }
        else { ((float*)Cv)[idx]=v+auxf[idx]; }
      }
    }
  }
}

// ---------------- split-precision GEMM (f32-accurate), 128x64 tile ----------------------
template<int ACT>
__global__ __launch_bounds__(256) void gemm_split(
    const u16* __restrict__ Ah, const u16* __restrict__ Al,
    const u16* __restrict__ Wh, const u16* __restrict__ Wl,
    const float* __restrict__ bias, float* __restrict__ C, int M, int N, int K)
{
  const int LDL=40;
  __shared__ __align__(16) u16 lAh[128*40], lAl[128*40], lBh[64*40], lBl[64*40];
  const int tid=threadIdx.x, lane=tid&63, wv=tid>>6;
  const int wr=wv>>1, wc=wv&1;
  const int bn=blockIdx.x*64, bm=blockIdx.y*128;
  f32x4 acc[4][2];
  #pragma unroll
  for(int m=0;m<4;++m){
    #pragma unroll
    for(int n=0;n<2;++n) acc[m][n]=(f32x4)0.f;
  }
  const int srow=tid>>2, scol=(tid&3)*8;
  for(int kt=0;kt<K;kt+=32){
    short8 rah[2],ral[2],rbh,rbl;
    #pragma unroll
    for(int i=0;i<2;++i){
      size_t ao=(size_t)(bm+i*64+srow)*K+kt+scol;
      rah[i]=*(const short8*)(Ah+ao); ral[i]=*(const short8*)(Al+ao);
    }
    {
      size_t bo=(size_t)(bn+srow)*K+kt+scol;
      rbh=*(const short8*)(Wh+bo); rbl=*(const short8*)(Wl+bo);
    }
    __syncthreads();
    #pragma unroll
    for(int i=0;i<2;++i){
      int d=(i*64+srow)*LDL+scol;
      *(short8*)&lAh[d]=rah[i]; *(short8*)&lAl[d]=ral[i];
    }
    {
      int d=srow*LDL+scol;
      *(short8*)&lBh[d]=rbh; *(short8*)&lBl[d]=rbl;
    }
    __syncthreads();
    const int fr=lane&15, kc=(lane>>4)*8;
    short8 ah[4],al[4],bh[2],bl[2];
    #pragma unroll
    for(int m=0;m<4;++m){ int r=(wr*64+m*16+fr)*LDL+kc; ah[m]=*(const short8*)&lAh[r]; al[m]=*(const short8*)&lAl[r]; }
    #pragma unroll
    for(int n=0;n<2;++n){ int r=(wc*32+n*16+fr)*LDL+kc; bh[n]=*(const short8*)&lBh[r]; bl[n]=*(const short8*)&lBl[r]; }
    #pragma unroll
    for(int m=0;m<4;++m){
      #pragma unroll
      for(int n=0;n<2;++n){
        acc[m][n]=__builtin_amdgcn_mfma_f32_16x16x32_bf16(ah[m],bh[n],acc[m][n],0,0,0);
        acc[m][n]=__builtin_amdgcn_mfma_f32_16x16x32_bf16(ah[m],bl[n],acc[m][n],0,0,0);
        acc[m][n]=__builtin_amdgcn_mfma_f32_16x16x32_bf16(al[m],bh[n],acc[m][n],0,0,0);
        acc[m][n]=__builtin_amdgcn_mfma_f32_16x16x32_bf16(al[m],bl[n],acc[m][n],0,0,0);
      }
    }
  }
  const int fr=lane&15, fq=lane>>4;
  #pragma unroll
  for(int m=0;m<4;++m){
    #pragma unroll
    for(int n=0;n<2;++n){
      const int col = bn + wc*32 + n*16 + fr;
      const float bv = bias[col];
      #pragma unroll
      for(int j=0;j<4;++j){
        const int row = bm + wr*64 + m*16 + fq*4 + j;
        C[(size_t)row*N+col] = actf(ACT, acc[m][n][j] + bv);
      }
    }
  }
}

// ---------------- feature stats + kpred MLP -> k_vals[row] (radix select) ---------------
__global__ __launch_bounds__(256) void feats_kernel(const float* __restrict__ x,
    const float* __restrict__ kw1, const float* __restrict__ kb1,
    const float* __restrict__ kw2, const float* __restrict__ kb2,
    float* __restrict__ kvals)
{
  __shared__ float xs[1024];
  __shared__ unsigned int cd[1024];
  __shared__ float rbuf[4*6];
  __shared__ float r2[4], r3[4];
  __shared__ float bres[6];
  __shared__ int hist[256];
  __shared__ unsigned int selT;
  __shared__ int selR;
  const int tid=threadIdx.x, lane=tid&63, wv=tid>>6;
  const int row=blockIdx.x;
  f32x4 u = ((const f32x4*)(x+(size_t)row*1024))[tid];
  float s=0.f, ss=0.f, amax=0.f, sa=0.f; float nz=0.f;
  #pragma unroll
  for(int j=0;j<4;++j){
    float f=u[j];
    union{float f;unsigned int i;} cv; cv.f=f;
    xs[4*tid+j]=f; cd[4*tid+j]=cv.i&0x7fffffffu;
    s+=f; ss+=f*f; float a=fabsf(f); sa+=a; amax=fmaxf(amax,a); if(f==0.f) nz+=1.f;
  }
  s=wred(s); ss=wred(ss); sa=wred(sa); nz=wred(nz); amax=wredmax(amax);
  if(lane==0){ rbuf[wv*6+0]=s; rbuf[wv*6+1]=ss; rbuf[wv*6+2]=sa; rbuf[wv*6+3]=nz; rbuf[wv*6+4]=amax; }
  __syncthreads();
  if(tid==0){
    float S=0,SS=0,SA=0,NZ=0,AM=0;
    for(int i=0;i<4;++i){ S+=rbuf[i*6]; SS+=rbuf[i*6+1]; SA+=rbuf[i*6+2]; NZ+=rbuf[i*6+3]; AM=fmaxf(AM,rbuf[i*6+4]); }
    bres[0]=S; bres[1]=SS; bres[2]=SA; bres[3]=NZ; bres[4]=AM;
  }
  __syncthreads();
  const float S=bres[0], SS=bres[1], SA=bres[2], NZ=bres[3], AM=bres[4];
  const float mean=S/1024.f;
  const float var=(SS - S*mean)/1023.f;
  const float inv=1.f/sqrtf(var+1e-8f);
  float sk=0.f;
  #pragma unroll
  for(int j=0;j<4;++j){ float z=(xs[4*tid+j]-mean)*inv; sk+=z*z*z; }
  sk=wred(sk);
  if(lane==0) rbuf[wv*6+5]=sk;
  unsigned int prefix=0u; int r=204;
  #pragma unroll
  for(int lvl=0;lvl<4;++lvl){
    const int shift=24-lvl*8;
    const unsigned int pmask = (lvl==0)?0u:(0xFFFFFFFFu<<(shift+8));
    hist[tid]=0;
    __syncthreads();
    #pragma unroll
    for(int j=0;j<4;++j){
      unsigned int c=cd[4*tid+j];
      if((c&pmask)==prefix) atomicAdd(&hist[(c>>shift)&0xFFu],1);
    }
    __syncthreads();
    if(wv==0){
      int h[4]; int ls=0;
      #pragma unroll
      for(int b=0;b<4;++b){ h[b]=hist[lane*4+b]; ls+=h[b]; }
      int pfx=ls;
      #pragma unroll
      for(int off=1;off<64;off<<=1){ int t=__shfl_up(pfx,off); if(lane>=off) pfx+=t; }
      int total=__shfl(pfx,63);
      int cgt = total - pfx;
      #pragma unroll
      for(int b=3;b>=0;--b){
        if(cgt < r && r <= cgt + h[b]){
          selT = prefix | ((unsigned int)(lane*4+b)<<shift);
          selR = r - cgt;
        }
        cgt += h[b];
      }
    }
    __syncthreads();
    prefix=selT; r=selR;
  }
  const unsigned int T=prefix;
  float sg=0.f; float cg=0.f;
  #pragma unroll
  for(int j=0;j<4;++j){ if(cd[4*tid+j] > T){ sg+=fabsf(xs[4*tid+j]); cg+=1.f; } }
  sg=wred(sg); cg=wred(cg);
  if(lane==0){ r2[wv]=sg; r3[wv]=cg; }
  __syncthreads();
  if(tid==0){
    float SK=rbuf[5]+rbuf[11]+rbuf[17]+rbuf[23];
    float SG=r2[0]+r2[1]+r2[2]+r2[3];
    float CG=r3[0]+r3[1]+r3[2]+r3[3];
    union{unsigned int i;float f;} tv; tv.i=T;
    float conc=(SG + (204.f-CG)*tv.f)/(SA + 1e-8f);
    float feats[6]={ NZ/1024.f, var, AM, sqrtf(SS), SK/1024.f, conc };
    float out=kb2[0];
    #pragma unroll
    for(int i=0;i<16;++i){
      float hv=kb1[i];
      #pragma unroll
      for(int j=0;j<6;++j) hv+=kw1[i*6+j]*feats[j];
      hv=fmaxf(hv,0.f);
      out+=kw2[i]*hv;
    }
    kvals[row]=1.f + 3.f*(1.f/(1.f+__expf(-out)));
  }
}

// ---------------- exact median of 8192 -> k (radix select x2) ----------------
__global__ __launch_bounds__(256) void median_kernel(const float* __restrict__ kvals, int* __restrict__ kint){
  __shared__ unsigned int v[8192];
  __shared__ int hist[256];
  __shared__ unsigned int selT;
  __shared__ int selR;
  const int tid=threadIdx.x, lane=tid&63, wv=tid>>6;
  for(int i=tid;i<8192;i+=256){ union{float f;unsigned int u;} c; c.f=kvals[i]; v[i]=c.u; }
  __syncthreads();
  unsigned int res[2];
  for(int t=0;t<2;++t){
    int r = 8192 - (4096+t) + 1;
    unsigned int prefix=0u;
    for(int lvl=0;lvl<4;++lvl){
      const int shift=24-lvl*8;
      const unsigned int pmask = (lvl==0)?0u:(0xFFFFFFFFu<<(shift+8));
      hist[tid]=0;
      __syncthreads();
      for(int i=tid;i<8192;i+=256){
        unsigned int c=v[i];
        if((c&pmask)==prefix) atomicAdd(&hist[(c>>shift)&0xFFu],1);
      }
      __syncthreads();
      if(wv==0){
        int h[4]; int ls=0;
        #pragma unroll
        for(int b=0;b<4;++b){ h[b]=hist[lane*4+b]; ls+=h[b]; }
        int pfx=ls;
        #pragma unroll
        for(int off=1;off<64;off<<=1){ int tt=__shfl_up(pfx,off); if(lane>=off) pfx+=tt; }
        int total=__shfl(pfx,63);
        int cgt = total - pfx;
        #pragma unroll
        for(int b=3;b>=0;--b){
          if(cgt < r && r <= cgt + h[b]){
            selT = prefix | ((unsigned int)(lane*4+b)<<shift);
            selR = r - cgt;
          }
          cgt += h[b];
        }
      }
      __syncthreads();
      prefix=selT; r=selR;
      __syncthreads();
    }
    res[t]=prefix;
  }
  if(tid==0){
    union{unsigned int u; float f;} a,b; a.u=res[0]; b.u=res[1];
    float med=0.5f*(a.f+b.f);
    int k=(int)floorf(med);
    k = k<1?1:(k>4?4:k);
    *kint=k;
  }
}

// ---------------- spec = sigmoid(x@esp^T + h512a@sim_w2^T + sim_b2), one wave/row ------
__global__ __launch_bounds__(256) void spec_kernel(const float* __restrict__ x, const float* __restrict__ h,
    const float* __restrict__ esp, const float* __restrict__ w2, const float* __restrict__ b2,
    float* __restrict__ spec){
  const int wv=threadIdx.x>>6, lane=threadIdx.x&63;
  const int row=blockIdx.x*4+wv;
  const float* xr=x+(size_t)row*1024;
  const float* hr=h+(size_t)row*512;
  float xv[16], hv[8];
  #pragma unroll
  for(int j=0;j<16;++j) xv[j]=xr[j*64+lane];
  #pragma unroll
  for(int j=0;j<8;++j) hv[j]=hr[j*64+lane];
  for(int e=0;e<6;++e){
    float s=0.f;
    #pragma unroll
    for(int j=0;j<16;++j) s+=xv[j]*esp[e*1024+j*64+lane];
    #pragma unroll
    for(int j=0;j<8;++j) s+=hv[j]*w2[e*512+j*64+lane];
    s=wred(s);
    if(lane==0) spec[row*6+e]=1.f/(1.f+__expf(-(s+b2[e])));
  }
}

// ---------------- rout pre-act += spec @ rw1[:,1024:]^T, relu (f32 h) ----------------
__global__ void rout_fix(float* __restrict__ h, const float* __restrict__ spec, const float* __restrict__ rw1){
  const int total=8192*128;
  for(int i=blockIdx.x*blockDim.x+threadIdx.x;i<total;i+=gridDim.x*blockDim.x){
    int row=i>>7, j0=(i&127)*4;
    const float* sp=&spec[row*6];
    f32x4 hv=((f32x4*)h)[i];
    #pragma unroll
    for(int j=0;j<4;++j){
      float v=hv[j];
      int col=j0+j;
      #pragma unroll
      for(int e=0;e<6;++e) v+=sp[e]*rw1[(size_t)col*1030+1024+e];
      hv[j]=fmaxf(v,0.f);
    }
    ((f32x4*)h)[i]=hv;
  }
}

// ---------------- probs = softmax(h512b@rout_w2^T + rout_b2), one wave per row ----------
__global__ __launch_bounds__(256) void probs_kernel(const float* __restrict__ h, const float* __restrict__ w2,
    const float* __restrict__ b2, float* __restrict__ probs){
  const int wv=threadIdx.x>>6, lane=threadIdx.x&63;
  const int row=blockIdx.x*4+wv;
  const float* hr=h+(size_t)row*512;
  float hv[8];
  #pragma unroll
  for(int j=0;j<8;++j) hv[j]=hr[j*64+lane];
  float lg[6];
  #pragma unroll
  for(int e=0;e<6;++e){
    float s=0.f;
    #pragma unroll
    for(int j=0;j<8;++j) s+=hv[j]*w2[e*512+j*64+lane];
    lg[e]=wred(s)+b2[e];
  }
  if(lane==0){
    float m=lg[0];
    #pragma unroll
    for(int e=1;e<6;++e) m=fmaxf(m,lg[e]);
    float den=0.f, ex[6];
    #pragma unroll
    for(int e=0;e<6;++e){ ex[e]=__expf(lg[e]-m); den+=ex[e]; }
    #pragma unroll
    for(int e=0;e<6;++e) probs[row*6+e]=ex[e]/den;
  }
}

// ---------------- top-4 + gates -> per-expert weights ----------------
__global__ void gates_kernel(const float* __restrict__ probs, const int* __restrict__ kint,
                             float* __restrict__ wsel){
  const int r=blockIdx.x*blockDim.x+threadIdx.x;
  if(r>=8192) return;
  const int k=*kint;
  float p[6];
  #pragma unroll
  for(int e=0;e<6;++e) p[e]=probs[r*6+e];
  float w[6]={0,0,0,0,0,0};
  bool used[6]={false,false,false,false,false,false};
  int idx[4]; float val[4];
  #pragma unroll
  for(int j=0;j<4;++j){
    int bi=0; float bv=-1e30f;
    #pragma unroll
    for(int e=0;e<6;++e) if(!used[e] && p[e]>bv){ bv=p[e]; bi=e; }
    used[bi]=true; idx[j]=bi; val[j]=bv;
  }
  float m=val[0], den=0.f, g[4]={0,0,0,0};
  for(int j=0;j<k;++j){ g[j]=__expf(val[j]-m); den+=g[j]; }
  for(int j=0;j<k;++j) w[idx[j]]=g[j]/den;
  #pragma unroll
  for(int e=0;e<6;++e) wsel[r*6+e]=w[e];
}

// ---------------- CrossField expert: MFMA, 1 wave/row, 4 rows/block ----------------
// frag conventions (verified by passing gemm_bt): A/W-frag lane holds row (lane&15),
// 8 k-elems at (lane>>4)*8.  C/D: col=lane&15, row=(lane>>4)*4+j.
__global__ __launch_bounds__(256) void cf_kernel(const float* __restrict__ x,
    const float* __restrict__ w_in, const float* __restrict__ b_in,
    const float* __restrict__ w_o, const float* __restrict__ b_o,
    const float* __restrict__ w_f, const float* __restrict__ b_f,
    const float* __restrict__ wsel, float* __restrict__ comb){
  __shared__ __align__(16) u16 smem[6400 + 4*6144];
  const int tid=threadIdx.x, wv=tid>>6, lane=tid&63;
  const int fr=lane&15, fq=lane>>4;
  // stage all three weights as bf16 rows (stride 40): w_in rows 0-95, w_o 96-127, w_f 128-159
  for(int i=tid;i<5120;i+=256){
    float v=(i<3072)? w_in[i] : (i<4096? w_o[i-3072] : w_f[i-4096]);
    smem[(i>>5)*40 + (i&31)] = f2bf(v);
  }
  u16* wb   = smem + 6400 + wv*6144;
  float* xfl= (float*)wb;            // 32 rows x stride 36 f32
  u16* bufA = wb + 2304;             // 32 x stride 40  (q -> P)
  u16* bufB = bufA + 1280;           // (k -> av)
  u16* bufC = bufB + 1280;           // (vT -> prod)
  const int row = blockIdx.x*4 + wv;
  const float* xr = x + (size_t)row*1024;
  #pragma unroll
  for(int t=0;t<4;++t){
    f32x4 v = ((const f32x4*)xr)[t*64+lane];
    int e=(t*64+lane)*4;
    *(f32x4*)&xfl[(e>>5)*36 + (e&31)] = v;
  }
  __syncthreads();
  // ---- stage1: qkv = xf @ w_in^T (12 MFMAs) ----
  short8 xa[2];
  #pragma unroll
  for(int ft=0;ft<2;++ft){
    f32x4 a=*(const f32x4*)&xfl[(ft*16+fr)*36 + fq*8];
    f32x4 b=*(const f32x4*)&xfl[(ft*16+fr)*36 + fq*8 + 4];
    short8 s;
    s[0]=(short)f2bf(a[0]); s[1]=(short)f2bf(a[1]); s[2]=(short)f2bf(a[2]); s[3]=(short)f2bf(a[3]);
    s[4]=(short)f2bf(b[0]); s[5]=(short)f2bf(b[1]); s[6]=(short)f2bf(b[2]); s[7]=(short)f2bf(b[3]);
    xa[ft]=s;
  }
  f32x4 acc1[2][6];
  #pragma unroll
  for(int ct=0;ct<6;++ct){
    short8 wfrag=*(const short8*)&smem[(ct*16+fr)*40 + fq*8];
    #pragma unroll
    for(int ft=0;ft<2;++ft)
      acc1[ft][ct]=__builtin_amdgcn_mfma_f32_16x16x32_bf16(xa[ft],wfrag,(f32x4)0.f,0,0,0);
  }
  float bi[6];
  #pragma unroll
  for(int ct=0;ct<6;++ct) bi[ct]=b_in[ct*16+fr];
  #pragma unroll
  for(int ct=0;ct<6;++ct){
    #pragma unroll
    for(int ft=0;ft<2;++ft){
      #pragma unroll
      for(int j=0;j<4;++j){
        u16 h=f2bf(acc1[ft][ct][j]+bi[ct]);
        int rg=ft*16+fq*4+j, cg=ct*16+fr;
        if(cg<32)      bufA[rg*40+cg]=h;           // q[field][dim]
        else if(cg<64) bufB[rg*40+(cg-32)]=h;      // k[field][dim]
        else           bufC[(cg-64)*40+rg]=h;      // vT[dim][field]
      }
    }
  }
  __syncthreads();
  // ---- stage2: S = q @ k^T, softmax -> P (into bufA) ----
  short8 qa0=*(const short8*)&bufA[fr*40+fq*8];
  short8 qa1=*(const short8*)&bufA[(16+fr)*40+fq*8];
  short8 kb0=*(const short8*)&bufB[fr*40+fq*8];
  short8 kb1=*(const short8*)&bufB[(16+fr)*40+fq*8];
  f32x4 aS[2][2];
  aS[0][0]=__builtin_amdgcn_mfma_f32_16x16x32_bf16(qa0,kb0,(f32x4)0.f,0,0,0);
  aS[0][1]=__builtin_amdgcn_mfma_f32_16x16x32_bf16(qa0,kb1,(f32x4)0.f,0,0,0);
  aS[1][0]=__builtin_amdgcn_mfma_f32_16x16x32_bf16(qa1,kb0,(f32x4)0.f,0,0,0);
  aS[1][1]=__builtin_amdgcn_mfma_f32_16x16x32_bf16(qa1,kb1,(f32x4)0.f,0,0,0);
  const float scale=0.17677669529663687f;
  #pragma unroll
  for(int rt=0;rt<2;++rt){
    #pragma unroll
    for(int j=0;j<4;++j){
      float e0=aS[rt][0][j]*scale, e1=aS[rt][1][j]*scale;
      float m=fmaxf(e0,e1);
      #pragma unroll
      for(int o=1;o<16;o<<=1) m=fmaxf(m,__shfl_xor(m,o));
      e0=__expf(e0-m); e1=__expf(e1-m);
      float den=e0+e1;
      #pragma unroll
      for(int o=1;o<16;o<<=1) den+=__shfl_xor(den,o);
      float inv=1.f/den;
      bufA[(rt*16+fq*4+j)*40 + fr]      = f2bf(e0*inv);
      bufA[(rt*16+fq*4+j)*40 + 16+fr]   = f2bf(e1*inv);
    }
  }
  __syncthreads();
  // ---- stage3: av = P @ vT^T (4 MFMAs) -> bufB ----
  short8 pa0=*(const short8*)&bufA[fr*40+fq*8];
  short8 pa1=*(const short8*)&bufA[(16+fr)*40+fq*8];
  short8 vb0=*(const short8*)&bufC[fr*40+fq*8];
  short8 vb1=*(const short8*)&bufC[(16+fr)*40+fq*8];
  f32x4 aA[2][2];
  aA[0][0]=__builtin_amdgcn_mfma_f32_16x16x32_bf16(pa0,vb0,(f32x4)0.f,0,0,0);
  aA[0][1]=__builtin_amdgcn_mfma_f32_16x16x32_bf16(pa0,vb1,(f32x4)0.f,0,0,0);
  aA[1][0]=__builtin_amdgcn_mfma_f32_16x16x32_bf16(pa1,vb0,(f32x4)0.f,0,0,0);
  aA[1][1]=__builtin_amdgcn_mfma_f32_16x16x32_bf16(pa1,vb1,(f32x4)0.f,0,0,0);
  #pragma unroll
  for(int rt=0;rt<2;++rt)
    #pragma unroll
    for(int dt=0;dt<2;++dt)
      #pragma unroll
      for(int j=0;j<4;++j)
        bufB[(rt*16+fq*4+j)*40 + dt*16+fr]=f2bf(aA[rt][dt][j]);
  __syncthreads();
  // ---- stage4: attf = av @ w_o^T; prod = attf*xf -> bufC ----
  short8 aa0=*(const short8*)&bufB[fr*40+fq*8];
  short8 aa1=*(const short8*)&bufB[(16+fr)*40+fq*8];
  short8 ob0=*(const short8*)&smem[(96+fr)*40+fq*8];
  short8 ob1=*(const short8*)&smem[(112+fr)*40+fq*8];
  f32x4 aF[2][2];
  aF[0][0]=__builtin_amdgcn_mfma_f32_16x16x32_bf16(aa0,ob0,(f32x4)0.f,0,0,0);
  aF[0][1]=__builtin_amdgcn_mfma_f32_16x16x32_bf16(aa0,ob1,(f32x4)0.f,0,0,0);
  aF[1][0]=__builtin_amdgcn_mfma_f32_16x16x32_bf16(aa1,ob0,(f32x4)0.f,0,0,0);
  aF[1][1]=__builtin_amdgcn_mfma_f32_16x16x32_bf16(aa1,ob1,(f32x4)0.f,0,0,0);
  float bo[2]={b_o[fr], b_o[16+fr]};
  #pragma unroll
  for(int rt=0;rt<2;++rt){
    #pragma unroll
    for(int dt=0;dt<2;++dt){
      #pragma unroll
      for(int j=0;j<4;++j){
        int fld=rt*16+fq*4+j, d=dt*16+fr;
        float attf=aF[rt][dt][j]+bo[dt];
        bufC[fld*40+d]=f2bf(attf*xfl[fld*36+d]);
      }
    }
  }
  __syncthreads();
  // ---- stage5: e_cf = prod @ w_f^T; comb += w2*e_cf ----
  short8 pr0=*(const short8*)&bufC[fr*40+fq*8];
  short8 pr1=*(const short8*)&bufC[(16+fr)*40+fq*8];
  short8 fb0=*(const short8*)&smem[(128+fr)*40+fq*8];
  short8 fb1=*(const short8*)&smem[(144+fr)*40+fq*8];
  f32x4 aE[2][2];
  aE[0][0]=__builtin_amdgcn_mfma_f32_16x16x32_bf16(pr0,fb0,(f32x4)0.f,0,0,0);
  aE[0][1]=__builtin_amdgcn_mfma_f32_16x16x32_bf16(pr0,fb1,(f32x4)0.f,0,0,0);
  aE[1][0]=__builtin_amdgcn_mfma_f32_16x16x32_bf16(pr1,fb0,(f32x4)0.f,0,0,0);
  aE[1][1]=__builtin_amdgcn_mfma_f32_16x16x32_bf16(pr1,fb1,(f32x4)0.f,0,0,0);
  float bff[2]={b_f[fr], b_f[16+fr]};
  const float w2=wsel[row*6+2];
  float* cb=&comb[(size_t)row*1024];
  #pragma unroll
  for(int rt=0;rt<2;++rt){
    #pragma unroll
    for(int dt=0;dt<2;++dt){
      #pragma unroll
      for(int j=0;j<4;++j){
        int fld=rt*16+fq*4+j, d=dt*16+fr;
        cb[fld*32+d]+=w2*(aE[rt][dt][j]+bff[dt]);
      }
    }
  }
}

// ---------------- Temporal expert + final bf16 conversion ----------------
__global__ __launch_bounds__(256) void tp_kernel(const float* __restrict__ x,
    const float* __restrict__ wsel, const float* __restrict__ comb,
    const float* __restrict__ tcw, const float* __restrict__ tcb,
    const float* __restrict__ tfw, const float* __restrict__ tfb,
    u16* __restrict__ obf){
  __shared__ float xs[1026];
  const int row=blockIdx.x, tid=threadIdx.x;
  f32x4 u=((const f32x4*)(x+(size_t)row*1024))[tid];
  #pragma unroll
  for(int j=0;j<4;++j) xs[1+4*tid+j]=u[j];
  if(tid==0){ xs[0]=0.f; xs[1025]=0.f; }
  __syncthreads();
  const float w4=wsel[row*6+4];
  float tc[4][3], tb[4], tf[4];
  #pragma unroll
  for(int o=0;o<4;++o){
    #pragma unroll
    for(int kh=0;kh<3;++kh) tc[o][kh]=tcw[o*3+kh];
    tb[o]=tcb[o]; tf[o]=tfw[o];
  }
  const float tfb0=tfb[0];
  f32x4 cv=((const f32x4*)(comb+(size_t)row*1024))[tid];
  u16x4 ov;
  #pragma unroll
  for(int j=0;j<4;++j){
    const int d=4*tid+j;
    float pre=tfb0;
    #pragma unroll
    for(int o=0;o<4;++o){
      float c=tb[o]+tc[o][0]*xs[d]+tc[o][1]*xs[d+1]+tc[o][2]*xs[d+2];
      pre+=tf[o]*fmaxf(c,0.f);
    }
    float wt=1.f/(1.f+__expf(-pre));
    float xv=xs[1+d];
    ov[j]=f2bf(cv[j]+w4*xv*xv*wt);
  }
  ((u16x4*)(obf+(size_t)row*1024))[tid]=ov;
}

// =======================================================================================
extern "C" void kernel_launch(void* const* d_in, const int* in_sizes, int n_in,
                              void* d_out, int out_size, void* d_ws, size_t ws_size,
                              hipStream_t stream)
{
  const float* x     =(const float*)d_in[0];
  const float* esp   =(const float*)d_in[1];
  const float* sim_w1=(const float*)d_in[2],  *sim_b1=(const float*)d_in[3];
  const float* sim_w2=(const float*)d_in[4],  *sim_b2=(const float*)d_in[5];
  const float* rout_w1=(const float*)d_in[6], *rout_b1=(const float*)d_in[7];
  const float* rout_w2=(const float*)d_in[8], *rout_b2=(const float*)d_in[9];
  const float* kw1=(const float*)d_in[10], *kb1=(const float*)d_in[11];
  const float* kw2=(const float*)d_in[12], *kb2=(const float*)d_in[13];
  const float* spv_w=(const float*)d_in[14], *spv_b=(const float*)d_in[15];
  const float* spo_w=(const float*)d_in[16], *spo_b=(const float*)d_in[17];
  const float* spq1_w=(const float*)d_in[18], *spq1_b=(const float*)d_in[19];
  const float* spq2_w=(const float*)d_in[20], *spq2_b=(const float*)d_in[21];
  const float* de_w1=(const float*)d_in[22], *de_b1=(const float*)d_in[23];
  const float* de_w2=(const float*)d_in[24], *de_b2=(const float*)d_in[25];
  const float* de_gw=(const float*)d_in[26], *de_gb=(const float*)d_in[27];
  const float* cf_inw=(const float*)d_in[28], *cf_inb=(const float*)d_in[29];
  const float* cf_ow=(const float*)d_in[30], *cf_ob=(const float*)d_in[31];
  const float* cf_fw=(const float*)d_in[32], *cf_fb=(const float*)d_in[33];
  const float* hf_w1=(const float*)d_in[34], *hf_b1=(const float*)d_in[35];
  const float* hf_w2=(const float*)d_in[36], *hf_b2=(const float*)d_in[37];
  const float* tc_w=(const float*)d_in[38], *tc_b=(const float*)d_in[39];
  const float* tf_w=(const float*)d_in[40], *tf_b=(const float*)d_in[41];
  const float* lt_w1=(const float*)d_in[42], *lt_b1=(const float*)d_in[43];
  const float* lt_w2=(const float*)d_in[44], *lt_b2=(const float*)d_in[45];
  const float* op_w=(const float*)d_in[46], *op_b=(const float*)d_in[47];
  float* out=(float*)d_out;
  (void)in_sizes; (void)n_in; (void)out_size; (void)ws_size;

  constexpr int NB=8192;
  const size_t BD=(size_t)NB*1024;
  char* base=(char*)d_ws; size_t off=0;
  auto carve=[&](size_t n)->void*{ void* q=base+off; off+=(n+255)&~(size_t)255; return q; };
  float* comb =(float*)carve(BD*4);
  u16*  bufA =(u16*)carve(BD*2);
  u16*  bufB =(u16*)carve(BD*2);
  u16*  x_hi =(u16*)carve(BD*2);
  u16*  x_lo =(u16*)carve(BD*2);
  float* h512a=(float*)carve((size_t)NB*512*4);
  float* h512b=(float*)carve((size_t)NB*512*4);
  u16*  h256 =(u16*)carve((size_t)NB*256*2);
  u16* sw1h=(u16*)carve((size_t)512*1024*2);
  u16* sw1l=(u16*)carve((size_t)512*1024*2);
  u16* rw1h=(u16*)carve((size_t)512*1024*2);
  u16* rw1l=(u16*)carve((size_t)512*1024*2);
  u16* spv_bf =(u16*)carve((size_t)1024*1024*2);
  u16* spo_bf =(u16*)carve((size_t)1024*1024*2);
  u16* spq1_bf=(u16*)carve((size_t)1024*1024*2);
  u16* spq2_bf=(u16*)carve((size_t)1024*1024*2);
  u16* dew1_bf=(u16*)carve((size_t)256*1024*2);
  u16* dew2_bf=(u16*)carve((size_t)1024*256*2);
  u16* degw_bf=(u16*)carve((size_t)1024*1024*2);
  u16* hfw1_bf=(u16*)carve((size_t)256*1024*2);
  u16* hfw2_bf=(u16*)carve((size_t)1024*256*2);
  u16* ltw1_bf=(u16*)carve((size_t)256*1024*2);
  u16* ltw2_bf=(u16*)carve((size_t)1024*256*2);
  u16* opw_bf =(u16*)carve((size_t)1024*1024*2);
  float* spec=(float*)carve((size_t)NB*6*4);
  float* probs=(float*)carve((size_t)NB*6*4);
  float* wsel=(float*)carve((size_t)NB*6*4);
  float* kvals=(float*)carve((size_t)NB*4);
  int*   kint=(int*)carve(256);

  const dim3 blk(256);
  const dim3 gEW(2048);
  auto cgrid=[&](int n4)->dim3{ int g=(n4+255)/256; return dim3(g>2048?2048:g); };

  // ---- conversions (batched) ----
  cvt_split<<<cgrid(2097152),blk,0,stream>>>(x, x_hi, x_lo, 2097152);
  cvt_split<<<cgrid(131072),blk,0,stream>>>(sim_w1, sw1h, sw1l, 131072);
  cvt_split_rw1<<<cgrid(131072),blk,0,stream>>>(rout_w1, rw1h, rw1l);
  cvt6_kernel<<<cgrid(6*262144),blk,0,stream>>>(spv_w,spo_w,spq1_w,spq2_w,de_gw,op_w,
                                                spv_bf,spo_bf,spq1_bf,spq2_bf,degw_bf,opw_bf, 262144);
  cvt6_kernel<<<cgrid(6*65536),blk,0,stream>>>(de_w1,de_w2,hf_w1,hf_w2,lt_w1,lt_w2,
                                               dew1_bf,dew2_bf,hfw1_bf,hfw2_bf,ltw1_bf,ltw2_bf, 65536);

  // ---- routing pipeline (f32-accurate) ----
  feats_kernel<<<dim3(NB),blk,0,stream>>>(x, kw1,kb1,kw2,kb2, kvals);
  median_kernel<<<dim3(1),blk,0,stream>>>(kvals, kint);
  gemm_split<1><<<dim3(8,64),blk,0,stream>>>(x_hi,x_lo, sw1h,sw1l, sim_b1, h512a, NB,512,1024);
  spec_kernel<<<gEW,blk,0,stream>>>(x, h512a, esp, sim_w2, sim_b2, spec);
  gemm_split<0><<<dim3(8,64),blk,0,stream>>>(x_hi,x_lo, rw1h,rw1l, rout_b1, h512b, NB,512,1024);
  rout_fix<<<gEW,blk,0,stream>>>(h512b, spec, rout_w1);
  probs_kernel<<<gEW,blk,0,stream>>>(h512b, rout_w2, rout_b2, probs);
  gates_kernel<<<dim3(32),blk,0,stream>>>(probs, kint, wsel);

  // ---- expert 0: SparseQuadratic ----
  gemm_bt<0,0><<<dim3(8,64),blk,0,stream>>>(x_hi, spv_bf, spv_b, nullptr, nullptr, nullptr, nullptr, bufA, NB,1024,1024);
  gemm_bt<0,2><<<dim3(8,64),blk,0,stream>>>(bufA, spo_bf, spo_b, nullptr, x, nullptr, nullptr, bufB, NB,1024,1024);
  gemm_bt<1,0><<<dim3(8,64),blk,0,stream>>>(bufB, spq1_bf, spq1_b, nullptr, nullptr, nullptr, nullptr, bufA, NB,1024,1024);
  gemm_bt<0,3><<<dim3(8,64),blk,0,stream>>>(bufA, spq2_bf, spq2_b, nullptr, nullptr, wsel, comb, nullptr, NB,1024,1024);

  // ---- expert 1: DenseQuadratic ----
  gemm_bt<1,0><<<dim3(2,64),blk,0,stream>>>(x_hi, dew1_bf, de_b1, nullptr, nullptr, nullptr, nullptr, h256, NB,256,1024);
  gemm_bt<2,0><<<dim3(8,64),blk,0,stream>>>(x_hi, degw_bf, de_gb, nullptr, nullptr, nullptr, nullptr, bufB, NB,1024,1024);
  gemm_bt<0,4><<<dim3(8,64),blk,0,stream>>>(h256, dew2_bf, de_b2, bufB, x, wsel, comb, nullptr, NB,1024,256);

  // ---- expert 2: CrossField (MFMA, fused accumulate) ----
  cf_kernel<<<dim3(2048),blk,0,stream>>>(x, cf_inw, cf_inb, cf_ow, cf_ob, cf_fw, cf_fb, wsel, comb);

  // ---- expert 3: HighFreq ----
  gemm_bt<3,0><<<dim3(2,64),blk,0,stream>>>(x_hi, hfw1_bf, hf_b1, nullptr, nullptr, nullptr, nullptr, h256, NB,256,1024);
  gemm_bt<0,5><<<dim3(8,64),blk,0,stream>>>(h256, hfw2_bf, hf_b2, nullptr, x, wsel, comb, nullptr, NB,1024,256);

  // ---- expert 5: LongTail ----
  gemm_bt<4,0><<<dim3(2,64),blk,0,stream>>>(x_hi, ltw1_bf, lt_b1, nullptr, nullptr, nullptr, nullptr, h256, NB,256,1024);
  gemm_bt<0,6><<<dim3(8,64),blk,0,stream>>>(h256, ltw2_bf, lt_b2, nullptr, x, wsel, comb, nullptr, NB,1024,256);

  // ---- expert 4: Temporal (last comb reader) + final bf16 conversion ----
  tp_kernel<<<dim3(NB),blk,0,stream>>>(x, wsel, comb, tc_w, tc_b, tf_w, tf_b, bufB);

  // ---- output projection + residual (f32 out) ----
  gemm_bt<0,7><<<dim3(8,64),blk,0,stream>>>(bufB, opw_bf, op_b, nullptr, x, nullptr, nullptr, out, NB,1024,1024);
}